// Round 13
// baseline (448.358 us; speedup 1.0000x reference)
//
#include <hip/hip_runtime.h>
#include <hip/hip_bf16.h>

#define B_   256
#define S_   2048
#define DIN  128
#define H_   64
#define SD_  5
#define GDT  16            // steps per group
#define NTT  (S_ / GDT)    // 128 groups
#define TOKB 256           // tokens per phaseA block
#define NIT  4             // tiles per wave in phaseA

typedef __attribute__((ext_vector_type(8))) short short8_t;   // 8 bf16
typedef __attribute__((ext_vector_type(4))) float float4_t;   // MFMA acc

__device__ __forceinline__ float rcpf_(float x){ return __builtin_amdgcn_rcpf(x); }

// exact-erf GELU: gelu(x)=0.5x(1+erf(x/sqrt2)), A&S 7.1.26
__device__ __forceinline__ float geluf(float v){
  const float kInvSqrt2 = 0.70710678118654752440f;
  float z = v * kInvSqrt2;
  float a = fabsf(z);
  float t = rcpf_(fmaf(0.3275911f, a, 1.0f));
  float p = fmaf(fmaf(fmaf(fmaf(1.061405429f, t, -1.453152027f), t, 1.421413741f),
                      t, -0.284496736f), t, 0.254829592f);
  p *= t;
  float e = 1.0f - p * __expf(-z * z);
  float er = copysignf(e, z);
  return 0.5f * v * (1.0f + er);
}

__device__ __forceinline__ float sigmoidf_(float x){
  return rcpf_(1.0f + __expf(-x));
}

// Pade(3,2) tanh with clamp: |err| <= 0.0065 (attenuated x0.01 by corr_scale)
__device__ __forceinline__ float tanh_pade(float x){
  float xc = fminf(fmaxf(x, -4.0f), 4.0f);
  float t = xc * xc;
  float n = xc * (27.0f + t);
  float d = fmaf(9.0f, t, 27.0f);
  return n * rcpf_(d);
}

__device__ __forceinline__ unsigned short f2bf_hw(float f){
  union { __hip_bfloat16 b; unsigned short u; } cv;
  cv.b = __float2bfloat16(f);
  return cv.u;
}
__device__ __forceinline__ float bf2f(unsigned short h){
  return __uint_as_float(((unsigned int)h) << 16);
}

// ---- DPP helpers ----
template<int CTRL>
__device__ __forceinline__ float dpp_radd(float x){
  int sh = __builtin_amdgcn_update_dpp(0, __float_as_int(x), CTRL, 0xf, 0xf, true);
  return x + __int_as_float(sh);
}
__device__ __forceinline__ float red16(float x){
  x = dpp_radd<0xB1>(x);   // quad_perm xor1
  x = dpp_radd<0x4E>(x);   // quad_perm xor2
  x = dpp_radd<0x124>(x);  // row_ror:4
  x = dpp_radd<0x128>(x);  // row_ror:8
  return x;
}

// raw barrier: drain LDS ops, barrier, pin the scheduler (keeps vmcnt counted)
#define BARRIER() do{                                   \
  asm volatile("s_waitcnt lgkmcnt(0)" ::: "memory");    \
  __builtin_amdgcn_s_barrier();                         \
  __builtin_amdgcn_sched_barrier(0);                    \
}while(0)

// ---------------------------------------------------------------------------
// Phase A (unchanged, MFMA-based)
// ---------------------------------------------------------------------------
__global__ __launch_bounds__(256, 4) void phaseA(
    const float* __restrict__ x, const float* __restrict__ W_in,
    const float* __restrict__ b_in, const float* __restrict__ ln_g,
    const float* __restrict__ ln_b, const float* __restrict__ W_innov,
    const float* __restrict__ b_innov, const float* __restrict__ W_c1,
    const float* __restrict__ b_c1,
    unsigned short* __restrict__ hp_out, float* __restrict__ bx_out)
{
  __shared__ __align__(16) unsigned short WfA[4][4][512];
  __shared__ __align__(16) unsigned short WfC[2][4][512];
  __shared__ __align__(16) unsigned short WfI[2][512];
  __shared__ __align__(16) unsigned short hbuf[4][16][72];

  const int tid  = threadIdx.x;
  const int lane = tid & 63;
  const int w    = tid >> 6;
  const int c16  = lane & 15;
  const int g4   = lane >> 4;
  const long tok0 = (long)blockIdx.x * TOKB;

  {
    const int l = lane, tg = w;
    #pragma unroll
    for (int pp = 0; pp < 4; ++pp){
      int p  = tg * 4 + pp;
      int kc = p >> 2, nc = p & 3;
      unsigned short tmp[8];
      #pragma unroll
      for (int m = 0; m < 8; ++m)
        tmp[m] = f2bf_hw(W_in[(32 * kc + 8 * (l >> 4) + m) * 64 + 16 * nc + (l & 15)]);
      *(uint4*)&WfA[kc][nc][l * 8] = *(uint4*)tmp;
    }
    #pragma unroll
    for (int pp = 0; pp < 2; ++pp){
      int p  = tg * 2 + pp;
      int kc2 = p >> 2, nc = p & 3;
      unsigned short tmp[8];
      #pragma unroll
      for (int m = 0; m < 8; ++m)
        tmp[m] = f2bf_hw(W_c1[(5 + 32 * kc2 + 8 * (l >> 4) + m) * 64 + 16 * nc + (l & 15)]);
      *(uint4*)&WfC[kc2][nc][l * 8] = *(uint4*)tmp;
    }
    if (tg < 2){
      int kc2 = tg;
      unsigned short tmp[8];
      #pragma unroll
      for (int m = 0; m < 8; ++m)
        tmp[m] = ((l & 15) < 5)
               ? f2bf_hw(W_innov[(32 * kc2 + 8 * (l >> 4) + m) * 5 + (l & 15)])
               : (unsigned short)0;
      *(uint4*)&WfI[kc2][l * 8] = *(uint4*)tmp;
    }
  }

  float binv[4], lg[4], lb[4], bc1v[4];
  #pragma unroll
  for (int nc = 0; nc < 4; ++nc){
    binv[nc] = b_in[16 * nc + c16];
    lg[nc]   = ln_g[16 * nc + c16];
    lb[nc]   = ln_b[16 * nc + c16];
    bc1v[nc] = b_c1[16 * nc + c16];
  }
  float binn = (c16 < 5) ? b_innov[c16] : 0.0f;

  __syncthreads();

  for (int it = 0; it < NIT; ++it){
    const long tbg = tok0 + it * 64 + w * 16;

    const float* xr = x + (size_t)(tbg + c16) * DIN;
    short8_t a1[4];
    #pragma unroll
    for (int kc = 0; kc < 4; ++kc){
      float4 f0 = *(const float4*)(xr + kc * 32 + g4 * 8);
      float4 f1 = *(const float4*)(xr + kc * 32 + g4 * 8 + 4);
      a1[kc][0] = (short)f2bf_hw(f0.x); a1[kc][1] = (short)f2bf_hw(f0.y);
      a1[kc][2] = (short)f2bf_hw(f0.z); a1[kc][3] = (short)f2bf_hw(f0.w);
      a1[kc][4] = (short)f2bf_hw(f1.x); a1[kc][5] = (short)f2bf_hw(f1.y);
      a1[kc][6] = (short)f2bf_hw(f1.z); a1[kc][7] = (short)f2bf_hw(f1.w);
    }

    float4_t acc1[4] = {{0,0,0,0},{0,0,0,0},{0,0,0,0},{0,0,0,0}};
    #pragma unroll
    for (int kc = 0; kc < 4; ++kc){
      #pragma unroll
      for (int nc = 0; nc < 4; ++nc){
        short8_t bf = *(const short8_t*)&WfA[kc][nc][lane * 8];
        acc1[nc] = __builtin_amdgcn_mfma_f32_16x16x32_bf16(a1[kc], bf, acc1[nc], 0, 0, 0);
      }
    }

    float v[4][4];
    #pragma unroll
    for (int nc = 0; nc < 4; ++nc)
      #pragma unroll
      for (int r = 0; r < 4; ++r)
        v[nc][r] = acc1[nc][r] + binv[nc];

    float mu[4], rstd[4];
    #pragma unroll
    for (int r = 0; r < 4; ++r){
      float vs = (v[0][r] + v[1][r]) + (v[2][r] + v[3][r]);
      float qs = v[0][r] * v[0][r];
      qs = fmaf(v[1][r], v[1][r], qs);
      qs = fmaf(v[2][r], v[2][r], qs);
      qs = fmaf(v[3][r], v[3][r], qs);
      vs = red16(vs);
      qs = red16(qs);
      float m  = vs * (1.0f / 64.0f);
      float va = fmaxf(qs * (1.0f / 64.0f) - m * m, 0.0f);
      mu[r]   = m;
      rstd[r] = rsqrtf(va + 1e-5f);
    }

    #pragma unroll
    for (int nc = 0; nc < 4; ++nc)
      #pragma unroll
      for (int r = 0; r < 4; ++r){
        float hn = fmaf((v[nc][r] - mu[r]) * rstd[r], lg[nc], lb[nc]);
        hbuf[w][4 * g4 + r][16 * nc + c16] = f2bf_hw(geluf(hn));
      }

    short8_t a2[2];
    a2[0] = *(const short8_t*)&hbuf[w][c16][8 * g4];
    a2[1] = *(const short8_t*)&hbuf[w][c16][32 + 8 * g4];

    float4_t acc2[4] = {{0,0,0,0},{0,0,0,0},{0,0,0,0},{0,0,0,0}};
    #pragma unroll
    for (int kc2 = 0; kc2 < 2; ++kc2){
      #pragma unroll
      for (int nc = 0; nc < 4; ++nc){
        short8_t bf = *(const short8_t*)&WfC[kc2][nc][lane * 8];
        acc2[nc] = __builtin_amdgcn_mfma_f32_16x16x32_bf16(a2[kc2], bf, acc2[nc], 0, 0, 0);
      }
    }
    float4_t acc3 = {0, 0, 0, 0};
    {
      short8_t bi0 = *(const short8_t*)&WfI[0][lane * 8];
      short8_t bi1 = *(const short8_t*)&WfI[1][lane * 8];
      acc3 = __builtin_amdgcn_mfma_f32_16x16x32_bf16(a2[0], bi0, acc3, 0, 0, 0);
      acc3 = __builtin_amdgcn_mfma_f32_16x16x32_bf16(a2[1], bi1, acc3, 0, 0, 0);
    }

    if (c16 < 5){
      #pragma unroll
      for (int r = 0; r < 4; ++r)
        bx_out[(size_t)(tbg + 4 * g4 + r) * 8 + c16] = acc3[r] + binn;
    }

    #pragma unroll
    for (int nc = 0; nc < 4; ++nc)
      #pragma unroll
      for (int r = 0; r < 4; ++r)
        hbuf[w][4 * g4 + r][16 * nc + c16] = f2bf_hw(acc2[nc][r] + bc1v[nc]);

    {
      const int tl = lane >> 2, j = lane & 3;
      uint4 v0 = *(const uint4*)&hbuf[w][tl][j * 16];
      uint4 v1 = *(const uint4*)&hbuf[w][tl][j * 16 + 8];
      unsigned short* hg = hp_out + (size_t)(tbg + tl) * 64 + j * 16;
      *(uint4*)hg       = v0;
      *(uint4*)(hg + 8) = v1;
    }
  }
}

// ---------------------------------------------------------------------------
// Phase B: producer-consumer (wave0 = recursion, wave1 = MFMA corr), delay-3
// (A^48) injection — numerics identical to R10/R11/R12. hp/bx now feed wave0
// through a CONTINUOUS depth-8 global->register rotating file (no LDS staging,
// no ISSUE/vmcnt machinery): per-step lgkm ops drop 6 -> 3, LDS pipe traffic
// halves, and the lgkmcnt FIFO stays inside its 15-entry counter. crR (from
// wave1) keeps the depth-4 LDS rotation; uT staging write unchanged.
// ---------------------------------------------------------------------------
__global__ __launch_bounds__(128, 1) void phaseB(
    const unsigned short* __restrict__ hp, const float* __restrict__ bx,
    const float* __restrict__ W_c1, const float* __restrict__ W_c2,
    const float* __restrict__ b_c2, const float* __restrict__ corr_scale,
    const float* __restrict__ rawL, const float* __restrict__ rawT,
    const float* __restrict__ rawG, const float* __restrict__ rawR,
    const float* __restrict__ omega, float* __restrict__ out)
{
  __shared__ __align__(16) unsigned short uT[2][GDT][64];   // 4 KB (swizzled cols)
  __shared__ __align__(16) float crR[3][GDT][8];            // 1.5 KB ring

  const int tid  = threadIdx.x;
  const int lane = tid & 63;
  const int wid  = tid >> 6;
  const int b = blockIdx.x;
  const int c16 = lane & 15;
  const int g4  = lane >> 4;

  // zero-init the correction ring (384 floats, 128 threads x 3)
  ((float*)crR)[tid]       = 0.f;
  ((float*)crR)[tid + 128] = 0.f;
  ((float*)crR)[tid + 256] = 0.f;

  float aL = sigmoidf_(rawL[0]) * 0.15f + 0.85f;
  float aT = sigmoidf_(rawT[0]) * 0.25f + 0.70f;
  float gg = sigmoidf_(rawG[0]) * 0.20f + 0.80f;
  float om = omega[0];
  float co = cosf(om), sn = sinf(om);
  float r00 = gg * co, r01 = -gg * sn, r10 = gg * sn, r11 = gg * co;
  float aR = sigmoidf_(rawR[0]) * 0.4f;
  float cs = corr_scale[0];

  // A^48 for the 3-group (48-step) delayed injection
  auto p16f = [](float v){ float t = v * v; t = t * t; t = t * t; return t * t; };
  float aL16 = p16f(aL), aT16 = p16f(aT), aR16 = p16f(aR), g16 = p16f(gg);
  float aL48 = aL16 * aL16 * aL16;
  float aT48 = aT16 * aT16 * aT16;
  float aR48 = aR16 * aR16 * aR16;
  float g48  = g16 * g16 * g16;
  float ck = cosf(48.0f * om), sk = sinf(48.0f * om);
  float p00 = g48 * ck, p01 = -g48 * sk, p10 = g48 * sk, p11 = g48 * ck;

  float w0 = W_c1[0 * 64 + lane], w1 = W_c1[1 * 64 + lane], w2 = W_c1[2 * 64 + lane];
  float w3 = W_c1[3 * 64 + lane], w4 = W_c1[4 * 64 + lane];
  float bc0 = b_c2[0], bc1 = b_c2[1], bc2v = b_c2[2], bc3 = b_c2[3], bc4 = b_c2[4];
  float bcs0 = (g4 == 1) ? bc4 : bc0;   // acc reg0 = row i=4*g4

  // static A-frags for CORR (wave 1): W_c2^T, K split j 0..31 / 32..63
  short8_t aF0, aF1;
  #pragma unroll
  for (int m = 0; m < 8; ++m){
    int j0 = 8 * g4 + m;
    float v0 = (c16 < 5) ? W_c2[j0 * 5 + c16] : 0.0f;
    float v1 = (c16 < 5) ? W_c2[(j0 + 32) * 5 + c16] : 0.0f;
    aF0[m] = (short)f2bf_hw(v0);
    aF1[m] = (short)f2bf_hw(v1);
  }

  const unsigned short* hpg = hp + (size_t)b * S_ * H_;
  const float* bxg = bx + (size_t)b * S_ * 8;

  float s0 = 0.f, s1 = 0.f, s2 = 0.f, s3 = 0.f, s4 = 0.f;

  // global->register rotating file (wave 0), depth 8, continuous over steps
  unsigned short hpR[8];
  float4 bxR[8];
  float  beR[8];

  // crR depth-4 rotation buffers (wave 0)
  float4 cpR[4];
  float  ceR[4];

  // wave0: 16-step recursion for group t; global operands pre-rotated.
  auto RECUR = [&](int t, int rsl, int ub){
    #pragma unroll
    for (int j = 0; j < 3; ++j){
      cpR[j] = *(const float4*)&crR[rsl][j][0];
      ceR[j] = crR[rsl][j][4];
    }
    #pragma unroll
    for (int k = 0; k < GDT; ++k){
      const int cur = k & 7;
      const int nxt = (k + 7) & 7;
      {
        int gl = t * GDT + k + 7;
        if (gl >= S_) gl = 0;                       // tail dummy
        hpR[nxt] = hpg[(size_t)gl * 64 + lane];
        bxR[nxt] = *(const float4*)&bxg[gl * 8];
        beR[nxt] = bxg[gl * 8 + 4];
      }
      const int c3 = k & 3;
      const int n3 = (k + 3) & 3;
      if (k + 3 < GDT){
        cpR[n3] = *(const float4*)&crR[rsl][k + 3][0];
        ceR[n3] = crR[rsl][k + 3][4];
      }

      float4 cp = cpR[c3];
      float  ce = ceR[c3];
      float4 xb = bxR[cur];
      float  xe = beR[cur];
      float  hk = bf2f(hpR[cur]);

      float i0 = fmaf(cp.x, aL48, xb.x);
      float i1 = fmaf(cp.y, aT48, xb.y);
      float i2 = fmaf(cp.z, p00, fmaf(cp.w, p10, xb.z));
      float i3 = fmaf(cp.z, p01, fmaf(cp.w, p11, xb.w));
      float i4 = fmaf(ce, aR48, xe);

      float n0 = fmaf(s0, aL, i0);
      float n1 = fmaf(s1, aT, i1);
      float n2 = fmaf(s2, r00, fmaf(s3, r10, i2));
      float n3v = fmaf(s2, r01, fmaf(s3, r11, i3));
      float n4 = fmaf(s4, aR, i4);
      s0 = n0; s1 = n1; s2 = n2; s3 = n3v; s4 = n4;

      float u = fmaf(n0, w0, hk);
      u = fmaf(n1, w1, u);
      u = fmaf(n2, w2, u);
      u = fmaf(n3v, w3, u);
      u = fmaf(n4, w4, u);
      float uu = u * rcpf_(1.0f + __expf(-1.702f * u));   // sigmoid-GELU
      const int jsw = lane ^ ((k & 7) << 3);              // bank swizzle
      uT[ub][k][jsw] = (unsigned short)(__float_as_uint(uu) >> 16);
    }
  };

  auto CORR = [&](int wsl, int ub){
    const int blk0 = (g4 ^ (c16 & 7)) * 8;
    const int blk1 = ((4 + g4) ^ (c16 & 7)) * 8;
    short8_t b0 = *(const short8_t*)&uT[ub][c16][blk0];
    short8_t b1 = *(const short8_t*)&uT[ub][c16][blk1];
    float4_t acc = {0.f, 0.f, 0.f, 0.f};
    acc = __builtin_amdgcn_mfma_f32_16x16x32_bf16(aF0, b0, acc, 0, 0, 0);
    acc = __builtin_amdgcn_mfma_f32_16x16x32_bf16(aF1, b1, acc, 0, 0, 0);
    float d0 = cs * tanh_pade(acc[0] + bcs0);
    float d1 = cs * tanh_pade(acc[1] + bc1);
    float d2 = cs * tanh_pade(acc[2] + bc2v);
    float d3 = cs * tanh_pade(acc[3] + bc3);
    if (g4 == 0)
      *(float4*)&crR[wsl][c16][0] = make_float4(d0, d1, d2, d3);  // i=0..3, k=c16
    if (g4 == 1)
      crR[wsl][c16][4] = d0;                                      // i=4
  };

  __syncthreads();   // crR zeros visible to all

  // ---- prologue: preload global steps 0..6, then g=0 ----
  if (wid == 0){
    #pragma unroll
    for (int j = 0; j < 7; ++j){
      hpR[j] = hpg[(size_t)j * 64 + lane];
      bxR[j] = *(const float4*)&bxg[j * 8];
      beR[j] = bxg[j * 8 + 4];
    }
    RECUR(0, 0, 0);           // g=0: reads crR[0] (zeros), stages uT[0]
  }

  int rs = 0, ws = 0;
  for (int t = 1; t < NTT; ++t){
    rs = (rs == 2) ? 0 : rs + 1;      // = t%3
    BARRIER();
    if (wid == 0){
      RECUR(t, rs, t & 1);            // g=t
    } else {
      CORR(ws, (t - 1) & 1);          // g=t-1 -> crR[(t-1)%3]
    }
    ws = (ws == 2) ? 0 : ws + 1;      // after iter t: ws = t%3
  }
  BARRIER();
  if (wid == 1) CORR(ws, (NTT - 1) & 1);   // g=NTT-1, ws=(NTT-1)%3
  BARRIER();

  // ---- tail: s_final = s_hat + Horner(last 48 corrections under A) ----
  if (wid == 0){
    const int sl0 = (NTT - 3) % 3, sl1 = (NTT - 2) % 3, sl2 = (NTT - 1) % 3;
    const int sl[3] = { sl0, sl1, sl2 };
    float v0 = 0.f, v1 = 0.f, v2 = 0.f, v3 = 0.f, v4 = 0.f;
    #pragma unroll
    for (int gi = 0; gi < 3; ++gi){
      const int sli = sl[gi];
      #pragma unroll
      for (int k = 0; k < GDT; ++k){
        float n0 = fmaf(v0, aL, crR[sli][k][0]);
        float n1 = fmaf(v1, aT, crR[sli][k][1]);
        float n2 = fmaf(v2, r00, fmaf(v3, r10, crR[sli][k][2]));
        float n3 = fmaf(v2, r01, fmaf(v3, r11, crR[sli][k][3]));
        float n4 = fmaf(v4, aR, crR[sli][k][4]);
        v0 = n0; v1 = n1; v2 = n2; v3 = n3; v4 = n4;
      }
    }
    if (lane == 0){
      float* o = out + b * SD_;
      o[0] = s0 + v0; o[1] = s1 + v1; o[2] = s2 + v2;
      o[3] = s3 + v3; o[4] = s4 + v4;
    }
  }
}

// ---------------------------------------------------------------------------
extern "C" void kernel_launch(void* const* d_in, const int* in_sizes, int n_in,
                              void* d_out, int out_size, void* d_ws, size_t ws_size,
                              hipStream_t stream)
{
  const float* x          = (const float*)d_in[0];
  const float* W_in       = (const float*)d_in[1];
  const float* b_in       = (const float*)d_in[2];
  const float* ln_g       = (const float*)d_in[3];
  const float* ln_b       = (const float*)d_in[4];
  const float* W_innov    = (const float*)d_in[5];
  const float* b_innov    = (const float*)d_in[6];
  const float* W_c1       = (const float*)d_in[7];
  const float* b_c1       = (const float*)d_in[8];
  const float* W_c2       = (const float*)d_in[9];
  const float* b_c2       = (const float*)d_in[10];
  const float* corr_scale = (const float*)d_in[11];
  const float* rawL       = (const float*)d_in[12];
  const float* rawT       = (const float*)d_in[13];
  const float* rawG       = (const float*)d_in[14];
  const float* rawR       = (const float*)d_in[15];
  const float* omega      = (const float*)d_in[16];

  unsigned short* hp = (unsigned short*)d_ws;
  float* bx = (float*)((char*)d_ws + (size_t)B_ * S_ * H_ * 2);

  int nblocksA = (B_ * S_) / TOKB;   // 2048
  phaseA<<<nblocksA, 256, 0, stream>>>(x, W_in, b_in, ln_g, ln_b,
                                       W_innov, b_innov, W_c1, b_c1, hp, bx);
  phaseB<<<B_, 128, 0, stream>>>(hp, bx, W_c1, W_c2, b_c2, corr_scale,
                                 rawL, rawT, rawG, rawR, omega, (float*)d_out);
}

// Round 14
// 208.267 us; speedup vs baseline: 2.1528x; 2.1528x over previous
//
#include <hip/hip_runtime.h>
#include <hip/hip_bf16.h>

#define B_   256
#define S_   2048
#define DIN  128
#define H_   64
#define SD_  5
#define TOKB 256   // tokens per phaseA block
#define NIT  4     // tiles per wave in phaseA

typedef __attribute__((ext_vector_type(8))) short short8_t;   // 8 bf16
typedef __attribute__((ext_vector_type(4))) float float4_t;   // MFMA acc

__device__ __forceinline__ float rcpf_(float x){ return __builtin_amdgcn_rcpf(x); }

// exact-erf GELU: gelu(x)=0.5x(1+erf(x/sqrt2)), A&S 7.1.26
__device__ __forceinline__ float geluf(float v){
  const float kInvSqrt2 = 0.70710678118654752440f;
  float z = v * kInvSqrt2;
  float a = fabsf(z);
  float t = rcpf_(fmaf(0.3275911f, a, 1.0f));
  float p = fmaf(fmaf(fmaf(fmaf(1.061405429f, t, -1.453152027f), t, 1.421413741f),
                      t, -0.284496736f), t, 0.254829592f);
  p *= t;
  float e = 1.0f - p * __expf(-z * z);
  float er = copysignf(e, z);
  return 0.5f * v * (1.0f + er);
}

__device__ __forceinline__ float sigmoidf_(float x){
  return rcpf_(1.0f + __expf(-x));
}

// Pade(3,2) tanh with clamp: |err| <= 0.0065 (attenuated x0.01 by corr_scale)
__device__ __forceinline__ float tanh_pade(float x){
  float xc = fminf(fmaxf(x, -4.0f), 4.0f);
  float t = xc * xc;
  float n = xc * (27.0f + t);
  float d = fmaf(9.0f, t, 27.0f);
  return n * rcpf_(d);
}

__device__ __forceinline__ unsigned short f2bf_hw(float f){
  union { __hip_bfloat16 b; unsigned short u; } cv;
  cv.b = __float2bfloat16(f);
  return cv.u;
}
__device__ __forceinline__ float bf2f(unsigned short h){
  return __uint_as_float(((unsigned int)h) << 16);
}

// ---- DPP helpers (phaseA) ----
template<int CTRL>
__device__ __forceinline__ float dpp_radd(float x){
  int sh = __builtin_amdgcn_update_dpp(0, __float_as_int(x), CTRL, 0xf, 0xf, true);
  return x + __int_as_float(sh);
}
__device__ __forceinline__ float red16(float x){
  x = dpp_radd<0xB1>(x);   // quad_perm xor1
  x = dpp_radd<0x4E>(x);   // quad_perm xor2
  x = dpp_radd<0x124>(x);  // row_ror:4
  x = dpp_radd<0x128>(x);  // row_ror:8
  return x;
}

// ---------------------------------------------------------------------------
// Phase A (unchanged, MFMA-based)
// ---------------------------------------------------------------------------
__global__ __launch_bounds__(256, 4) void phaseA(
    const float* __restrict__ x, const float* __restrict__ W_in,
    const float* __restrict__ b_in, const float* __restrict__ ln_g,
    const float* __restrict__ ln_b, const float* __restrict__ W_innov,
    const float* __restrict__ b_innov, const float* __restrict__ W_c1,
    const float* __restrict__ b_c1,
    unsigned short* __restrict__ hp_out, float* __restrict__ bx_out)
{
  __shared__ __align__(16) unsigned short WfA[4][4][512];
  __shared__ __align__(16) unsigned short WfC[2][4][512];
  __shared__ __align__(16) unsigned short WfI[2][512];
  __shared__ __align__(16) unsigned short hbuf[4][16][72];

  const int tid  = threadIdx.x;
  const int lane = tid & 63;
  const int w    = tid >> 6;
  const int c16  = lane & 15;
  const int g4   = lane >> 4;
  const long tok0 = (long)blockIdx.x * TOKB;

  {
    const int l = lane, tg = w;
    #pragma unroll
    for (int pp = 0; pp < 4; ++pp){
      int p  = tg * 4 + pp;
      int kc = p >> 2, nc = p & 3;
      unsigned short tmp[8];
      #pragma unroll
      for (int m = 0; m < 8; ++m)
        tmp[m] = f2bf_hw(W_in[(32 * kc + 8 * (l >> 4) + m) * 64 + 16 * nc + (l & 15)]);
      *(uint4*)&WfA[kc][nc][l * 8] = *(uint4*)tmp;
    }
    #pragma unroll
    for (int pp = 0; pp < 2; ++pp){
      int p  = tg * 2 + pp;
      int kc2 = p >> 2, nc = p & 3;
      unsigned short tmp[8];
      #pragma unroll
      for (int m = 0; m < 8; ++m)
        tmp[m] = f2bf_hw(W_c1[(5 + 32 * kc2 + 8 * (l >> 4) + m) * 64 + 16 * nc + (l & 15)]);
      *(uint4*)&WfC[kc2][nc][l * 8] = *(uint4*)tmp;
    }
    if (tg < 2){
      int kc2 = tg;
      unsigned short tmp[8];
      #pragma unroll
      for (int m = 0; m < 8; ++m)
        tmp[m] = ((l & 15) < 5)
               ? f2bf_hw(W_innov[(32 * kc2 + 8 * (l >> 4) + m) * 5 + (l & 15)])
               : (unsigned short)0;
      *(uint4*)&WfI[kc2][l * 8] = *(uint4*)tmp;
    }
  }

  float binv[4], lg[4], lb[4], bc1v[4];
  #pragma unroll
  for (int nc = 0; nc < 4; ++nc){
    binv[nc] = b_in[16 * nc + c16];
    lg[nc]   = ln_g[16 * nc + c16];
    lb[nc]   = ln_b[16 * nc + c16];
    bc1v[nc] = b_c1[16 * nc + c16];
  }
  float binn = (c16 < 5) ? b_innov[c16] : 0.0f;

  __syncthreads();

  for (int it = 0; it < NIT; ++it){
    const long tbg = tok0 + it * 64 + w * 16;

    const float* xr = x + (size_t)(tbg + c16) * DIN;
    short8_t a1[4];
    #pragma unroll
    for (int kc = 0; kc < 4; ++kc){
      float4 f0 = *(const float4*)(xr + kc * 32 + g4 * 8);
      float4 f1 = *(const float4*)(xr + kc * 32 + g4 * 8 + 4);
      a1[kc][0] = (short)f2bf_hw(f0.x); a1[kc][1] = (short)f2bf_hw(f0.y);
      a1[kc][2] = (short)f2bf_hw(f0.z); a1[kc][3] = (short)f2bf_hw(f0.w);
      a1[kc][4] = (short)f2bf_hw(f1.x); a1[kc][5] = (short)f2bf_hw(f1.y);
      a1[kc][6] = (short)f2bf_hw(f1.z); a1[kc][7] = (short)f2bf_hw(f1.w);
    }

    float4_t acc1[4] = {{0,0,0,0},{0,0,0,0},{0,0,0,0},{0,0,0,0}};
    #pragma unroll
    for (int kc = 0; kc < 4; ++kc){
      #pragma unroll
      for (int nc = 0; nc < 4; ++nc){
        short8_t bf = *(const short8_t*)&WfA[kc][nc][lane * 8];
        acc1[nc] = __builtin_amdgcn_mfma_f32_16x16x32_bf16(a1[kc], bf, acc1[nc], 0, 0, 0);
      }
    }

    float v[4][4];
    #pragma unroll
    for (int nc = 0; nc < 4; ++nc)
      #pragma unroll
      for (int r = 0; r < 4; ++r)
        v[nc][r] = acc1[nc][r] + binv[nc];

    float mu[4], rstd[4];
    #pragma unroll
    for (int r = 0; r < 4; ++r){
      float vs = (v[0][r] + v[1][r]) + (v[2][r] + v[3][r]);
      float qs = v[0][r] * v[0][r];
      qs = fmaf(v[1][r], v[1][r], qs);
      qs = fmaf(v[2][r], v[2][r], qs);
      qs = fmaf(v[3][r], v[3][r], qs);
      vs = red16(vs);
      qs = red16(qs);
      float m  = vs * (1.0f / 64.0f);
      float va = fmaxf(qs * (1.0f / 64.0f) - m * m, 0.0f);
      mu[r]   = m;
      rstd[r] = rsqrtf(va + 1e-5f);
    }

    #pragma unroll
    for (int nc = 0; nc < 4; ++nc)
      #pragma unroll
      for (int r = 0; r < 4; ++r){
        float hn = fmaf((v[nc][r] - mu[r]) * rstd[r], lg[nc], lb[nc]);
        hbuf[w][4 * g4 + r][16 * nc + c16] = f2bf_hw(geluf(hn));
      }

    short8_t a2[2];
    a2[0] = *(const short8_t*)&hbuf[w][c16][8 * g4];
    a2[1] = *(const short8_t*)&hbuf[w][c16][32 + 8 * g4];

    float4_t acc2[4] = {{0,0,0,0},{0,0,0,0},{0,0,0,0},{0,0,0,0}};
    #pragma unroll
    for (int kc2 = 0; kc2 < 2; ++kc2){
      #pragma unroll
      for (int nc = 0; nc < 4; ++nc){
        short8_t bf = *(const short8_t*)&WfC[kc2][nc][lane * 8];
        acc2[nc] = __builtin_amdgcn_mfma_f32_16x16x32_bf16(a2[kc2], bf, acc2[nc], 0, 0, 0);
      }
    }
    float4_t acc3 = {0, 0, 0, 0};
    {
      short8_t bi0 = *(const short8_t*)&WfI[0][lane * 8];
      short8_t bi1 = *(const short8_t*)&WfI[1][lane * 8];
      acc3 = __builtin_amdgcn_mfma_f32_16x16x32_bf16(a2[0], bi0, acc3, 0, 0, 0);
      acc3 = __builtin_amdgcn_mfma_f32_16x16x32_bf16(a2[1], bi1, acc3, 0, 0, 0);
    }

    if (c16 < 5){
      #pragma unroll
      for (int r = 0; r < 4; ++r)
        bx_out[(size_t)(tbg + 4 * g4 + r) * 8 + c16] = acc3[r] + binn;
    }

    #pragma unroll
    for (int nc = 0; nc < 4; ++nc)
      #pragma unroll
      for (int r = 0; r < 4; ++r)
        hbuf[w][4 * g4 + r][16 * nc + c16] = f2bf_hw(acc2[nc][r] + bc1v[nc]);

    {
      const int tl = lane >> 2, j = lane & 3;
      uint4 v0 = *(const uint4*)&hbuf[w][tl][j * 16];
      uint4 v1 = *(const uint4*)&hbuf[w][tl][j * 16 + 8];
      unsigned short* hg = hp_out + (size_t)(tbg + tl) * 64 + j * 16;
      *(uint4*)hg       = v0;
      *(uint4*)(hg + 8) = v1;
    }
  }
}

// ---------------------------------------------------------------------------
// Phase B (two-pass parallel scan): per row (block, 256 threads):
//   pass1: parallel linear scan of bx under A (segments of 8 + Kogge-Stone,
//          A^len in closed 5-param form) -> all states s0_t
//   c-eval: c_t = cs*tanh(W2^T gelu(W1^T s0_t + hp_t)), all tokens parallel
//   pass2: aggregate-only scan of (bx + c) -> s_2047
// No serial chain, no inter-wave pipeline, no MFMA.
// ---------------------------------------------------------------------------
__global__ __launch_bounds__(256, 1) void phaseB(
    const unsigned short* __restrict__ hp, const float* __restrict__ bx,
    const float* __restrict__ W_c1, const float* __restrict__ W_c2,
    const float* __restrict__ b_c2, const float* __restrict__ corr_scale,
    const float* __restrict__ rawL, const float* __restrict__ rawT,
    const float* __restrict__ rawG, const float* __restrict__ rawR,
    const float* __restrict__ omega, float* __restrict__ out)
{
  __shared__ __align__(16) float scanb[2][256][6];   // 12 KB
  __shared__ __align__(16) float Wp[64][12];         // 3 KB

  const int tid = threadIdx.x;
  const int b = blockIdx.x;

  float aL = sigmoidf_(rawL[0]) * 0.15f + 0.85f;
  float aT = sigmoidf_(rawT[0]) * 0.25f + 0.70f;
  float gg = sigmoidf_(rawG[0]) * 0.20f + 0.80f;
  float om = omega[0];
  float gc = gg * cosf(om), gs = gg * sinf(om);   // n2 =  gc*s2 + gs*s3
                                                  // n3 = -gs*s2 + gc*s3
  float aR = sigmoidf_(rawR[0]) * 0.4f;
  float cs = corr_scale[0];
  float bc0 = b_c2[0], bc1 = b_c2[1], bc2v = b_c2[2], bc3 = b_c2[3], bc4 = b_c2[4];

  // stage correction weights: Wp[j] = {W_c1[0..4][j], W_c2[j][0..4]}
  if (tid < 64){
    #pragma unroll
    for (int i = 0; i < 5; ++i) Wp[tid][i]     = W_c1[i * 64 + tid];
    #pragma unroll
    for (int i = 0; i < 5; ++i) Wp[tid][5 + i] = W_c2[tid * 5 + i];
  }

  const float* bxr = bx + (size_t)b * S_ * 8 + (size_t)tid * 64;
  const unsigned short* hpg = hp + (size_t)b * S_ * H_;

  // ---- pass 1 local: 8-step serial prefix within segment ----
  float p[8][5];
  {
    float c0 = 0.f, c1 = 0.f, c2 = 0.f, c3 = 0.f, c4 = 0.f;
    #pragma unroll
    for (int j = 0; j < 8; ++j){
      float4 vb = *(const float4*)&bxr[j * 8];
      float  ve = bxr[j * 8 + 4];
      float n0 = fmaf(c0, aL, vb.x);
      float n1 = fmaf(c1, aT, vb.y);
      float n2 = fmaf(c2, gc, fmaf(c3, gs, vb.z));
      float n3 = fmaf(c2, -gs, fmaf(c3, gc, vb.w));
      float n4 = fmaf(c4, aR, ve);
      c0 = n0; c1 = n1; c2 = n2; c3 = n3; c4 = n4;
      p[j][0] = n0; p[j][1] = n1; p[j][2] = n2; p[j][3] = n3; p[j][4] = n4;
    }
    scanb[0][tid][0] = c0; scanb[0][tid][1] = c1; scanb[0][tid][2] = c2;
    scanb[0][tid][3] = c3; scanb[0][tid][4] = c4;
  }
  __syncthreads();

  // ---- Kogge-Stone over 256 segment aggregates (level-d matrix = A^(8*2^d))
  int bufc = 0;
  {
    // A^8 via 3 squarings of (aL, aT, gc, gs, aR)
    float mL = aL, mT = aT, mc = gc, ms = gs, mR = aR;
    #pragma unroll
    for (int q = 0; q < 3; ++q){
      float nc = mc * mc - ms * ms, ns = 2.f * mc * ms;
      mL *= mL; mT *= mT; mR *= mR; mc = nc; ms = ns;
    }
    #pragma unroll
    for (int d = 0; d < 8; ++d){
      const int off = 1 << d;
      float x0 = scanb[bufc][tid][0], x1 = scanb[bufc][tid][1],
            x2 = scanb[bufc][tid][2], x3 = scanb[bufc][tid][3],
            x4 = scanb[bufc][tid][4];
      if (tid >= off){
        const float* pr = &scanb[bufc][tid - off][0];
        float q0 = pr[0], q1 = pr[1], q2 = pr[2], q3 = pr[3], q4 = pr[4];
        x0 = fmaf(q0, mL, x0);
        x1 = fmaf(q1, mT, x1);
        x2 = fmaf(q2, mc, fmaf(q3, gs * 0.f + ms, x2));   // gc/gs of level: mc, ms
        x3 = fmaf(q2, -ms, fmaf(q3, mc, x3));
        x4 = fmaf(q4, mR, x4);
      }
      scanb[bufc ^ 1][tid][0] = x0; scanb[bufc ^ 1][tid][1] = x1;
      scanb[bufc ^ 1][tid][2] = x2; scanb[bufc ^ 1][tid][3] = x3;
      scanb[bufc ^ 1][tid][4] = x4;
      __syncthreads();
      bufc ^= 1;
      float nc = mc * mc - ms * ms, ns = 2.f * mc * ms;
      mL *= mL; mT *= mT; mR *= mR; mc = nc; ms = ns;
    }
  }

  // ---- exclusive offset + full states: p[j] <- A^{j+1} O + p[j] ----
  {
    float o0 = 0.f, o1 = 0.f, o2 = 0.f, o3 = 0.f, o4 = 0.f;
    if (tid > 0){
      const float* pr = &scanb[bufc][tid - 1][0];
      o0 = pr[0]; o1 = pr[1]; o2 = pr[2]; o3 = pr[3]; o4 = pr[4];
    }
    #pragma unroll
    for (int j = 0; j < 8; ++j){
      float n0 = o0 * aL;
      float n1 = o1 * aT;
      float n2 = fmaf(o2, gc, o3 * gs);
      float n3 = fmaf(o3, gc, -o2 * gs);
      float n4 = o4 * aR;
      o0 = n0; o1 = n1; o2 = n2; o3 = n3; o4 = n4;
      p[j][0] += n0; p[j][1] += n1; p[j][2] += n2; p[j][3] += n3; p[j][4] += n4;
    }
  }

  // ---- c-eval: all tokens in parallel ----
  float acc[8][5];
  #pragma unroll
  for (int j = 0; j < 8; ++j){ acc[j][0]=0.f; acc[j][1]=0.f; acc[j][2]=0.f; acc[j][3]=0.f; acc[j][4]=0.f; }

  #pragma unroll
  for (int ch = 0; ch < 8; ++ch){
    uint4 hpc[8];
    #pragma unroll
    for (int tok = 0; tok < 8; ++tok)
      hpc[tok] = *(const uint4*)&hpg[(size_t)(tid * 8 + tok) * 64 + ch * 8];
    #pragma unroll
    for (int jj = 0; jj < 8; ++jj){
      const float* wr = &Wp[ch * 8 + jj][0];
      float w0 = wr[0], w1 = wr[1], w2 = wr[2], w3 = wr[3], w4 = wr[4];
      float q0 = wr[5], q1 = wr[6], q2 = wr[7], q3 = wr[8], q4 = wr[9];
      #pragma unroll
      for (int tok = 0; tok < 8; ++tok){
        unsigned int word = ((const unsigned int*)&hpc[tok])[jj >> 1];
        unsigned short hu = (jj & 1) ? (unsigned short)(word >> 16)
                                     : (unsigned short)(word & 0xffff);
        float hv = bf2f(hu);
        float up = fmaf(p[tok][0], w0, hv);
        up = fmaf(p[tok][1], w1, up);
        up = fmaf(p[tok][2], w2, up);
        up = fmaf(p[tok][3], w3, up);
        up = fmaf(p[tok][4], w4, up);
        float u = up * rcpf_(1.0f + __expf(-1.702f * up));   // sigmoid-GELU
        acc[tok][0] = fmaf(u, q0, acc[tok][0]);
        acc[tok][1] = fmaf(u, q1, acc[tok][1]);
        acc[tok][2] = fmaf(u, q2, acc[tok][2]);
        acc[tok][3] = fmaf(u, q3, acc[tok][3]);
        acc[tok][4] = fmaf(u, q4, acc[tok][4]);
      }
    }
  }

  // ---- pass 2 local aggregate: v' = bx + c ----
  float a0 = 0.f, a1 = 0.f, a2 = 0.f, a3 = 0.f, a4 = 0.f;
  #pragma unroll
  for (int j = 0; j < 8; ++j){
    float4 vb = *(const float4*)&bxr[j * 8];
    float  ve = bxr[j * 8 + 4];
    float c0v = cs * tanh_pade(acc[j][0] + bc0);
    float c1v = cs * tanh_pade(acc[j][1] + bc1);
    float c2v = cs * tanh_pade(acc[j][2] + bc2v);
    float c3v = cs * tanh_pade(acc[j][3] + bc3);
    float c4v = cs * tanh_pade(acc[j][4] + bc4);
    float v0 = vb.x + c0v, v1 = vb.y + c1v, v2 = vb.z + c2v,
          v3 = vb.w + c3v, v4 = ve + c4v;
    float n0 = fmaf(a0, aL, v0);
    float n1 = fmaf(a1, aT, v1);
    float n2 = fmaf(a2, gc, fmaf(a3, gs, v2));
    float n3 = fmaf(a2, -gs, fmaf(a3, gc, v3));
    float n4 = fmaf(a4, aR, v4);
    a0 = n0; a1 = n1; a2 = n2; a3 = n3; a4 = n4;
  }
  __syncthreads();   // pass-1 scan reads complete before buffer reuse
  scanb[0][tid][0] = a0; scanb[0][tid][1] = a1; scanb[0][tid][2] = a2;
  scanb[0][tid][3] = a3; scanb[0][tid][4] = a4;
  __syncthreads();

  // ---- Kogge-Stone pass 2 (inclusive; thread 255 ends with s_2047) ----
  bufc = 0;
  {
    float mL = aL, mT = aT, mc = gc, ms = gs, mR = aR;
    #pragma unroll
    for (int q = 0; q < 3; ++q){
      float nc = mc * mc - ms * ms, ns = 2.f * mc * ms;
      mL *= mL; mT *= mT; mR *= mR; mc = nc; ms = ns;
    }
    float x0 = 0.f, x1 = 0.f, x2 = 0.f, x3 = 0.f, x4 = 0.f;
    #pragma unroll
    for (int d = 0; d < 8; ++d){
      const int off = 1 << d;
      x0 = scanb[bufc][tid][0]; x1 = scanb[bufc][tid][1];
      x2 = scanb[bufc][tid][2]; x3 = scanb[bufc][tid][3];
      x4 = scanb[bufc][tid][4];
      if (tid >= off){
        const float* pr = &scanb[bufc][tid - off][0];
        float q0 = pr[0], q1 = pr[1], q2 = pr[2], q3 = pr[3], q4 = pr[4];
        x0 = fmaf(q0, mL, x0);
        x1 = fmaf(q1, mT, x1);
        x2 = fmaf(q2, mc, fmaf(q3, ms, x2));
        x3 = fmaf(q2, -ms, fmaf(q3, mc, x3));
        x4 = fmaf(q4, mR, x4);
      }
      scanb[bufc ^ 1][tid][0] = x0; scanb[bufc ^ 1][tid][1] = x1;
      scanb[bufc ^ 1][tid][2] = x2; scanb[bufc ^ 1][tid][3] = x3;
      scanb[bufc ^ 1][tid][4] = x4;
      __syncthreads();
      bufc ^= 1;
      float nc = mc * mc - ms * ms, ns = 2.f * mc * ms;
      mL *= mL; mT *= mT; mR *= mR; mc = nc; ms = ns;
    }
    if (tid == 255){
      float* o = out + b * SD_;
      o[0] = x0; o[1] = x1; o[2] = x2; o[3] = x3; o[4] = x4;
    }
  }
}

// ---------------------------------------------------------------------------
extern "C" void kernel_launch(void* const* d_in, const int* in_sizes, int n_in,
                              void* d_out, int out_size, void* d_ws, size_t ws_size,
                              hipStream_t stream)
{
  const float* x          = (const float*)d_in[0];
  const float* W_in       = (const float*)d_in[1];
  const float* b_in       = (const float*)d_in[2];
  const float* ln_g       = (const float*)d_in[3];
  const float* ln_b       = (const float*)d_in[4];
  const float* W_innov    = (const float*)d_in[5];
  const float* b_innov    = (const float*)d_in[6];
  const float* W_c1       = (const float*)d_in[7];
  const float* b_c1       = (const float*)d_in[8];
  const float* W_c2       = (const float*)d_in[9];
  const float* b_c2       = (const float*)d_in[10];
  const float* corr_scale = (const float*)d_in[11];
  const float* rawL       = (const float*)d_in[12];
  const float* rawT       = (const float*)d_in[13];
  const float* rawG       = (const float*)d_in[14];
  const float* rawR       = (const float*)d_in[15];
  const float* omega      = (const float*)d_in[16];

  unsigned short* hp = (unsigned short*)d_ws;
  float* bx = (float*)((char*)d_ws + (size_t)B_ * S_ * H_ * 2);

  int nblocksA = (B_ * S_) / TOKB;   // 2048
  phaseA<<<nblocksA, 256, 0, stream>>>(x, W_in, b_in, ln_g, ln_b,
                                       W_innov, b_innov, W_c1, b_c1, hp, bx);
  phaseB<<<B_, 256, 0, stream>>>(hp, bx, W_c1, W_c2, b_c2, corr_scale,
                                 rawL, rawT, rawG, rawR, omega, (float*)d_out);
}

// Round 15
// 164.128 us; speedup vs baseline: 2.7317x; 1.2689x over previous
//
#include <hip/hip_runtime.h>
#include <hip/hip_bf16.h>

#define B_   256
#define S_   2048
#define DIN  128
#define H_   64
#define SD_  5
#define TOKB 256   // tokens per phaseA block
#define NIT  4     // tiles per wave in phaseA

typedef __attribute__((ext_vector_type(8))) short short8_t;   // 8 bf16
typedef __attribute__((ext_vector_type(4))) float float4_t;   // MFMA acc

__device__ __forceinline__ float rcpf_(float x){ return __builtin_amdgcn_rcpf(x); }

// exact-erf GELU: gelu(x)=0.5x(1+erf(x/sqrt2)), A&S 7.1.26
__device__ __forceinline__ float geluf(float v){
  const float kInvSqrt2 = 0.70710678118654752440f;
  float z = v * kInvSqrt2;
  float a = fabsf(z);
  float t = rcpf_(fmaf(0.3275911f, a, 1.0f));
  float p = fmaf(fmaf(fmaf(fmaf(1.061405429f, t, -1.453152027f), t, 1.421413741f),
                      t, -0.284496736f), t, 0.254829592f);
  p *= t;
  float e = 1.0f - p * __expf(-z * z);
  float er = copysignf(e, z);
  return 0.5f * v * (1.0f + er);
}

__device__ __forceinline__ float sigmoidf_(float x){
  return rcpf_(1.0f + __expf(-x));
}

// Pade(3,2) tanh with clamp: |err| <= 0.0065 (attenuated x0.01 by corr_scale)
__device__ __forceinline__ float tanh_pade(float x){
  float xc = fminf(fmaxf(x, -4.0f), 4.0f);
  float t = xc * xc;
  float n = xc * (27.0f + t);
  float d = fmaf(9.0f, t, 27.0f);
  return n * rcpf_(d);
}

__device__ __forceinline__ unsigned short f2bf_hw(float f){
  union { __hip_bfloat16 b; unsigned short u; } cv;
  cv.b = __float2bfloat16(f);
  return cv.u;
}
__device__ __forceinline__ float bf2f(unsigned short h){
  return __uint_as_float(((unsigned int)h) << 16);
}

// ---- DPP helpers (phaseA) ----
template<int CTRL>
__device__ __forceinline__ float dpp_radd(float x){
  int sh = __builtin_amdgcn_update_dpp(0, __float_as_int(x), CTRL, 0xf, 0xf, true);
  return x + __int_as_float(sh);
}
__device__ __forceinline__ float red16(float x){
  x = dpp_radd<0xB1>(x);   // quad_perm xor1
  x = dpp_radd<0x4E>(x);   // quad_perm xor2
  x = dpp_radd<0x124>(x);  // row_ror:4
  x = dpp_radd<0x128>(x);  // row_ror:8
  return x;
}

// ---------------------------------------------------------------------------
// Phase A (MFMA-based; x loads now software-prefetched one tile ahead)
// ---------------------------------------------------------------------------
__global__ __launch_bounds__(256, 3) void phaseA(
    const float* __restrict__ x, const float* __restrict__ W_in,
    const float* __restrict__ b_in, const float* __restrict__ ln_g,
    const float* __restrict__ ln_b, const float* __restrict__ W_innov,
    const float* __restrict__ b_innov, const float* __restrict__ W_c1,
    const float* __restrict__ b_c1,
    unsigned short* __restrict__ hp_out, float* __restrict__ bx_out)
{
  __shared__ __align__(16) unsigned short WfA[4][4][512];
  __shared__ __align__(16) unsigned short WfC[2][4][512];
  __shared__ __align__(16) unsigned short WfI[2][512];
  __shared__ __align__(16) unsigned short hbuf[4][16][72];

  const int tid  = threadIdx.x;
  const int lane = tid & 63;
  const int w    = tid >> 6;
  const int c16  = lane & 15;
  const int g4   = lane >> 4;
  const long tok0 = (long)blockIdx.x * TOKB;

  {
    const int l = lane, tg = w;
    #pragma unroll
    for (int pp = 0; pp < 4; ++pp){
      int p  = tg * 4 + pp;
      int kc = p >> 2, nc = p & 3;
      unsigned short tmp[8];
      #pragma unroll
      for (int m = 0; m < 8; ++m)
        tmp[m] = f2bf_hw(W_in[(32 * kc + 8 * (l >> 4) + m) * 64 + 16 * nc + (l & 15)]);
      *(uint4*)&WfA[kc][nc][l * 8] = *(uint4*)tmp;
    }
    #pragma unroll
    for (int pp = 0; pp < 2; ++pp){
      int p  = tg * 2 + pp;
      int kc2 = p >> 2, nc = p & 3;
      unsigned short tmp[8];
      #pragma unroll
      for (int m = 0; m < 8; ++m)
        tmp[m] = f2bf_hw(W_c1[(5 + 32 * kc2 + 8 * (l >> 4) + m) * 64 + 16 * nc + (l & 15)]);
      *(uint4*)&WfC[kc2][nc][l * 8] = *(uint4*)tmp;
    }
    if (tg < 2){
      int kc2 = tg;
      unsigned short tmp[8];
      #pragma unroll
      for (int m = 0; m < 8; ++m)
        tmp[m] = ((l & 15) < 5)
               ? f2bf_hw(W_innov[(32 * kc2 + 8 * (l >> 4) + m) * 5 + (l & 15)])
               : (unsigned short)0;
      *(uint4*)&WfI[kc2][l * 8] = *(uint4*)tmp;
    }
  }

  float binv[4], lg[4], lb[4], bc1v[4];
  #pragma unroll
  for (int nc = 0; nc < 4; ++nc){
    binv[nc] = b_in[16 * nc + c16];
    lg[nc]   = ln_g[16 * nc + c16];
    lb[nc]   = ln_b[16 * nc + c16];
    bc1v[nc] = b_c1[16 * nc + c16];
  }
  float binn = (c16 < 5) ? b_innov[c16] : 0.0f;

  __syncthreads();

  // ---- x prefetch: tile 0 into xf[0] ----
  float4 xf[2][8];
  {
    const float* xr = x + (size_t)(tok0 + w * 16 + c16) * DIN;
    #pragma unroll
    for (int kc = 0; kc < 4; ++kc){
      xf[0][2 * kc]     = *(const float4*)(xr + kc * 32 + g4 * 8);
      xf[0][2 * kc + 1] = *(const float4*)(xr + kc * 32 + g4 * 8 + 4);
    }
  }

  #pragma unroll
  for (int it = 0; it < NIT; ++it){
    const int cur = it & 1;
    const int nxt = cur ^ 1;
    const long tbg = tok0 + it * 64 + w * 16;

    // issue next tile's loads before this tile's compute
    if (it + 1 < NIT){
      const float* xr = x + (size_t)(tbg + 64 + c16) * DIN;
      #pragma unroll
      for (int kc = 0; kc < 4; ++kc){
        xf[nxt][2 * kc]     = *(const float4*)(xr + kc * 32 + g4 * 8);
        xf[nxt][2 * kc + 1] = *(const float4*)(xr + kc * 32 + g4 * 8 + 4);
      }
    }

    short8_t a1[4];
    #pragma unroll
    for (int kc = 0; kc < 4; ++kc){
      float4 f0 = xf[cur][2 * kc];
      float4 f1 = xf[cur][2 * kc + 1];
      a1[kc][0] = (short)f2bf_hw(f0.x); a1[kc][1] = (short)f2bf_hw(f0.y);
      a1[kc][2] = (short)f2bf_hw(f0.z); a1[kc][3] = (short)f2bf_hw(f0.w);
      a1[kc][4] = (short)f2bf_hw(f1.x); a1[kc][5] = (short)f2bf_hw(f1.y);
      a1[kc][6] = (short)f2bf_hw(f1.z); a1[kc][7] = (short)f2bf_hw(f1.w);
    }

    float4_t acc1[4] = {{0,0,0,0},{0,0,0,0},{0,0,0,0},{0,0,0,0}};
    #pragma unroll
    for (int kc = 0; kc < 4; ++kc){
      #pragma unroll
      for (int nc = 0; nc < 4; ++nc){
        short8_t bf = *(const short8_t*)&WfA[kc][nc][lane * 8];
        acc1[nc] = __builtin_amdgcn_mfma_f32_16x16x32_bf16(a1[kc], bf, acc1[nc], 0, 0, 0);
      }
    }

    float v[4][4];
    #pragma unroll
    for (int nc = 0; nc < 4; ++nc)
      #pragma unroll
      for (int r = 0; r < 4; ++r)
        v[nc][r] = acc1[nc][r] + binv[nc];

    float mu[4], rstd[4];
    #pragma unroll
    for (int r = 0; r < 4; ++r){
      float vs = (v[0][r] + v[1][r]) + (v[2][r] + v[3][r]);
      float qs = v[0][r] * v[0][r];
      qs = fmaf(v[1][r], v[1][r], qs);
      qs = fmaf(v[2][r], v[2][r], qs);
      qs = fmaf(v[3][r], v[3][r], qs);
      vs = red16(vs);
      qs = red16(qs);
      float m  = vs * (1.0f / 64.0f);
      float va = fmaxf(qs * (1.0f / 64.0f) - m * m, 0.0f);
      mu[r]   = m;
      rstd[r] = rsqrtf(va + 1e-5f);
    }

    #pragma unroll
    for (int nc = 0; nc < 4; ++nc)
      #pragma unroll
      for (int r = 0; r < 4; ++r){
        float hn = fmaf((v[nc][r] - mu[r]) * rstd[r], lg[nc], lb[nc]);
        hbuf[w][4 * g4 + r][16 * nc + c16] = f2bf_hw(geluf(hn));
      }

    short8_t a2[2];
    a2[0] = *(const short8_t*)&hbuf[w][c16][8 * g4];
    a2[1] = *(const short8_t*)&hbuf[w][c16][32 + 8 * g4];

    float4_t acc2[4] = {{0,0,0,0},{0,0,0,0},{0,0,0,0},{0,0,0,0}};
    #pragma unroll
    for (int kc2 = 0; kc2 < 2; ++kc2){
      #pragma unroll
      for (int nc = 0; nc < 4; ++nc){
        short8_t bf = *(const short8_t*)&WfC[kc2][nc][lane * 8];
        acc2[nc] = __builtin_amdgcn_mfma_f32_16x16x32_bf16(a2[kc2], bf, acc2[nc], 0, 0, 0);
      }
    }
    float4_t acc3 = {0, 0, 0, 0};
    {
      short8_t bi0 = *(const short8_t*)&WfI[0][lane * 8];
      short8_t bi1 = *(const short8_t*)&WfI[1][lane * 8];
      acc3 = __builtin_amdgcn_mfma_f32_16x16x32_bf16(a2[0], bi0, acc3, 0, 0, 0);
      acc3 = __builtin_amdgcn_mfma_f32_16x16x32_bf16(a2[1], bi1, acc3, 0, 0, 0);
    }

    if (c16 < 5){
      #pragma unroll
      for (int r = 0; r < 4; ++r)
        bx_out[(size_t)(tbg + 4 * g4 + r) * 8 + c16] = acc3[r] + binn;
    }

    #pragma unroll
    for (int nc = 0; nc < 4; ++nc)
      #pragma unroll
      for (int r = 0; r < 4; ++r)
        hbuf[w][4 * g4 + r][16 * nc + c16] = f2bf_hw(acc2[nc][r] + bc1v[nc]);

    {
      const int tl = lane >> 2, j = lane & 3;
      uint4 v0 = *(const uint4*)&hbuf[w][tl][j * 16];
      uint4 v1 = *(const uint4*)&hbuf[w][tl][j * 16 + 8];
      unsigned short* hg = hp_out + (size_t)(tbg + tl) * 64 + j * 16;
      *(uint4*)hg       = v0;
      *(uint4*)(hg + 8) = v1;
    }
  }
}

// ---------------------------------------------------------------------------
// Phase B (two-pass parallel scan, unchanged from R14): per row (block, 256
// threads): pass1 parallel linear scan of bx under A; c-eval for all tokens
// in parallel; pass2 aggregate-only scan of (bx + c) -> s_2047.
// ---------------------------------------------------------------------------
__global__ __launch_bounds__(256, 1) void phaseB(
    const unsigned short* __restrict__ hp, const float* __restrict__ bx,
    const float* __restrict__ W_c1, const float* __restrict__ W_c2,
    const float* __restrict__ b_c2, const float* __restrict__ corr_scale,
    const float* __restrict__ rawL, const float* __restrict__ rawT,
    const float* __restrict__ rawG, const float* __restrict__ rawR,
    const float* __restrict__ omega, float* __restrict__ out)
{
  __shared__ __align__(16) float scanb[2][256][6];   // 12 KB
  __shared__ __align__(16) float Wp[64][12];         // 3 KB

  const int tid = threadIdx.x;
  const int b = blockIdx.x;

  float aL = sigmoidf_(rawL[0]) * 0.15f + 0.85f;
  float aT = sigmoidf_(rawT[0]) * 0.25f + 0.70f;
  float gg = sigmoidf_(rawG[0]) * 0.20f + 0.80f;
  float om = omega[0];
  float gc = gg * cosf(om), gs = gg * sinf(om);   // n2 =  gc*s2 + gs*s3
                                                  // n3 = -gs*s2 + gc*s3
  float aR = sigmoidf_(rawR[0]) * 0.4f;
  float cs = corr_scale[0];
  float bc0 = b_c2[0], bc1 = b_c2[1], bc2v = b_c2[2], bc3 = b_c2[3], bc4 = b_c2[4];

  // stage correction weights: Wp[j] = {W_c1[0..4][j], W_c2[j][0..4]}
  if (tid < 64){
    #pragma unroll
    for (int i = 0; i < 5; ++i) Wp[tid][i]     = W_c1[i * 64 + tid];
    #pragma unroll
    for (int i = 0; i < 5; ++i) Wp[tid][5 + i] = W_c2[tid * 5 + i];
  }

  const float* bxr = bx + (size_t)b * S_ * 8 + (size_t)tid * 64;
  const unsigned short* hpg = hp + (size_t)b * S_ * H_;

  // ---- pass 1 local: 8-step serial prefix within segment ----
  float p[8][5];
  {
    float c0 = 0.f, c1 = 0.f, c2 = 0.f, c3 = 0.f, c4 = 0.f;
    #pragma unroll
    for (int j = 0; j < 8; ++j){
      float4 vb = *(const float4*)&bxr[j * 8];
      float  ve = bxr[j * 8 + 4];
      float n0 = fmaf(c0, aL, vb.x);
      float n1 = fmaf(c1, aT, vb.y);
      float n2 = fmaf(c2, gc, fmaf(c3, gs, vb.z));
      float n3 = fmaf(c2, -gs, fmaf(c3, gc, vb.w));
      float n4 = fmaf(c4, aR, ve);
      c0 = n0; c1 = n1; c2 = n2; c3 = n3; c4 = n4;
      p[j][0] = n0; p[j][1] = n1; p[j][2] = n2; p[j][3] = n3; p[j][4] = n4;
    }
    scanb[0][tid][0] = c0; scanb[0][tid][1] = c1; scanb[0][tid][2] = c2;
    scanb[0][tid][3] = c3; scanb[0][tid][4] = c4;
  }
  __syncthreads();

  // ---- Kogge-Stone over 256 segment aggregates (level-d matrix = A^(8*2^d))
  int bufc = 0;
  {
    float mL = aL, mT = aT, mc = gc, ms = gs, mR = aR;
    #pragma unroll
    for (int q = 0; q < 3; ++q){
      float nc = mc * mc - ms * ms, ns = 2.f * mc * ms;
      mL *= mL; mT *= mT; mR *= mR; mc = nc; ms = ns;
    }
    #pragma unroll
    for (int d = 0; d < 8; ++d){
      const int off = 1 << d;
      float x0 = scanb[bufc][tid][0], x1 = scanb[bufc][tid][1],
            x2 = scanb[bufc][tid][2], x3 = scanb[bufc][tid][3],
            x4 = scanb[bufc][tid][4];
      if (tid >= off){
        const float* pr = &scanb[bufc][tid - off][0];
        float q0 = pr[0], q1 = pr[1], q2 = pr[2], q3 = pr[3], q4 = pr[4];
        x0 = fmaf(q0, mL, x0);
        x1 = fmaf(q1, mT, x1);
        x2 = fmaf(q2, mc, fmaf(q3, ms, x2));
        x3 = fmaf(q2, -ms, fmaf(q3, mc, x3));
        x4 = fmaf(q4, mR, x4);
      }
      scanb[bufc ^ 1][tid][0] = x0; scanb[bufc ^ 1][tid][1] = x1;
      scanb[bufc ^ 1][tid][2] = x2; scanb[bufc ^ 1][tid][3] = x3;
      scanb[bufc ^ 1][tid][4] = x4;
      __syncthreads();
      bufc ^= 1;
      float nc = mc * mc - ms * ms, ns = 2.f * mc * ms;
      mL *= mL; mT *= mT; mR *= mR; mc = nc; ms = ns;
    }
  }

  // ---- exclusive offset + full states: p[j] <- A^{j+1} O + p[j] ----
  {
    float o0 = 0.f, o1 = 0.f, o2 = 0.f, o3 = 0.f, o4 = 0.f;
    if (tid > 0){
      const float* pr = &scanb[bufc][tid - 1][0];
      o0 = pr[0]; o1 = pr[1]; o2 = pr[2]; o3 = pr[3]; o4 = pr[4];
    }
    #pragma unroll
    for (int j = 0; j < 8; ++j){
      float n0 = o0 * aL;
      float n1 = o1 * aT;
      float n2 = fmaf(o2, gc, o3 * gs);
      float n3 = fmaf(o3, gc, -o2 * gs);
      float n4 = o4 * aR;
      o0 = n0; o1 = n1; o2 = n2; o3 = n3; o4 = n4;
      p[j][0] += n0; p[j][1] += n1; p[j][2] += n2; p[j][3] += n3; p[j][4] += n4;
    }
  }

  // ---- c-eval: all tokens in parallel ----
  float acc[8][5];
  #pragma unroll
  for (int j = 0; j < 8; ++j){ acc[j][0]=0.f; acc[j][1]=0.f; acc[j][2]=0.f; acc[j][3]=0.f; acc[j][4]=0.f; }

  #pragma unroll
  for (int ch = 0; ch < 8; ++ch){
    uint4 hpc[8];
    #pragma unroll
    for (int tok = 0; tok < 8; ++tok)
      hpc[tok] = *(const uint4*)&hpg[(size_t)(tid * 8 + tok) * 64 + ch * 8];
    #pragma unroll
    for (int jj = 0; jj < 8; ++jj){
      const float* wr = &Wp[ch * 8 + jj][0];
      float w0 = wr[0], w1 = wr[1], w2 = wr[2], w3 = wr[3], w4 = wr[4];
      float q0 = wr[5], q1 = wr[6], q2 = wr[7], q3 = wr[8], q4 = wr[9];
      #pragma unroll
      for (int tok = 0; tok < 8; ++tok){
        unsigned int word = ((const unsigned int*)&hpc[tok])[jj >> 1];
        unsigned short hu = (jj & 1) ? (unsigned short)(word >> 16)
                                     : (unsigned short)(word & 0xffff);
        float hv = bf2f(hu);
        float up = fmaf(p[tok][0], w0, hv);
        up = fmaf(p[tok][1], w1, up);
        up = fmaf(p[tok][2], w2, up);
        up = fmaf(p[tok][3], w3, up);
        up = fmaf(p[tok][4], w4, up);
        float u = up * rcpf_(1.0f + __expf(-1.702f * up));   // sigmoid-GELU
        acc[tok][0] = fmaf(u, q0, acc[tok][0]);
        acc[tok][1] = fmaf(u, q1, acc[tok][1]);
        acc[tok][2] = fmaf(u, q2, acc[tok][2]);
        acc[tok][3] = fmaf(u, q3, acc[tok][3]);
        acc[tok][4] = fmaf(u, q4, acc[tok][4]);
      }
    }
  }

  // ---- pass 2 local aggregate: v' = bx + c ----
  float a0 = 0.f, a1 = 0.f, a2 = 0.f, a3 = 0.f, a4 = 0.f;
  #pragma unroll
  for (int j = 0; j < 8; ++j){
    float4 vb = *(const float4*)&bxr[j * 8];
    float  ve = bxr[j * 8 + 4];
    float c0v = cs * tanh_pade(acc[j][0] + bc0);
    float c1v = cs * tanh_pade(acc[j][1] + bc1);
    float c2v = cs * tanh_pade(acc[j][2] + bc2v);
    float c3v = cs * tanh_pade(acc[j][3] + bc3);
    float c4v = cs * tanh_pade(acc[j][4] + bc4);
    float v0 = vb.x + c0v, v1 = vb.y + c1v, v2 = vb.z + c2v,
          v3 = vb.w + c3v, v4 = ve + c4v;
    float n0 = fmaf(a0, aL, v0);
    float n1 = fmaf(a1, aT, v1);
    float n2 = fmaf(a2, gc, fmaf(a3, gs, v2));
    float n3 = fmaf(a2, -gs, fmaf(a3, gc, v3));
    float n4 = fmaf(a4, aR, v4);
    a0 = n0; a1 = n1; a2 = n2; a3 = n3; a4 = n4;
  }
  __syncthreads();   // pass-1 scan reads complete before buffer reuse
  scanb[0][tid][0] = a0; scanb[0][tid][1] = a1; scanb[0][tid][2] = a2;
  scanb[0][tid][3] = a3; scanb[0][tid][4] = a4;
  __syncthreads();

  // ---- Kogge-Stone pass 2 (inclusive; thread 255 ends with s_2047) ----
  bufc = 0;
  {
    float mL = aL, mT = aT, mc = gc, ms = gs, mR = aR;
    #pragma unroll
    for (int q = 0; q < 3; ++q){
      float nc = mc * mc - ms * ms, ns = 2.f * mc * ms;
      mL *= mL; mT *= mT; mR *= mR; mc = nc; ms = ns;
    }
    float x0 = 0.f, x1 = 0.f, x2 = 0.f, x3 = 0.f, x4 = 0.f;
    #pragma unroll
    for (int d = 0; d < 8; ++d){
      const int off = 1 << d;
      x0 = scanb[bufc][tid][0]; x1 = scanb[bufc][tid][1];
      x2 = scanb[bufc][tid][2]; x3 = scanb[bufc][tid][3];
      x4 = scanb[bufc][tid][4];
      if (tid >= off){
        const float* pr = &scanb[bufc][tid - off][0];
        float q0 = pr[0], q1 = pr[1], q2 = pr[2], q3 = pr[3], q4 = pr[4];
        x0 = fmaf(q0, mL, x0);
        x1 = fmaf(q1, mT, x1);
        x2 = fmaf(q2, mc, fmaf(q3, ms, x2));
        x3 = fmaf(q2, -ms, fmaf(q3, mc, x3));
        x4 = fmaf(q4, mR, x4);
      }
      scanb[bufc ^ 1][tid][0] = x0; scanb[bufc ^ 1][tid][1] = x1;
      scanb[bufc ^ 1][tid][2] = x2; scanb[bufc ^ 1][tid][3] = x3;
      scanb[bufc ^ 1][tid][4] = x4;
      __syncthreads();
      bufc ^= 1;
      float nc = mc * mc - ms * ms, ns = 2.f * mc * ms;
      mL *= mL; mT *= mT; mR *= mR; mc = nc; ms = ns;
    }
    if (tid == 255){
      float* o = out + b * SD_;
      o[0] = x0; o[1] = x1; o[2] = x2; o[3] = x3; o[4] = x4;
    }
  }
}

// ---------------------------------------------------------------------------
extern "C" void kernel_launch(void* const* d_in, const int* in_sizes, int n_in,
                              void* d_out, int out_size, void* d_ws, size_t ws_size,
                              hipStream_t stream)
{
  const float* x          = (const float*)d_in[0];
  const float* W_in       = (const float*)d_in[1];
  const float* b_in       = (const float*)d_in[2];
  const float* ln_g       = (const float*)d_in[3];
  const float* ln_b       = (const float*)d_in[4];
  const float* W_innov    = (const float*)d_in[5];
  const float* b_innov    = (const float*)d_in[6];
  const float* W_c1       = (const float*)d_in[7];
  const float* b_c1       = (const float*)d_in[8];
  const float* W_c2       = (const float*)d_in[9];
  const float* b_c2       = (const float*)d_in[10];
  const float* corr_scale = (const float*)d_in[11];
  const float* rawL       = (const float*)d_in[12];
  const float* rawT       = (const float*)d_in[13];
  const float* rawG       = (const float*)d_in[14];
  const float* rawR       = (const float*)d_in[15];
  const float* omega      = (const float*)d_in[16];

  unsigned short* hp = (unsigned short*)d_ws;
  float* bx = (float*)((char*)d_ws + (size_t)B_ * S_ * H_ * 2);

  int nblocksA = (B_ * S_) / TOKB;   // 2048
  phaseA<<<nblocksA, 256, 0, stream>>>(x, W_in, b_in, ln_g, ln_b,
                                       W_innov, b_innov, W_c1, b_c1, hp, bx);
  phaseB<<<B_, 256, 0, stream>>>(hp, bx, W_c1, W_c2, b_c2, corr_scale,
                                 rawL, rawT, rawG, rawR, omega, (float*)d_out);
}

// Round 16
// 163.453 us; speedup vs baseline: 2.7430x; 1.0041x over previous
//
#include <hip/hip_runtime.h>
#include <hip/hip_bf16.h>

#define B_   256
#define S_   2048
#define DIN  128
#define H_   64
#define SD_  5
#define TOKB 256   // tokens per phaseA block
#define NIT  4     // tiles per wave in phaseA

typedef __attribute__((ext_vector_type(8))) short short8_t;   // 8 bf16
typedef __attribute__((ext_vector_type(4))) float float4_t;   // MFMA acc

__device__ __forceinline__ float rcpf_(float x){ return __builtin_amdgcn_rcpf(x); }

// exact-erf GELU: gelu(x)=0.5x(1+erf(x/sqrt2)), A&S 7.1.26
__device__ __forceinline__ float geluf(float v){
  const float kInvSqrt2 = 0.70710678118654752440f;
  float z = v * kInvSqrt2;
  float a = fabsf(z);
  float t = rcpf_(fmaf(0.3275911f, a, 1.0f));
  float p = fmaf(fmaf(fmaf(fmaf(1.061405429f, t, -1.453152027f), t, 1.421413741f),
                      t, -0.284496736f), t, 0.254829592f);
  p *= t;
  float e = 1.0f - p * __expf(-z * z);
  float er = copysignf(e, z);
  return 0.5f * v * (1.0f + er);
}

__device__ __forceinline__ float sigmoidf_(float x){
  return rcpf_(1.0f + __expf(-x));
}

// Pade(3,2) tanh with clamp: |err| <= 0.0065 (attenuated x0.01 by corr_scale)
__device__ __forceinline__ float tanh_pade(float x){
  float xc = fminf(fmaxf(x, -4.0f), 4.0f);
  float t = xc * xc;
  float n = xc * (27.0f + t);
  float d = fmaf(9.0f, t, 27.0f);
  return n * rcpf_(d);
}

__device__ __forceinline__ unsigned short f2bf_hw(float f){
  union { __hip_bfloat16 b; unsigned short u; } cv;
  cv.b = __float2bfloat16(f);
  return cv.u;
}
__device__ __forceinline__ float bf2f(unsigned short h){
  return __uint_as_float(((unsigned int)h) << 16);
}

// ---- async global->LDS (dest = wave-uniform base + lane*16) ----
__device__ __forceinline__ void gl_lds16(const void* g, void* l){
  __builtin_amdgcn_global_load_lds(
      (const __attribute__((address_space(1))) void*)g,
      (__attribute__((address_space(3))) void*)l, 16, 0, 0);
}

// ---- DPP helpers (phaseA) ----
template<int CTRL>
__device__ __forceinline__ float dpp_radd(float x){
  int sh = __builtin_amdgcn_update_dpp(0, __float_as_int(x), CTRL, 0xf, 0xf, true);
  return x + __int_as_float(sh);
}
__device__ __forceinline__ float red16(float x){
  x = dpp_radd<0xB1>(x);   // quad_perm xor1
  x = dpp_radd<0x4E>(x);   // quad_perm xor2
  x = dpp_radd<0x124>(x);  // row_ror:4
  x = dpp_radd<0x128>(x);  // row_ror:8
  return x;
}

// ---------------------------------------------------------------------------
// wsetup: precompute all weight fragments once (26 KB) into d_ws.
// Layout (ushort): [0..8191] WfA(16 sets), [8192..12287] WfC(8 sets),
//                  [12288..13311] WfI(2 sets). Values identical to the old
//                  per-block staging (same f2bf_hw).
// ---------------------------------------------------------------------------
__global__ __launch_bounds__(64) void wsetup(
    const float* __restrict__ W_in, const float* __restrict__ W_c1,
    const float* __restrict__ W_innov, unsigned short* __restrict__ wf)
{
  const int l = threadIdx.x;
  #pragma unroll
  for (int p = 0; p < 16; ++p){
    int kc = p >> 2, nc = p & 3;
    unsigned short tmp[8];
    #pragma unroll
    for (int m = 0; m < 8; ++m)
      tmp[m] = f2bf_hw(W_in[(32 * kc + 8 * (l >> 4) + m) * 64 + 16 * nc + (l & 15)]);
    *(uint4*)&wf[p * 512 + l * 8] = *(uint4*)tmp;
  }
  #pragma unroll
  for (int p = 0; p < 8; ++p){
    int kc2 = p >> 2, nc = p & 3;
    unsigned short tmp[8];
    #pragma unroll
    for (int m = 0; m < 8; ++m)
      tmp[m] = f2bf_hw(W_c1[(5 + 32 * kc2 + 8 * (l >> 4) + m) * 64 + 16 * nc + (l & 15)]);
    *(uint4*)&wf[8192 + p * 512 + l * 8] = *(uint4*)tmp;
  }
  #pragma unroll
  for (int p = 0; p < 2; ++p){
    unsigned short tmp[8];
    #pragma unroll
    for (int m = 0; m < 8; ++m)
      tmp[m] = ((l & 15) < 5)
             ? f2bf_hw(W_innov[(32 * p + 8 * (l >> 4) + m) * 5 + (l & 15)])
             : (unsigned short)0;
    *(uint4*)&wf[12288 + p * 512 + l * 8] = *(uint4*)tmp;
  }
}

// ---------------------------------------------------------------------------
// Phase A (MFMA-based; x prefetched one tile ahead; weight frags async-copied
// from the precomputed global image via global_load_lds — no per-block gather)
// ---------------------------------------------------------------------------
__global__ __launch_bounds__(256, 3) void phaseA(
    const float* __restrict__ x, const unsigned short* __restrict__ wf,
    const float* __restrict__ b_in, const float* __restrict__ ln_g,
    const float* __restrict__ ln_b, const float* __restrict__ b_innov,
    const float* __restrict__ b_c1,
    unsigned short* __restrict__ hp_out, float* __restrict__ bx_out)
{
  __shared__ __align__(16) unsigned short Wfs[13312];       // 26 KB contiguous
  __shared__ __align__(16) unsigned short hbuf[4][16][72];  // 9.2 KB

  unsigned short* WfA = Wfs;                 // [16][512]
  unsigned short* WfC = Wfs + 8192;          // [8][512]
  unsigned short* WfI = Wfs + 12288;         // [2][512]

  const int tid  = threadIdx.x;
  const int lane = tid & 63;
  const int w    = tid >> 6;
  const int c16  = lane & 15;
  const int g4   = lane >> 4;
  const long tok0 = (long)blockIdx.x * TOKB;

  // ---- async-copy the 26 KB fragment image (26 x 1KB wave-instructions) ----
  for (int i = w; i < 26; i += 4)
    gl_lds16(wf + i * 512 + lane * 8, (char*)Wfs + (size_t)i * 1024);

  float binv[4], lg[4], lb[4], bc1v[4];
  #pragma unroll
  for (int nc = 0; nc < 4; ++nc){
    binv[nc] = b_in[16 * nc + c16];
    lg[nc]   = ln_g[16 * nc + c16];
    lb[nc]   = ln_b[16 * nc + c16];
    bc1v[nc] = b_c1[16 * nc + c16];
  }
  float binn = (c16 < 5) ? b_innov[c16] : 0.0f;

  // ---- x prefetch: tile 0 into xf[0] ----
  float4 xf[2][8];
  {
    const float* xr = x + (size_t)(tok0 + w * 16 + c16) * DIN;
    #pragma unroll
    for (int kc = 0; kc < 4; ++kc){
      xf[0][2 * kc]     = *(const float4*)(xr + kc * 32 + g4 * 8);
      xf[0][2 * kc + 1] = *(const float4*)(xr + kc * 32 + g4 * 8 + 4);
    }
  }

  asm volatile("s_waitcnt vmcnt(0)" ::: "memory");
  __builtin_amdgcn_sched_barrier(0);
  __syncthreads();

  #pragma unroll
  for (int it = 0; it < NIT; ++it){
    const int cur = it & 1;
    const int nxt = cur ^ 1;
    const long tbg = tok0 + it * 64 + w * 16;

    // issue next tile's loads before this tile's compute
    if (it + 1 < NIT){
      const float* xr = x + (size_t)(tbg + 64 + c16) * DIN;
      #pragma unroll
      for (int kc = 0; kc < 4; ++kc){
        xf[nxt][2 * kc]     = *(const float4*)(xr + kc * 32 + g4 * 8);
        xf[nxt][2 * kc + 1] = *(const float4*)(xr + kc * 32 + g4 * 8 + 4);
      }
    }

    short8_t a1[4];
    #pragma unroll
    for (int kc = 0; kc < 4; ++kc){
      float4 f0 = xf[cur][2 * kc];
      float4 f1 = xf[cur][2 * kc + 1];
      a1[kc][0] = (short)f2bf_hw(f0.x); a1[kc][1] = (short)f2bf_hw(f0.y);
      a1[kc][2] = (short)f2bf_hw(f0.z); a1[kc][3] = (short)f2bf_hw(f0.w);
      a1[kc][4] = (short)f2bf_hw(f1.x); a1[kc][5] = (short)f2bf_hw(f1.y);
      a1[kc][6] = (short)f2bf_hw(f1.z); a1[kc][7] = (short)f2bf_hw(f1.w);
    }

    float4_t acc1[4] = {{0,0,0,0},{0,0,0,0},{0,0,0,0},{0,0,0,0}};
    #pragma unroll
    for (int kc = 0; kc < 4; ++kc){
      #pragma unroll
      for (int nc = 0; nc < 4; ++nc){
        short8_t bf = *(const short8_t*)&WfA[(kc * 4 + nc) * 512 + lane * 8];
        acc1[nc] = __builtin_amdgcn_mfma_f32_16x16x32_bf16(a1[kc], bf, acc1[nc], 0, 0, 0);
      }
    }

    float v[4][4];
    #pragma unroll
    for (int nc = 0; nc < 4; ++nc)
      #pragma unroll
      for (int r = 0; r < 4; ++r)
        v[nc][r] = acc1[nc][r] + binv[nc];

    float mu[4], rstd[4];
    #pragma unroll
    for (int r = 0; r < 4; ++r){
      float vs = (v[0][r] + v[1][r]) + (v[2][r] + v[3][r]);
      float qs = v[0][r] * v[0][r];
      qs = fmaf(v[1][r], v[1][r], qs);
      qs = fmaf(v[2][r], v[2][r], qs);
      qs = fmaf(v[3][r], v[3][r], qs);
      vs = red16(vs);
      qs = red16(qs);
      float m  = vs * (1.0f / 64.0f);
      float va = fmaxf(qs * (1.0f / 64.0f) - m * m, 0.0f);
      mu[r]   = m;
      rstd[r] = rsqrtf(va + 1e-5f);
    }

    #pragma unroll
    for (int nc = 0; nc < 4; ++nc)
      #pragma unroll
      for (int r = 0; r < 4; ++r){
        float hn = fmaf((v[nc][r] - mu[r]) * rstd[r], lg[nc], lb[nc]);
        hbuf[w][4 * g4 + r][16 * nc + c16] = f2bf_hw(geluf(hn));
      }

    short8_t a2[2];
    a2[0] = *(const short8_t*)&hbuf[w][c16][8 * g4];
    a2[1] = *(const short8_t*)&hbuf[w][c16][32 + 8 * g4];

    float4_t acc2[4] = {{0,0,0,0},{0,0,0,0},{0,0,0,0},{0,0,0,0}};
    #pragma unroll
    for (int kc2 = 0; kc2 < 2; ++kc2){
      #pragma unroll
      for (int nc = 0; nc < 4; ++nc){
        short8_t bf = *(const short8_t*)&WfC[(kc2 * 4 + nc) * 512 + lane * 8];
        acc2[nc] = __builtin_amdgcn_mfma_f32_16x16x32_bf16(a2[kc2], bf, acc2[nc], 0, 0, 0);
      }
    }
    float4_t acc3 = {0, 0, 0, 0};
    {
      short8_t bi0 = *(const short8_t*)&WfI[0 * 512 + lane * 8];
      short8_t bi1 = *(const short8_t*)&WfI[1 * 512 + lane * 8];
      acc3 = __builtin_amdgcn_mfma_f32_16x16x32_bf16(a2[0], bi0, acc3, 0, 0, 0);
      acc3 = __builtin_amdgcn_mfma_f32_16x16x32_bf16(a2[1], bi1, acc3, 0, 0, 0);
    }

    if (c16 < 5){
      #pragma unroll
      for (int r = 0; r < 4; ++r)
        bx_out[(size_t)(tbg + 4 * g4 + r) * 8 + c16] = acc3[r] + binn;
    }

    #pragma unroll
    for (int nc = 0; nc < 4; ++nc)
      #pragma unroll
      for (int r = 0; r < 4; ++r)
        hbuf[w][4 * g4 + r][16 * nc + c16] = f2bf_hw(acc2[nc][r] + bc1v[nc]);

    {
      const int tl = lane >> 2, j = lane & 3;
      uint4 v0 = *(const uint4*)&hbuf[w][tl][j * 16];
      uint4 v1 = *(const uint4*)&hbuf[w][tl][j * 16 + 8];
      unsigned short* hg = hp_out + (size_t)(tbg + tl) * 64 + j * 16;
      *(uint4*)hg       = v0;
      *(uint4*)(hg + 8) = v1;
    }
  }
}

// ---------------------------------------------------------------------------
// Phase B (two-pass parallel scan, unchanged from R14/R15)
// ---------------------------------------------------------------------------
__global__ __launch_bounds__(256, 1) void phaseB(
    const unsigned short* __restrict__ hp, const float* __restrict__ bx,
    const float* __restrict__ W_c1, const float* __restrict__ W_c2,
    const float* __restrict__ b_c2, const float* __restrict__ corr_scale,
    const float* __restrict__ rawL, const float* __restrict__ rawT,
    const float* __restrict__ rawG, const float* __restrict__ rawR,
    const float* __restrict__ omega, float* __restrict__ out)
{
  __shared__ __align__(16) float scanb[2][256][6];   // 12 KB
  __shared__ __align__(16) float Wp[64][12];         // 3 KB

  const int tid = threadIdx.x;
  const int b = blockIdx.x;

  float aL = sigmoidf_(rawL[0]) * 0.15f + 0.85f;
  float aT = sigmoidf_(rawT[0]) * 0.25f + 0.70f;
  float gg = sigmoidf_(rawG[0]) * 0.20f + 0.80f;
  float om = omega[0];
  float gc = gg * cosf(om), gs = gg * sinf(om);
  float aR = sigmoidf_(rawR[0]) * 0.4f;
  float cs = corr_scale[0];
  float bc0 = b_c2[0], bc1 = b_c2[1], bc2v = b_c2[2], bc3 = b_c2[3], bc4 = b_c2[4];

  if (tid < 64){
    #pragma unroll
    for (int i = 0; i < 5; ++i) Wp[tid][i]     = W_c1[i * 64 + tid];
    #pragma unroll
    for (int i = 0; i < 5; ++i) Wp[tid][5 + i] = W_c2[tid * 5 + i];
  }

  const float* bxr = bx + (size_t)b * S_ * 8 + (size_t)tid * 64;
  const unsigned short* hpg = hp + (size_t)b * S_ * H_;

  // ---- pass 1 local: 8-step serial prefix within segment ----
  float p[8][5];
  {
    float c0 = 0.f, c1 = 0.f, c2 = 0.f, c3 = 0.f, c4 = 0.f;
    #pragma unroll
    for (int j = 0; j < 8; ++j){
      float4 vb = *(const float4*)&bxr[j * 8];
      float  ve = bxr[j * 8 + 4];
      float n0 = fmaf(c0, aL, vb.x);
      float n1 = fmaf(c1, aT, vb.y);
      float n2 = fmaf(c2, gc, fmaf(c3, gs, vb.z));
      float n3 = fmaf(c2, -gs, fmaf(c3, gc, vb.w));
      float n4 = fmaf(c4, aR, ve);
      c0 = n0; c1 = n1; c2 = n2; c3 = n3; c4 = n4;
      p[j][0] = n0; p[j][1] = n1; p[j][2] = n2; p[j][3] = n3; p[j][4] = n4;
    }
    scanb[0][tid][0] = c0; scanb[0][tid][1] = c1; scanb[0][tid][2] = c2;
    scanb[0][tid][3] = c3; scanb[0][tid][4] = c4;
  }
  __syncthreads();

  // ---- Kogge-Stone over 256 segment aggregates ----
  int bufc = 0;
  {
    float mL = aL, mT = aT, mc = gc, ms = gs, mR = aR;
    #pragma unroll
    for (int q = 0; q < 3; ++q){
      float nc = mc * mc - ms * ms, ns = 2.f * mc * ms;
      mL *= mL; mT *= mT; mR *= mR; mc = nc; ms = ns;
    }
    #pragma unroll
    for (int d = 0; d < 8; ++d){
      const int off = 1 << d;
      float x0 = scanb[bufc][tid][0], x1 = scanb[bufc][tid][1],
            x2 = scanb[bufc][tid][2], x3 = scanb[bufc][tid][3],
            x4 = scanb[bufc][tid][4];
      if (tid >= off){
        const float* pr = &scanb[bufc][tid - off][0];
        float q0 = pr[0], q1 = pr[1], q2 = pr[2], q3 = pr[3], q4 = pr[4];
        x0 = fmaf(q0, mL, x0);
        x1 = fmaf(q1, mT, x1);
        x2 = fmaf(q2, mc, fmaf(q3, ms, x2));
        x3 = fmaf(q2, -ms, fmaf(q3, mc, x3));
        x4 = fmaf(q4, mR, x4);
      }
      scanb[bufc ^ 1][tid][0] = x0; scanb[bufc ^ 1][tid][1] = x1;
      scanb[bufc ^ 1][tid][2] = x2; scanb[bufc ^ 1][tid][3] = x3;
      scanb[bufc ^ 1][tid][4] = x4;
      __syncthreads();
      bufc ^= 1;
      float nc = mc * mc - ms * ms, ns = 2.f * mc * ms;
      mL *= mL; mT *= mT; mR *= mR; mc = nc; ms = ns;
    }
  }

  // ---- exclusive offset + full states ----
  {
    float o0 = 0.f, o1 = 0.f, o2 = 0.f, o3 = 0.f, o4 = 0.f;
    if (tid > 0){
      const float* pr = &scanb[bufc][tid - 1][0];
      o0 = pr[0]; o1 = pr[1]; o2 = pr[2]; o3 = pr[3]; o4 = pr[4];
    }
    #pragma unroll
    for (int j = 0; j < 8; ++j){
      float n0 = o0 * aL;
      float n1 = o1 * aT;
      float n2 = fmaf(o2, gc, o3 * gs);
      float n3 = fmaf(o3, gc, -o2 * gs);
      float n4 = o4 * aR;
      o0 = n0; o1 = n1; o2 = n2; o3 = n3; o4 = n4;
      p[j][0] += n0; p[j][1] += n1; p[j][2] += n2; p[j][3] += n3; p[j][4] += n4;
    }
  }

  // ---- c-eval: all tokens in parallel ----
  float acc[8][5];
  #pragma unroll
  for (int j = 0; j < 8; ++j){ acc[j][0]=0.f; acc[j][1]=0.f; acc[j][2]=0.f; acc[j][3]=0.f; acc[j][4]=0.f; }

  #pragma unroll
  for (int ch = 0; ch < 8; ++ch){
    uint4 hpc[8];
    #pragma unroll
    for (int tok = 0; tok < 8; ++tok)
      hpc[tok] = *(const uint4*)&hpg[(size_t)(tid * 8 + tok) * 64 + ch * 8];
    #pragma unroll
    for (int jj = 0; jj < 8; ++jj){
      const float* wr = &Wp[ch * 8 + jj][0];
      float w0 = wr[0], w1 = wr[1], w2 = wr[2], w3 = wr[3], w4 = wr[4];
      float q0 = wr[5], q1 = wr[6], q2 = wr[7], q3 = wr[8], q4 = wr[9];
      #pragma unroll
      for (int tok = 0; tok < 8; ++tok){
        unsigned int word = ((const unsigned int*)&hpc[tok])[jj >> 1];
        unsigned short hu = (jj & 1) ? (unsigned short)(word >> 16)
                                     : (unsigned short)(word & 0xffff);
        float hv = bf2f(hu);
        float up = fmaf(p[tok][0], w0, hv);
        up = fmaf(p[tok][1], w1, up);
        up = fmaf(p[tok][2], w2, up);
        up = fmaf(p[tok][3], w3, up);
        up = fmaf(p[tok][4], w4, up);
        float u = up * rcpf_(1.0f + __expf(-1.702f * up));
        acc[tok][0] = fmaf(u, q0, acc[tok][0]);
        acc[tok][1] = fmaf(u, q1, acc[tok][1]);
        acc[tok][2] = fmaf(u, q2, acc[tok][2]);
        acc[tok][3] = fmaf(u, q3, acc[tok][3]);
        acc[tok][4] = fmaf(u, q4, acc[tok][4]);
      }
    }
  }

  // ---- pass 2 local aggregate: v' = bx + c ----
  float a0 = 0.f, a1 = 0.f, a2 = 0.f, a3 = 0.f, a4 = 0.f;
  #pragma unroll
  for (int j = 0; j < 8; ++j){
    float4 vb = *(const float4*)&bxr[j * 8];
    float  ve = bxr[j * 8 + 4];
    float c0v = cs * tanh_pade(acc[j][0] + bc0);
    float c1v = cs * tanh_pade(acc[j][1] + bc1);
    float c2v = cs * tanh_pade(acc[j][2] + bc2v);
    float c3v = cs * tanh_pade(acc[j][3] + bc3);
    float c4v = cs * tanh_pade(acc[j][4] + bc4);
    float v0 = vb.x + c0v, v1 = vb.y + c1v, v2 = vb.z + c2v,
          v3 = vb.w + c3v, v4 = ve + c4v;
    float n0 = fmaf(a0, aL, v0);
    float n1 = fmaf(a1, aT, v1);
    float n2 = fmaf(a2, gc, fmaf(a3, gs, v2));
    float n3 = fmaf(a2, -gs, fmaf(a3, gc, v3));
    float n4 = fmaf(a4, aR, v4);
    a0 = n0; a1 = n1; a2 = n2; a3 = n3; a4 = n4;
  }
  __syncthreads();
  scanb[0][tid][0] = a0; scanb[0][tid][1] = a1; scanb[0][tid][2] = a2;
  scanb[0][tid][3] = a3; scanb[0][tid][4] = a4;
  __syncthreads();

  // ---- Kogge-Stone pass 2 (inclusive; thread 255 ends with s_2047) ----
  bufc = 0;
  {
    float mL = aL, mT = aT, mc = gc, ms = gs, mR = aR;
    #pragma unroll
    for (int q = 0; q < 3; ++q){
      float nc = mc * mc - ms * ms, ns = 2.f * mc * ms;
      mL *= mL; mT *= mT; mR *= mR; mc = nc; ms = ns;
    }
    float x0 = 0.f, x1 = 0.f, x2 = 0.f, x3 = 0.f, x4 = 0.f;
    #pragma unroll
    for (int d = 0; d < 8; ++d){
      const int off = 1 << d;
      x0 = scanb[bufc][tid][0]; x1 = scanb[bufc][tid][1];
      x2 = scanb[bufc][tid][2]; x3 = scanb[bufc][tid][3];
      x4 = scanb[bufc][tid][4];
      if (tid >= off){
        const float* pr = &scanb[bufc][tid - off][0];
        float q0 = pr[0], q1 = pr[1], q2 = pr[2], q3 = pr[3], q4 = pr[4];
        x0 = fmaf(q0, mL, x0);
        x1 = fmaf(q1, mT, x1);
        x2 = fmaf(q2, mc, fmaf(q3, ms, x2));
        x3 = fmaf(q2, -ms, fmaf(q3, mc, x3));
        x4 = fmaf(q4, mR, x4);
      }
      scanb[bufc ^ 1][tid][0] = x0; scanb[bufc ^ 1][tid][1] = x1;
      scanb[bufc ^ 1][tid][2] = x2; scanb[bufc ^ 1][tid][3] = x3;
      scanb[bufc ^ 1][tid][4] = x4;
      __syncthreads();
      bufc ^= 1;
      float nc = mc * mc - ms * ms, ns = 2.f * mc * ms;
      mL *= mL; mT *= mT; mR *= mR; mc = nc; ms = ns;
    }
    if (tid == 255){
      float* o = out + b * SD_;
      o[0] = x0; o[1] = x1; o[2] = x2; o[3] = x3; o[4] = x4;
    }
  }
}

// ---------------------------------------------------------------------------
extern "C" void kernel_launch(void* const* d_in, const int* in_sizes, int n_in,
                              void* d_out, int out_size, void* d_ws, size_t ws_size,
                              hipStream_t stream)
{
  const float* x          = (const float*)d_in[0];
  const float* W_in       = (const float*)d_in[1];
  const float* b_in       = (const float*)d_in[2];
  const float* ln_g       = (const float*)d_in[3];
  const float* ln_b       = (const float*)d_in[4];
  const float* W_innov    = (const float*)d_in[5];
  const float* b_innov    = (const float*)d_in[6];
  const float* W_c1       = (const float*)d_in[7];
  const float* b_c1       = (const float*)d_in[8];
  const float* W_c2       = (const float*)d_in[9];
  const float* b_c2       = (const float*)d_in[10];
  const float* corr_scale = (const float*)d_in[11];
  const float* rawL       = (const float*)d_in[12];
  const float* rawT       = (const float*)d_in[13];
  const float* rawG       = (const float*)d_in[14];
  const float* rawR       = (const float*)d_in[15];
  const float* omega      = (const float*)d_in[16];

  unsigned short* hp = (unsigned short*)d_ws;
  float* bx = (float*)((char*)d_ws + (size_t)B_ * S_ * H_ * 2);
  unsigned short* wf = (unsigned short*)((char*)d_ws
                        + (size_t)B_ * S_ * H_ * 2 + (size_t)B_ * S_ * 8 * 4);

  wsetup<<<1, 64, 0, stream>>>(W_in, W_c1, W_innov, wf);
  int nblocksA = (B_ * S_) / TOKB;   // 2048
  phaseA<<<nblocksA, 256, 0, stream>>>(x, wf, b_in, ln_g, ln_b,
                                       b_innov, b_c1, hp, bx);
  phaseB<<<B_, 256, 0, stream>>>(hp, bx, W_c1, W_c2, b_c2, corr_scale,
                                 rawL, rawT, rawG, rawR, omega, (float*)d_out);
}

// Round 17
// 117.250 us; speedup vs baseline: 3.8239x; 1.3941x over previous
//
#include <hip/hip_runtime.h>
#include <hip/hip_bf16.h>

#define B_   256
#define S_   2048
#define DIN  128
#define H_   64
#define SD_  5
#define TOKB 256   // tokens per phaseA block
#define NIT  4     // tiles per wave in phaseA
#define TPB  1024  // phaseB threads per block
#define SEG  2     // tokens per phaseB thread
#define LEV  10    // log2(TPB)

typedef __attribute__((ext_vector_type(8))) short short8_t;   // 8 bf16
typedef __attribute__((ext_vector_type(4))) float float4_t;   // MFMA acc

__device__ __forceinline__ float rcpf_(float x){ return __builtin_amdgcn_rcpf(x); }

// exact-erf GELU: gelu(x)=0.5x(1+erf(x/sqrt2)), A&S 7.1.26
__device__ __forceinline__ float geluf(float v){
  const float kInvSqrt2 = 0.70710678118654752440f;
  float z = v * kInvSqrt2;
  float a = fabsf(z);
  float t = rcpf_(fmaf(0.3275911f, a, 1.0f));
  float p = fmaf(fmaf(fmaf(fmaf(1.061405429f, t, -1.453152027f), t, 1.421413741f),
                      t, -0.284496736f), t, 0.254829592f);
  p *= t;
  float e = 1.0f - p * __expf(-z * z);
  float er = copysignf(e, z);
  return 0.5f * v * (1.0f + er);
}

__device__ __forceinline__ float sigmoidf_(float x){
  return rcpf_(1.0f + __expf(-x));
}

// Pade(3,2) tanh with clamp: |err| <= 0.0065 (attenuated x0.01 by corr_scale)
__device__ __forceinline__ float tanh_pade(float x){
  float xc = fminf(fmaxf(x, -4.0f), 4.0f);
  float t = xc * xc;
  float n = xc * (27.0f + t);
  float d = fmaf(9.0f, t, 27.0f);
  return n * rcpf_(d);
}

__device__ __forceinline__ unsigned short f2bf_hw(float f){
  union { __hip_bfloat16 b; unsigned short u; } cv;
  cv.b = __float2bfloat16(f);
  return cv.u;
}
__device__ __forceinline__ float bf2f(unsigned short h){
  return __uint_as_float(((unsigned int)h) << 16);
}

// ---- async global->LDS (dest = wave-uniform base + lane*16) ----
__device__ __forceinline__ void gl_lds16(const void* g, void* l){
  __builtin_amdgcn_global_load_lds(
      (const __attribute__((address_space(1))) void*)g,
      (__attribute__((address_space(3))) void*)l, 16, 0, 0);
}

// ---- DPP helpers (phaseA) ----
template<int CTRL>
__device__ __forceinline__ float dpp_radd(float x){
  int sh = __builtin_amdgcn_update_dpp(0, __float_as_int(x), CTRL, 0xf, 0xf, true);
  return x + __int_as_float(sh);
}
__device__ __forceinline__ float red16(float x){
  x = dpp_radd<0xB1>(x);   // quad_perm xor1
  x = dpp_radd<0x4E>(x);   // quad_perm xor2
  x = dpp_radd<0x124>(x);  // row_ror:4
  x = dpp_radd<0x128>(x);  // row_ror:8
  return x;
}

// ---------------------------------------------------------------------------
// wsetup: precompute all weight fragments once (26 KB) into d_ws.
// ---------------------------------------------------------------------------
__global__ __launch_bounds__(64) void wsetup(
    const float* __restrict__ W_in, const float* __restrict__ W_c1,
    const float* __restrict__ W_innov, unsigned short* __restrict__ wf)
{
  const int l = threadIdx.x;
  #pragma unroll
  for (int p = 0; p < 16; ++p){
    int kc = p >> 2, nc = p & 3;
    unsigned short tmp[8];
    #pragma unroll
    for (int m = 0; m < 8; ++m)
      tmp[m] = f2bf_hw(W_in[(32 * kc + 8 * (l >> 4) + m) * 64 + 16 * nc + (l & 15)]);
    *(uint4*)&wf[p * 512 + l * 8] = *(uint4*)tmp;
  }
  #pragma unroll
  for (int p = 0; p < 8; ++p){
    int kc2 = p >> 2, nc = p & 3;
    unsigned short tmp[8];
    #pragma unroll
    for (int m = 0; m < 8; ++m)
      tmp[m] = f2bf_hw(W_c1[(5 + 32 * kc2 + 8 * (l >> 4) + m) * 64 + 16 * nc + (l & 15)]);
    *(uint4*)&wf[8192 + p * 512 + l * 8] = *(uint4*)tmp;
  }
  #pragma unroll
  for (int p = 0; p < 2; ++p){
    unsigned short tmp[8];
    #pragma unroll
    for (int m = 0; m < 8; ++m)
      tmp[m] = ((l & 15) < 5)
             ? f2bf_hw(W_innov[(32 * p + 8 * (l >> 4) + m) * 5 + (l & 15)])
             : (unsigned short)0;
    *(uint4*)&wf[12288 + p * 512 + l * 8] = *(uint4*)tmp;
  }
}

// ---------------------------------------------------------------------------
// Phase A (unchanged from R16: MFMA + x-prefetch + async weight-frag copy)
// ---------------------------------------------------------------------------
__global__ __launch_bounds__(256, 3) void phaseA(
    const float* __restrict__ x, const unsigned short* __restrict__ wf,
    const float* __restrict__ b_in, const float* __restrict__ ln_g,
    const float* __restrict__ ln_b, const float* __restrict__ b_innov,
    const float* __restrict__ b_c1,
    unsigned short* __restrict__ hp_out, float* __restrict__ bx_out)
{
  __shared__ __align__(16) unsigned short Wfs[13312];
  __shared__ __align__(16) unsigned short hbuf[4][16][72];

  unsigned short* WfA = Wfs;
  unsigned short* WfC = Wfs + 8192;
  unsigned short* WfI = Wfs + 12288;

  const int tid  = threadIdx.x;
  const int lane = tid & 63;
  const int w    = tid >> 6;
  const int c16  = lane & 15;
  const int g4   = lane >> 4;
  const long tok0 = (long)blockIdx.x * TOKB;

  for (int i = w; i < 26; i += 4)
    gl_lds16(wf + i * 512 + lane * 8, (char*)Wfs + (size_t)i * 1024);

  float binv[4], lg[4], lb[4], bc1v[4];
  #pragma unroll
  for (int nc = 0; nc < 4; ++nc){
    binv[nc] = b_in[16 * nc + c16];
    lg[nc]   = ln_g[16 * nc + c16];
    lb[nc]   = ln_b[16 * nc + c16];
    bc1v[nc] = b_c1[16 * nc + c16];
  }
  float binn = (c16 < 5) ? b_innov[c16] : 0.0f;

  float4 xf[2][8];
  {
    const float* xr = x + (size_t)(tok0 + w * 16 + c16) * DIN;
    #pragma unroll
    for (int kc = 0; kc < 4; ++kc){
      xf[0][2 * kc]     = *(const float4*)(xr + kc * 32 + g4 * 8);
      xf[0][2 * kc + 1] = *(const float4*)(xr + kc * 32 + g4 * 8 + 4);
    }
  }

  asm volatile("s_waitcnt vmcnt(0)" ::: "memory");
  __builtin_amdgcn_sched_barrier(0);
  __syncthreads();

  #pragma unroll
  for (int it = 0; it < NIT; ++it){
    const int cur = it & 1;
    const int nxt = cur ^ 1;
    const long tbg = tok0 + it * 64 + w * 16;

    if (it + 1 < NIT){
      const float* xr = x + (size_t)(tbg + 64 + c16) * DIN;
      #pragma unroll
      for (int kc = 0; kc < 4; ++kc){
        xf[nxt][2 * kc]     = *(const float4*)(xr + kc * 32 + g4 * 8);
        xf[nxt][2 * kc + 1] = *(const float4*)(xr + kc * 32 + g4 * 8 + 4);
      }
    }

    short8_t a1[4];
    #pragma unroll
    for (int kc = 0; kc < 4; ++kc){
      float4 f0 = xf[cur][2 * kc];
      float4 f1 = xf[cur][2 * kc + 1];
      a1[kc][0] = (short)f2bf_hw(f0.x); a1[kc][1] = (short)f2bf_hw(f0.y);
      a1[kc][2] = (short)f2bf_hw(f0.z); a1[kc][3] = (short)f2bf_hw(f0.w);
      a1[kc][4] = (short)f2bf_hw(f1.x); a1[kc][5] = (short)f2bf_hw(f1.y);
      a1[kc][6] = (short)f2bf_hw(f1.z); a1[kc][7] = (short)f2bf_hw(f1.w);
    }

    float4_t acc1[4] = {{0,0,0,0},{0,0,0,0},{0,0,0,0},{0,0,0,0}};
    #pragma unroll
    for (int kc = 0; kc < 4; ++kc){
      #pragma unroll
      for (int nc = 0; nc < 4; ++nc){
        short8_t bf = *(const short8_t*)&WfA[(kc * 4 + nc) * 512 + lane * 8];
        acc1[nc] = __builtin_amdgcn_mfma_f32_16x16x32_bf16(a1[kc], bf, acc1[nc], 0, 0, 0);
      }
    }

    float v[4][4];
    #pragma unroll
    for (int nc = 0; nc < 4; ++nc)
      #pragma unroll
      for (int r = 0; r < 4; ++r)
        v[nc][r] = acc1[nc][r] + binv[nc];

    float mu[4], rstd[4];
    #pragma unroll
    for (int r = 0; r < 4; ++r){
      float vs = (v[0][r] + v[1][r]) + (v[2][r] + v[3][r]);
      float qs = v[0][r] * v[0][r];
      qs = fmaf(v[1][r], v[1][r], qs);
      qs = fmaf(v[2][r], v[2][r], qs);
      qs = fmaf(v[3][r], v[3][r], qs);
      vs = red16(vs);
      qs = red16(qs);
      float m  = vs * (1.0f / 64.0f);
      float va = fmaxf(qs * (1.0f / 64.0f) - m * m, 0.0f);
      mu[r]   = m;
      rstd[r] = rsqrtf(va + 1e-5f);
    }

    #pragma unroll
    for (int nc = 0; nc < 4; ++nc)
      #pragma unroll
      for (int r = 0; r < 4; ++r){
        float hn = fmaf((v[nc][r] - mu[r]) * rstd[r], lg[nc], lb[nc]);
        hbuf[w][4 * g4 + r][16 * nc + c16] = f2bf_hw(geluf(hn));
      }

    short8_t a2[2];
    a2[0] = *(const short8_t*)&hbuf[w][c16][8 * g4];
    a2[1] = *(const short8_t*)&hbuf[w][c16][32 + 8 * g4];

    float4_t acc2[4] = {{0,0,0,0},{0,0,0,0},{0,0,0,0},{0,0,0,0}};
    #pragma unroll
    for (int kc2 = 0; kc2 < 2; ++kc2){
      #pragma unroll
      for (int nc = 0; nc < 4; ++nc){
        short8_t bf = *(const short8_t*)&WfC[(kc2 * 4 + nc) * 512 + lane * 8];
        acc2[nc] = __builtin_amdgcn_mfma_f32_16x16x32_bf16(a2[kc2], bf, acc2[nc], 0, 0, 0);
      }
    }
    float4_t acc3 = {0, 0, 0, 0};
    {
      short8_t bi0 = *(const short8_t*)&WfI[0 * 512 + lane * 8];
      short8_t bi1 = *(const short8_t*)&WfI[1 * 512 + lane * 8];
      acc3 = __builtin_amdgcn_mfma_f32_16x16x32_bf16(a2[0], bi0, acc3, 0, 0, 0);
      acc3 = __builtin_amdgcn_mfma_f32_16x16x32_bf16(a2[1], bi1, acc3, 0, 0, 0);
    }

    if (c16 < 5){
      #pragma unroll
      for (int r = 0; r < 4; ++r)
        bx_out[(size_t)(tbg + 4 * g4 + r) * 8 + c16] = acc3[r] + binn;
    }

    #pragma unroll
    for (int nc = 0; nc < 4; ++nc)
      #pragma unroll
      for (int r = 0; r < 4; ++r)
        hbuf[w][4 * g4 + r][16 * nc + c16] = f2bf_hw(acc2[nc][r] + bc1v[nc]);

    {
      const int tl = lane >> 2, j = lane & 3;
      uint4 v0 = *(const uint4*)&hbuf[w][tl][j * 16];
      uint4 v1 = *(const uint4*)&hbuf[w][tl][j * 16 + 8];
      unsigned short* hg = hp_out + (size_t)(tbg + tl) * 64 + j * 16;
      *(uint4*)hg       = v0;
      *(uint4*)(hg + 8) = v1;
    }
  }
}

// ---------------------------------------------------------------------------
// Phase B (two-pass parallel scan, 1024 threads / 2 tokens per thread):
// 4x the waves per CU vs R14-R16 (16 waves/CU) so the c-eval gelu chains and
// hp streams have real TLP. Same algorithm: pass1 scan of bx under A ->
// states; c-eval all tokens; pass2 aggregate scan of (bx + c) -> s_2047.
// ---------------------------------------------------------------------------
__global__ __launch_bounds__(TPB, 1) void phaseB(
    const unsigned short* __restrict__ hp, const float* __restrict__ bx,
    const float* __restrict__ W_c1, const float* __restrict__ W_c2,
    const float* __restrict__ b_c2, const float* __restrict__ corr_scale,
    const float* __restrict__ rawL, const float* __restrict__ rawT,
    const float* __restrict__ rawG, const float* __restrict__ rawR,
    const float* __restrict__ omega, float* __restrict__ out)
{
  __shared__ __align__(16) float scanb[2][TPB][6];   // 48 KB
  __shared__ __align__(16) float Wp[64][12];         // 3 KB

  const int tid = threadIdx.x;
  const int b = blockIdx.x;

  float aL = sigmoidf_(rawL[0]) * 0.15f + 0.85f;
  float aT = sigmoidf_(rawT[0]) * 0.25f + 0.70f;
  float gg = sigmoidf_(rawG[0]) * 0.20f + 0.80f;
  float om = omega[0];
  float gc = gg * cosf(om), gs = gg * sinf(om);
  float aR = sigmoidf_(rawR[0]) * 0.4f;
  float cs = corr_scale[0];
  float bc0 = b_c2[0], bc1 = b_c2[1], bc2v = b_c2[2], bc3 = b_c2[3], bc4 = b_c2[4];

  if (tid < 64){
    #pragma unroll
    for (int i = 0; i < 5; ++i) Wp[tid][i]     = W_c1[i * 64 + tid];
    #pragma unroll
    for (int i = 0; i < 5; ++i) Wp[tid][5 + i] = W_c2[tid * 5 + i];
  }

  const float* bxr = bx + (size_t)b * S_ * 8 + (size_t)tid * (SEG * 8);
  const unsigned short* hpg = hp + (size_t)b * S_ * H_;

  // ---- pass 1 local: SEG-step serial prefix within segment ----
  float p[SEG][5];
  {
    float c0 = 0.f, c1 = 0.f, c2 = 0.f, c3 = 0.f, c4 = 0.f;
    #pragma unroll
    for (int j = 0; j < SEG; ++j){
      float4 vb = *(const float4*)&bxr[j * 8];
      float  ve = bxr[j * 8 + 4];
      float n0 = fmaf(c0, aL, vb.x);
      float n1 = fmaf(c1, aT, vb.y);
      float n2 = fmaf(c2, gc, fmaf(c3, gs, vb.z));
      float n3 = fmaf(c2, -gs, fmaf(c3, gc, vb.w));
      float n4 = fmaf(c4, aR, ve);
      c0 = n0; c1 = n1; c2 = n2; c3 = n3; c4 = n4;
      p[j][0] = n0; p[j][1] = n1; p[j][2] = n2; p[j][3] = n3; p[j][4] = n4;
    }
    scanb[0][tid][0] = c0; scanb[0][tid][1] = c1; scanb[0][tid][2] = c2;
    scanb[0][tid][3] = c3; scanb[0][tid][4] = c4;
  }
  __syncthreads();

  // ---- Kogge-Stone over TPB segment aggregates (level-d matrix = A^(SEG*2^d))
  int bufc = 0;
  {
    float mL = aL, mT = aT, mc = gc, ms = gs, mR = aR;
    // A^SEG (SEG=2 -> one squaring)
    {
      float nc = mc * mc - ms * ms, ns = 2.f * mc * ms;
      mL *= mL; mT *= mT; mR *= mR; mc = nc; ms = ns;
    }
    #pragma unroll
    for (int d = 0; d < LEV; ++d){
      const int off = 1 << d;
      float x0 = scanb[bufc][tid][0], x1 = scanb[bufc][tid][1],
            x2 = scanb[bufc][tid][2], x3 = scanb[bufc][tid][3],
            x4 = scanb[bufc][tid][4];
      if (tid >= off){
        const float* pr = &scanb[bufc][tid - off][0];
        float q0 = pr[0], q1 = pr[1], q2 = pr[2], q3 = pr[3], q4 = pr[4];
        x0 = fmaf(q0, mL, x0);
        x1 = fmaf(q1, mT, x1);
        x2 = fmaf(q2, mc, fmaf(q3, ms, x2));
        x3 = fmaf(q2, -ms, fmaf(q3, mc, x3));
        x4 = fmaf(q4, mR, x4);
      }
      scanb[bufc ^ 1][tid][0] = x0; scanb[bufc ^ 1][tid][1] = x1;
      scanb[bufc ^ 1][tid][2] = x2; scanb[bufc ^ 1][tid][3] = x3;
      scanb[bufc ^ 1][tid][4] = x4;
      __syncthreads();
      bufc ^= 1;
      float nc = mc * mc - ms * ms, ns = 2.f * mc * ms;
      mL *= mL; mT *= mT; mR *= mR; mc = nc; ms = ns;
    }
  }

  // ---- exclusive offset + full states: p[j] <- A^{j+1} O + p[j] ----
  {
    float o0 = 0.f, o1 = 0.f, o2 = 0.f, o3 = 0.f, o4 = 0.f;
    if (tid > 0){
      const float* pr = &scanb[bufc][tid - 1][0];
      o0 = pr[0]; o1 = pr[1]; o2 = pr[2]; o3 = pr[3]; o4 = pr[4];
    }
    #pragma unroll
    for (int j = 0; j < SEG; ++j){
      float n0 = o0 * aL;
      float n1 = o1 * aT;
      float n2 = fmaf(o2, gc, o3 * gs);
      float n3 = fmaf(o3, gc, -o2 * gs);
      float n4 = o4 * aR;
      o0 = n0; o1 = n1; o2 = n2; o3 = n3; o4 = n4;
      p[j][0] += n0; p[j][1] += n1; p[j][2] += n2; p[j][3] += n3; p[j][4] += n4;
    }
  }

  // ---- c-eval: all tokens in parallel ----
  float acc[SEG][5];
  #pragma unroll
  for (int j = 0; j < SEG; ++j){
    acc[j][0]=0.f; acc[j][1]=0.f; acc[j][2]=0.f; acc[j][3]=0.f; acc[j][4]=0.f;
  }

  #pragma unroll
  for (int ch = 0; ch < 8; ++ch){
    uint4 hpc[SEG];
    #pragma unroll
    for (int tok = 0; tok < SEG; ++tok)
      hpc[tok] = *(const uint4*)&hpg[(size_t)(tid * SEG + tok) * 64 + ch * 8];
    #pragma unroll
    for (int jj = 0; jj < 8; ++jj){
      const float* wr = &Wp[ch * 8 + jj][0];
      float w0 = wr[0], w1 = wr[1], w2 = wr[2], w3 = wr[3], w4 = wr[4];
      float q0 = wr[5], q1 = wr[6], q2 = wr[7], q3 = wr[8], q4 = wr[9];
      #pragma unroll
      for (int tok = 0; tok < SEG; ++tok){
        unsigned int word = ((const unsigned int*)&hpc[tok])[jj >> 1];
        unsigned short hu = (jj & 1) ? (unsigned short)(word >> 16)
                                     : (unsigned short)(word & 0xffff);
        float hv = bf2f(hu);
        float up = fmaf(p[tok][0], w0, hv);
        up = fmaf(p[tok][1], w1, up);
        up = fmaf(p[tok][2], w2, up);
        up = fmaf(p[tok][3], w3, up);
        up = fmaf(p[tok][4], w4, up);
        float u = up * rcpf_(1.0f + __expf(-1.702f * up));   // sigmoid-GELU
        acc[tok][0] = fmaf(u, q0, acc[tok][0]);
        acc[tok][1] = fmaf(u, q1, acc[tok][1]);
        acc[tok][2] = fmaf(u, q2, acc[tok][2]);
        acc[tok][3] = fmaf(u, q3, acc[tok][3]);
        acc[tok][4] = fmaf(u, q4, acc[tok][4]);
      }
    }
  }

  // ---- pass 2 local aggregate: v' = bx + c ----
  float a0 = 0.f, a1 = 0.f, a2 = 0.f, a3 = 0.f, a4 = 0.f;
  #pragma unroll
  for (int j = 0; j < SEG; ++j){
    float4 vb = *(const float4*)&bxr[j * 8];
    float  ve = bxr[j * 8 + 4];
    float c0v = cs * tanh_pade(acc[j][0] + bc0);
    float c1v = cs * tanh_pade(acc[j][1] + bc1);
    float c2v = cs * tanh_pade(acc[j][2] + bc2v);
    float c3v = cs * tanh_pade(acc[j][3] + bc3);
    float c4v = cs * tanh_pade(acc[j][4] + bc4);
    float v0 = vb.x + c0v, v1 = vb.y + c1v, v2 = vb.z + c2v,
          v3 = vb.w + c3v, v4 = ve + c4v;
    float n0 = fmaf(a0, aL, v0);
    float n1 = fmaf(a1, aT, v1);
    float n2 = fmaf(a2, gc, fmaf(a3, gs, v2));
    float n3 = fmaf(a2, -gs, fmaf(a3, gc, v3));
    float n4 = fmaf(a4, aR, v4);
    a0 = n0; a1 = n1; a2 = n2; a3 = n3; a4 = n4;
  }
  __syncthreads();   // pass-1 scan reads complete before buffer reuse
  scanb[0][tid][0] = a0; scanb[0][tid][1] = a1; scanb[0][tid][2] = a2;
  scanb[0][tid][3] = a3; scanb[0][tid][4] = a4;
  __syncthreads();

  // ---- Kogge-Stone pass 2 (inclusive; thread TPB-1 ends with s_2047) ----
  bufc = 0;
  {
    float mL = aL, mT = aT, mc = gc, ms = gs, mR = aR;
    {
      float nc = mc * mc - ms * ms, ns = 2.f * mc * ms;
      mL *= mL; mT *= mT; mR *= mR; mc = nc; ms = ns;
    }
    float x0 = 0.f, x1 = 0.f, x2 = 0.f, x3 = 0.f, x4 = 0.f;
    #pragma unroll
    for (int d = 0; d < LEV; ++d){
      const int off = 1 << d;
      x0 = scanb[bufc][tid][0]; x1 = scanb[bufc][tid][1];
      x2 = scanb[bufc][tid][2]; x3 = scanb[bufc][tid][3];
      x4 = scanb[bufc][tid][4];
      if (tid >= off){
        const float* pr = &scanb[bufc][tid - off][0];
        float q0 = pr[0], q1 = pr[1], q2 = pr[2], q3 = pr[3], q4 = pr[4];
        x0 = fmaf(q0, mL, x0);
        x1 = fmaf(q1, mT, x1);
        x2 = fmaf(q2, mc, fmaf(q3, ms, x2));
        x3 = fmaf(q2, -ms, fmaf(q3, mc, x3));
        x4 = fmaf(q4, mR, x4);
      }
      scanb[bufc ^ 1][tid][0] = x0; scanb[bufc ^ 1][tid][1] = x1;
      scanb[bufc ^ 1][tid][2] = x2; scanb[bufc ^ 1][tid][3] = x3;
      scanb[bufc ^ 1][tid][4] = x4;
      __syncthreads();
      bufc ^= 1;
      float nc = mc * mc - ms * ms, ns = 2.f * mc * ms;
      mL *= mL; mT *= mT; mR *= mR; mc = nc; ms = ns;
    }
    if (tid == TPB - 1){
      float* o = out + b * SD_;
      o[0] = x0; o[1] = x1; o[2] = x2; o[3] = x3; o[4] = x4;
    }
  }
}

// ---------------------------------------------------------------------------
extern "C" void kernel_launch(void* const* d_in, const int* in_sizes, int n_in,
                              void* d_out, int out_size, void* d_ws, size_t ws_size,
                              hipStream_t stream)
{
  const float* x          = (const float*)d_in[0];
  const float* W_in       = (const float*)d_in[1];
  const float* b_in       = (const float*)d_in[2];
  const float* ln_g       = (const float*)d_in[3];
  const float* ln_b       = (const float*)d_in[4];
  const float* W_innov    = (const float*)d_in[5];
  const float* b_innov    = (const float*)d_in[6];
  const float* W_c1       = (const float*)d_in[7];
  const float* b_c1       = (const float*)d_in[8];
  const float* W_c2       = (const float*)d_in[9];
  const float* b_c2       = (const float*)d_in[10];
  const float* corr_scale = (const float*)d_in[11];
  const float* rawL       = (const float*)d_in[12];
  const float* rawT       = (const float*)d_in[13];
  const float* rawG       = (const float*)d_in[14];
  const float* rawR       = (const float*)d_in[15];
  const float* omega      = (const float*)d_in[16];

  unsigned short* hp = (unsigned short*)d_ws;
  float* bx = (float*)((char*)d_ws + (size_t)B_ * S_ * H_ * 2);
  unsigned short* wf = (unsigned short*)((char*)d_ws
                        + (size_t)B_ * S_ * H_ * 2 + (size_t)B_ * S_ * 8 * 4);

  wsetup<<<1, 64, 0, stream>>>(W_in, W_c1, W_innov, wf);
  int nblocksA = (B_ * S_) / TOKB;   // 2048
  phaseA<<<nblocksA, 256, 0, stream>>>(x, wf, b_in, ln_g, ln_b,
                                       b_innov, b_c1, hp, bx);
  phaseB<<<B_, TPB, 0, stream>>>(hp, bx, W_c1, W_c2, b_c2, corr_scale,
                                 rawL, rawT, rawG, rawR, omega, (float*)d_out);
}

// Round 18
// 111.372 us; speedup vs baseline: 4.0258x; 1.0528x over previous
//
#include <hip/hip_runtime.h>
#include <hip/hip_bf16.h>

#define B_   256
#define S_   2048
#define DIN  128
#define H_   64
#define SD_  5
#define TOKB 256   // tokens per phaseA block
#define NIT  4     // tiles per wave in phaseA
#define TPB  1024  // phaseB threads per block
#define SEG  2     // tokens per phaseB thread
#define LEV  10    // log2(TPB)

typedef __attribute__((ext_vector_type(8))) short short8_t;   // 8 bf16
typedef __attribute__((ext_vector_type(4))) float float4_t;   // MFMA acc

__device__ __forceinline__ float rcpf_(float x){ return __builtin_amdgcn_rcpf(x); }

// exact-erf GELU: gelu(x)=0.5x(1+erf(x/sqrt2)), A&S 7.1.26
__device__ __forceinline__ float geluf(float v){
  const float kInvSqrt2 = 0.70710678118654752440f;
  float z = v * kInvSqrt2;
  float a = fabsf(z);
  float t = rcpf_(fmaf(0.3275911f, a, 1.0f));
  float p = fmaf(fmaf(fmaf(fmaf(1.061405429f, t, -1.453152027f), t, 1.421413741f),
                      t, -0.284496736f), t, 0.254829592f);
  p *= t;
  float e = 1.0f - p * __expf(-z * z);
  float er = copysignf(e, z);
  return 0.5f * v * (1.0f + er);
}

__device__ __forceinline__ float sigmoidf_(float x){
  return rcpf_(1.0f + __expf(-x));
}

// Pade(3,2) tanh with clamp: |err| <= 0.0065 (attenuated x0.01 by corr_scale)
__device__ __forceinline__ float tanh_pade(float x){
  float xc = fminf(fmaxf(x, -4.0f), 4.0f);
  float t = xc * xc;
  float n = xc * (27.0f + t);
  float d = fmaf(9.0f, t, 27.0f);
  return n * rcpf_(d);
}

__device__ __forceinline__ unsigned short f2bf_hw(float f){
  union { __hip_bfloat16 b; unsigned short u; } cv;
  cv.b = __float2bfloat16(f);
  return cv.u;
}
__device__ __forceinline__ float bf2f(unsigned short h){
  return __uint_as_float(((unsigned int)h) << 16);
}

// ---- async global->LDS (dest = wave-uniform base + lane*16) ----
__device__ __forceinline__ void gl_lds16(const void* g, void* l){
  __builtin_amdgcn_global_load_lds(
      (const __attribute__((address_space(1))) void*)g,
      (__attribute__((address_space(3))) void*)l, 16, 0, 0);
}

// ---- DPP helpers (phaseA) ----
template<int CTRL>
__device__ __forceinline__ float dpp_radd(float x){
  int sh = __builtin_amdgcn_update_dpp(0, __float_as_int(x), CTRL, 0xf, 0xf, true);
  return x + __int_as_float(sh);
}
__device__ __forceinline__ float red16(float x){
  x = dpp_radd<0xB1>(x);   // quad_perm xor1
  x = dpp_radd<0x4E>(x);   // quad_perm xor2
  x = dpp_radd<0x124>(x);  // row_ror:4
  x = dpp_radd<0x128>(x);  // row_ror:8
  return x;
}

// ---------------------------------------------------------------------------
// wsetup: precompute all weight fragments once (26 KB) into d_ws.
// ---------------------------------------------------------------------------
__global__ __launch_bounds__(64) void wsetup(
    const float* __restrict__ W_in, const float* __restrict__ W_c1,
    const float* __restrict__ W_innov, unsigned short* __restrict__ wf)
{
  const int l = threadIdx.x;
  #pragma unroll
  for (int p = 0; p < 16; ++p){
    int kc = p >> 2, nc = p & 3;
    unsigned short tmp[8];
    #pragma unroll
    for (int m = 0; m < 8; ++m)
      tmp[m] = f2bf_hw(W_in[(32 * kc + 8 * (l >> 4) + m) * 64 + 16 * nc + (l & 15)]);
    *(uint4*)&wf[p * 512 + l * 8] = *(uint4*)tmp;
  }
  #pragma unroll
  for (int p = 0; p < 8; ++p){
    int kc2 = p >> 2, nc = p & 3;
    unsigned short tmp[8];
    #pragma unroll
    for (int m = 0; m < 8; ++m)
      tmp[m] = f2bf_hw(W_c1[(5 + 32 * kc2 + 8 * (l >> 4) + m) * 64 + 16 * nc + (l & 15)]);
    *(uint4*)&wf[8192 + p * 512 + l * 8] = *(uint4*)tmp;
  }
  #pragma unroll
  for (int p = 0; p < 2; ++p){
    unsigned short tmp[8];
    #pragma unroll
    for (int m = 0; m < 8; ++m)
      tmp[m] = ((l & 15) < 5)
             ? f2bf_hw(W_innov[(32 * p + 8 * (l >> 4) + m) * 5 + (l & 15)])
             : (unsigned short)0;
    *(uint4*)&wf[12288 + p * 512 + l * 8] = *(uint4*)tmp;
  }
}

// ---------------------------------------------------------------------------
// Phase A: MFMA + x-prefetch + async weight-frag copy. hp now written in
// channel-group-major layout hp2[b][ch8][tok][8] so phaseB reads coalesce.
// ---------------------------------------------------------------------------
__global__ __launch_bounds__(256, 3) void phaseA(
    const float* __restrict__ x, const unsigned short* __restrict__ wf,
    const float* __restrict__ b_in, const float* __restrict__ ln_g,
    const float* __restrict__ ln_b, const float* __restrict__ b_innov,
    const float* __restrict__ b_c1,
    unsigned short* __restrict__ hp_out, float* __restrict__ bx_out)
{
  __shared__ __align__(16) unsigned short Wfs[13312];
  __shared__ __align__(16) unsigned short hbuf[4][16][72];

  unsigned short* WfA = Wfs;
  unsigned short* WfC = Wfs + 8192;
  unsigned short* WfI = Wfs + 12288;

  const int tid  = threadIdx.x;
  const int lane = tid & 63;
  const int w    = tid >> 6;
  const int c16  = lane & 15;
  const int g4   = lane >> 4;
  const long tok0 = (long)blockIdx.x * TOKB;

  for (int i = w; i < 26; i += 4)
    gl_lds16(wf + i * 512 + lane * 8, (char*)Wfs + (size_t)i * 1024);

  float binv[4], lg[4], lb[4], bc1v[4];
  #pragma unroll
  for (int nc = 0; nc < 4; ++nc){
    binv[nc] = b_in[16 * nc + c16];
    lg[nc]   = ln_g[16 * nc + c16];
    lb[nc]   = ln_b[16 * nc + c16];
    bc1v[nc] = b_c1[16 * nc + c16];
  }
  float binn = (c16 < 5) ? b_innov[c16] : 0.0f;

  float4 xf[2][8];
  {
    const float* xr = x + (size_t)(tok0 + w * 16 + c16) * DIN;
    #pragma unroll
    for (int kc = 0; kc < 4; ++kc){
      xf[0][2 * kc]     = *(const float4*)(xr + kc * 32 + g4 * 8);
      xf[0][2 * kc + 1] = *(const float4*)(xr + kc * 32 + g4 * 8 + 4);
    }
  }

  asm volatile("s_waitcnt vmcnt(0)" ::: "memory");
  __builtin_amdgcn_sched_barrier(0);
  __syncthreads();

  #pragma unroll
  for (int it = 0; it < NIT; ++it){
    const int cur = it & 1;
    const int nxt = cur ^ 1;
    const long tbg = tok0 + it * 64 + w * 16;

    if (it + 1 < NIT){
      const float* xr = x + (size_t)(tbg + 64 + c16) * DIN;
      #pragma unroll
      for (int kc = 0; kc < 4; ++kc){
        xf[nxt][2 * kc]     = *(const float4*)(xr + kc * 32 + g4 * 8);
        xf[nxt][2 * kc + 1] = *(const float4*)(xr + kc * 32 + g4 * 8 + 4);
      }
    }

    short8_t a1[4];
    #pragma unroll
    for (int kc = 0; kc < 4; ++kc){
      float4 f0 = xf[cur][2 * kc];
      float4 f1 = xf[cur][2 * kc + 1];
      a1[kc][0] = (short)f2bf_hw(f0.x); a1[kc][1] = (short)f2bf_hw(f0.y);
      a1[kc][2] = (short)f2bf_hw(f0.z); a1[kc][3] = (short)f2bf_hw(f0.w);
      a1[kc][4] = (short)f2bf_hw(f1.x); a1[kc][5] = (short)f2bf_hw(f1.y);
      a1[kc][6] = (short)f2bf_hw(f1.z); a1[kc][7] = (short)f2bf_hw(f1.w);
    }

    float4_t acc1[4] = {{0,0,0,0},{0,0,0,0},{0,0,0,0},{0,0,0,0}};
    #pragma unroll
    for (int kc = 0; kc < 4; ++kc){
      #pragma unroll
      for (int nc = 0; nc < 4; ++nc){
        short8_t bf = *(const short8_t*)&WfA[(kc * 4 + nc) * 512 + lane * 8];
        acc1[nc] = __builtin_amdgcn_mfma_f32_16x16x32_bf16(a1[kc], bf, acc1[nc], 0, 0, 0);
      }
    }

    float v[4][4];
    #pragma unroll
    for (int nc = 0; nc < 4; ++nc)
      #pragma unroll
      for (int r = 0; r < 4; ++r)
        v[nc][r] = acc1[nc][r] + binv[nc];

    float mu[4], rstd[4];
    #pragma unroll
    for (int r = 0; r < 4; ++r){
      float vs = (v[0][r] + v[1][r]) + (v[2][r] + v[3][r]);
      float qs = v[0][r] * v[0][r];
      qs = fmaf(v[1][r], v[1][r], qs);
      qs = fmaf(v[2][r], v[2][r], qs);
      qs = fmaf(v[3][r], v[3][r], qs);
      vs = red16(vs);
      qs = red16(qs);
      float m  = vs * (1.0f / 64.0f);
      float va = fmaxf(qs * (1.0f / 64.0f) - m * m, 0.0f);
      mu[r]   = m;
      rstd[r] = rsqrtf(va + 1e-5f);
    }

    #pragma unroll
    for (int nc = 0; nc < 4; ++nc)
      #pragma unroll
      for (int r = 0; r < 4; ++r){
        float hn = fmaf((v[nc][r] - mu[r]) * rstd[r], lg[nc], lb[nc]);
        hbuf[w][4 * g4 + r][16 * nc + c16] = f2bf_hw(geluf(hn));
      }

    short8_t a2[2];
    a2[0] = *(const short8_t*)&hbuf[w][c16][8 * g4];
    a2[1] = *(const short8_t*)&hbuf[w][c16][32 + 8 * g4];

    float4_t acc2[4] = {{0,0,0,0},{0,0,0,0},{0,0,0,0},{0,0,0,0}};
    #pragma unroll
    for (int kc2 = 0; kc2 < 2; ++kc2){
      #pragma unroll
      for (int nc = 0; nc < 4; ++nc){
        short8_t bf = *(const short8_t*)&WfC[(kc2 * 4 + nc) * 512 + lane * 8];
        acc2[nc] = __builtin_amdgcn_mfma_f32_16x16x32_bf16(a2[kc2], bf, acc2[nc], 0, 0, 0);
      }
    }
    float4_t acc3 = {0, 0, 0, 0};
    {
      short8_t bi0 = *(const short8_t*)&WfI[0 * 512 + lane * 8];
      short8_t bi1 = *(const short8_t*)&WfI[1 * 512 + lane * 8];
      acc3 = __builtin_amdgcn_mfma_f32_16x16x32_bf16(a2[0], bi0, acc3, 0, 0, 0);
      acc3 = __builtin_amdgcn_mfma_f32_16x16x32_bf16(a2[1], bi1, acc3, 0, 0, 0);
    }

    if (c16 < 5){
      #pragma unroll
      for (int r = 0; r < 4; ++r)
        bx_out[(size_t)(tbg + 4 * g4 + r) * 8 + c16] = acc3[r] + binn;
    }

    #pragma unroll
    for (int nc = 0; nc < 4; ++nc)
      #pragma unroll
      for (int r = 0; r < 4; ++r)
        hbuf[w][4 * g4 + r][16 * nc + c16] = f2bf_hw(acc2[nc][r] + bc1v[nc]);

    {
      // hp2[b][ch8][tok][8]: lanes 0..15 = tokens (contiguous 256B segments)
      const int tl = lane & 15, jj = lane >> 4;   // token-in-tile, ch8-pair
      uint4 v0 = *(const uint4*)&hbuf[w][tl][jj * 16];
      uint4 v1 = *(const uint4*)&hbuf[w][tl][jj * 16 + 8];
      const long gt  = tbg + tl;          // global token
      const long bb  = gt >> 11;          // batch row
      const long tlc = gt & (S_ - 1);     // token within row
      unsigned short* hg = hp_out + (((bb * 8 + 2 * jj) * (long)S_ + tlc) * 8);
      *(uint4*)hg            = v0;        // ch8 = 2*jj
      *(uint4*)(hg + S_ * 8) = v1;        // ch8 = 2*jj+1
    }
  }
}

// ---------------------------------------------------------------------------
// Phase B (two-pass parallel scan, 1024 threads / 2 tokens per thread).
// hp reads now coalesced via the channel-group-major layout.
// ---------------------------------------------------------------------------
__global__ __launch_bounds__(TPB, 1) void phaseB(
    const unsigned short* __restrict__ hp, const float* __restrict__ bx,
    const float* __restrict__ W_c1, const float* __restrict__ W_c2,
    const float* __restrict__ b_c2, const float* __restrict__ corr_scale,
    const float* __restrict__ rawL, const float* __restrict__ rawT,
    const float* __restrict__ rawG, const float* __restrict__ rawR,
    const float* __restrict__ omega, float* __restrict__ out)
{
  __shared__ __align__(16) float scanb[2][TPB][6];   // 48 KB
  __shared__ __align__(16) float Wp[64][12];         // 3 KB

  const int tid = threadIdx.x;
  const int b = blockIdx.x;

  float aL = sigmoidf_(rawL[0]) * 0.15f + 0.85f;
  float aT = sigmoidf_(rawT[0]) * 0.25f + 0.70f;
  float gg = sigmoidf_(rawG[0]) * 0.20f + 0.80f;
  float om = omega[0];
  float gc = gg * cosf(om), gs = gg * sinf(om);
  float aR = sigmoidf_(rawR[0]) * 0.4f;
  float cs = corr_scale[0];
  float bc0 = b_c2[0], bc1 = b_c2[1], bc2v = b_c2[2], bc3 = b_c2[3], bc4 = b_c2[4];

  if (tid < 64){
    #pragma unroll
    for (int i = 0; i < 5; ++i) Wp[tid][i]     = W_c1[i * 64 + tid];
    #pragma unroll
    for (int i = 0; i < 5; ++i) Wp[tid][5 + i] = W_c2[tid * 5 + i];
  }

  const float* bxr = bx + (size_t)b * S_ * 8 + (size_t)tid * (SEG * 8);
  const unsigned short* hpg = hp + (size_t)b * S_ * H_;   // = b*8*S*8

  // ---- pass 1 local: SEG-step serial prefix within segment ----
  float p[SEG][5];
  {
    float c0 = 0.f, c1 = 0.f, c2 = 0.f, c3 = 0.f, c4 = 0.f;
    #pragma unroll
    for (int j = 0; j < SEG; ++j){
      float4 vb = *(const float4*)&bxr[j * 8];
      float  ve = bxr[j * 8 + 4];
      float n0 = fmaf(c0, aL, vb.x);
      float n1 = fmaf(c1, aT, vb.y);
      float n2 = fmaf(c2, gc, fmaf(c3, gs, vb.z));
      float n3 = fmaf(c2, -gs, fmaf(c3, gc, vb.w));
      float n4 = fmaf(c4, aR, ve);
      c0 = n0; c1 = n1; c2 = n2; c3 = n3; c4 = n4;
      p[j][0] = n0; p[j][1] = n1; p[j][2] = n2; p[j][3] = n3; p[j][4] = n4;
    }
    scanb[0][tid][0] = c0; scanb[0][tid][1] = c1; scanb[0][tid][2] = c2;
    scanb[0][tid][3] = c3; scanb[0][tid][4] = c4;
  }
  __syncthreads();

  // ---- Kogge-Stone over TPB segment aggregates ----
  int bufc = 0;
  {
    float mL = aL, mT = aT, mc = gc, ms = gs, mR = aR;
    {
      float nc = mc * mc - ms * ms, ns = 2.f * mc * ms;
      mL *= mL; mT *= mT; mR *= mR; mc = nc; ms = ns;
    }
    #pragma unroll
    for (int d = 0; d < LEV; ++d){
      const int off = 1 << d;
      float x0 = scanb[bufc][tid][0], x1 = scanb[bufc][tid][1],
            x2 = scanb[bufc][tid][2], x3 = scanb[bufc][tid][3],
            x4 = scanb[bufc][tid][4];
      if (tid >= off){
        const float* pr = &scanb[bufc][tid - off][0];
        float q0 = pr[0], q1 = pr[1], q2 = pr[2], q3 = pr[3], q4 = pr[4];
        x0 = fmaf(q0, mL, x0);
        x1 = fmaf(q1, mT, x1);
        x2 = fmaf(q2, mc, fmaf(q3, ms, x2));
        x3 = fmaf(q2, -ms, fmaf(q3, mc, x3));
        x4 = fmaf(q4, mR, x4);
      }
      scanb[bufc ^ 1][tid][0] = x0; scanb[bufc ^ 1][tid][1] = x1;
      scanb[bufc ^ 1][tid][2] = x2; scanb[bufc ^ 1][tid][3] = x3;
      scanb[bufc ^ 1][tid][4] = x4;
      __syncthreads();
      bufc ^= 1;
      float nc = mc * mc - ms * ms, ns = 2.f * mc * ms;
      mL *= mL; mT *= mT; mR *= mR; mc = nc; ms = ns;
    }
  }

  // ---- exclusive offset + full states ----
  {
    float o0 = 0.f, o1 = 0.f, o2 = 0.f, o3 = 0.f, o4 = 0.f;
    if (tid > 0){
      const float* pr = &scanb[bufc][tid - 1][0];
      o0 = pr[0]; o1 = pr[1]; o2 = pr[2]; o3 = pr[3]; o4 = pr[4];
    }
    #pragma unroll
    for (int j = 0; j < SEG; ++j){
      float n0 = o0 * aL;
      float n1 = o1 * aT;
      float n2 = fmaf(o2, gc, o3 * gs);
      float n3 = fmaf(o3, gc, -o2 * gs);
      float n4 = o4 * aR;
      o0 = n0; o1 = n1; o2 = n2; o3 = n3; o4 = n4;
      p[j][0] += n0; p[j][1] += n1; p[j][2] += n2; p[j][3] += n3; p[j][4] += n4;
    }
  }

  // ---- c-eval: all tokens in parallel (coalesced hp reads) ----
  float acc[SEG][5];
  #pragma unroll
  for (int j = 0; j < SEG; ++j){
    acc[j][0]=0.f; acc[j][1]=0.f; acc[j][2]=0.f; acc[j][3]=0.f; acc[j][4]=0.f;
  }

  #pragma unroll
  for (int ch = 0; ch < 8; ++ch){
    uint4 hpc[SEG];
    #pragma unroll
    for (int tok = 0; tok < SEG; ++tok)
      hpc[tok] = *(const uint4*)&hpg[((size_t)ch * S_ + (tid * SEG + tok)) * 8];
    #pragma unroll
    for (int jj = 0; jj < 8; ++jj){
      const float* wr = &Wp[ch * 8 + jj][0];
      float w0 = wr[0], w1 = wr[1], w2 = wr[2], w3 = wr[3], w4 = wr[4];
      float q0 = wr[5], q1 = wr[6], q2 = wr[7], q3 = wr[8], q4 = wr[9];
      #pragma unroll
      for (int tok = 0; tok < SEG; ++tok){
        unsigned int word = ((const unsigned int*)&hpc[tok])[jj >> 1];
        unsigned short hu = (jj & 1) ? (unsigned short)(word >> 16)
                                     : (unsigned short)(word & 0xffff);
        float hv = bf2f(hu);
        float up = fmaf(p[tok][0], w0, hv);
        up = fmaf(p[tok][1], w1, up);
        up = fmaf(p[tok][2], w2, up);
        up = fmaf(p[tok][3], w3, up);
        up = fmaf(p[tok][4], w4, up);
        float u = up * rcpf_(1.0f + __expf(-1.702f * up));   // sigmoid-GELU
        acc[tok][0] = fmaf(u, q0, acc[tok][0]);
        acc[tok][1] = fmaf(u, q1, acc[tok][1]);
        acc[tok][2] = fmaf(u, q2, acc[tok][2]);
        acc[tok][3] = fmaf(u, q3, acc[tok][3]);
        acc[tok][4] = fmaf(u, q4, acc[tok][4]);
      }
    }
  }

  // ---- pass 2 local aggregate: v' = bx + c ----
  float a0 = 0.f, a1 = 0.f, a2 = 0.f, a3 = 0.f, a4 = 0.f;
  #pragma unroll
  for (int j = 0; j < SEG; ++j){
    float4 vb = *(const float4*)&bxr[j * 8];
    float  ve = bxr[j * 8 + 4];
    float c0v = cs * tanh_pade(acc[j][0] + bc0);
    float c1v = cs * tanh_pade(acc[j][1] + bc1);
    float c2v = cs * tanh_pade(acc[j][2] + bc2v);
    float c3v = cs * tanh_pade(acc[j][3] + bc3);
    float c4v = cs * tanh_pade(acc[j][4] + bc4);
    float v0 = vb.x + c0v, v1 = vb.y + c1v, v2 = vb.z + c2v,
          v3 = vb.w + c3v, v4 = ve + c4v;
    float n0 = fmaf(a0, aL, v0);
    float n1 = fmaf(a1, aT, v1);
    float n2 = fmaf(a2, gc, fmaf(a3, gs, v2));
    float n3 = fmaf(a2, -gs, fmaf(a3, gc, v3));
    float n4 = fmaf(a4, aR, v4);
    a0 = n0; a1 = n1; a2 = n2; a3 = n3; a4 = n4;
  }
  __syncthreads();
  scanb[0][tid][0] = a0; scanb[0][tid][1] = a1; scanb[0][tid][2] = a2;
  scanb[0][tid][3] = a3; scanb[0][tid][4] = a4;
  __syncthreads();

  // ---- Kogge-Stone pass 2 (inclusive; thread TPB-1 ends with s_2047) ----
  bufc = 0;
  {
    float mL = aL, mT = aT, mc = gc, ms = gs, mR = aR;
    {
      float nc = mc * mc - ms * ms, ns = 2.f * mc * ms;
      mL *= mL; mT *= mT; mR *= mR; mc = nc; ms = ns;
    }
    float x0 = 0.f, x1 = 0.f, x2 = 0.f, x3 = 0.f, x4 = 0.f;
    #pragma unroll
    for (int d = 0; d < LEV; ++d){
      const int off = 1 << d;
      x0 = scanb[bufc][tid][0]; x1 = scanb[bufc][tid][1];
      x2 = scanb[bufc][tid][2]; x3 = scanb[bufc][tid][3];
      x4 = scanb[bufc][tid][4];
      if (tid >= off){
        const float* pr = &scanb[bufc][tid - off][0];
        float q0 = pr[0], q1 = pr[1], q2 = pr[2], q3 = pr[3], q4 = pr[4];
        x0 = fmaf(q0, mL, x0);
        x1 = fmaf(q1, mT, x1);
        x2 = fmaf(q2, mc, fmaf(q3, ms, x2));
        x3 = fmaf(q2, -ms, fmaf(q3, mc, x3));
        x4 = fmaf(q4, mR, x4);
      }
      scanb[bufc ^ 1][tid][0] = x0; scanb[bufc ^ 1][tid][1] = x1;
      scanb[bufc ^ 1][tid][2] = x2; scanb[bufc ^ 1][tid][3] = x3;
      scanb[bufc ^ 1][tid][4] = x4;
      __syncthreads();
      bufc ^= 1;
      float nc = mc * mc - ms * ms, ns = 2.f * mc * ms;
      mL *= mL; mT *= mT; mR *= mR; mc = nc; ms = ns;
    }
    if (tid == TPB - 1){
      float* o = out + b * SD_;
      o[0] = x0; o[1] = x1; o[2] = x2; o[3] = x3; o[4] = x4;
    }
  }
}

// ---------------------------------------------------------------------------
extern "C" void kernel_launch(void* const* d_in, const int* in_sizes, int n_in,
                              void* d_out, int out_size, void* d_ws, size_t ws_size,
                              hipStream_t stream)
{
  const float* x          = (const float*)d_in[0];
  const float* W_in       = (const float*)d_in[1];
  const float* b_in       = (const float*)d_in[2];
  const float* ln_g       = (const float*)d_in[3];
  const float* ln_b       = (const float*)d_in[4];
  const float* W_innov    = (const float*)d_in[5];
  const float* b_innov    = (const float*)d_in[6];
  const float* W_c1       = (const float*)d_in[7];
  const float* b_c1       = (const float*)d_in[8];
  const float* W_c2       = (const float*)d_in[9];
  const float* b_c2       = (const float*)d_in[10];
  const float* corr_scale = (const float*)d_in[11];
  const float* rawL       = (const float*)d_in[12];
  const float* rawT       = (const float*)d_in[13];
  const float* rawG       = (const float*)d_in[14];
  const float* rawR       = (const float*)d_in[15];
  const float* omega      = (const float*)d_in[16];

  unsigned short* hp = (unsigned short*)d_ws;
  float* bx = (float*)((char*)d_ws + (size_t)B_ * S_ * H_ * 2);
  unsigned short* wf = (unsigned short*)((char*)d_ws
                        + (size_t)B_ * S_ * H_ * 2 + (size_t)B_ * S_ * 8 * 4);

  wsetup<<<1, 64, 0, stream>>>(W_in, W_c1, W_innov, wf);
  int nblocksA = (B_ * S_) / TOKB;   // 2048
  phaseA<<<nblocksA, 256, 0, stream>>>(x, wf, b_in, ln_g, ln_b,
                                       b_innov, b_c1, hp, bx);
  phaseB<<<B_, TPB, 0, stream>>>(hp, bx, W_c1, W_c2, b_c2, corr_scale,
                                 rawL, rawT, rawG, rawR, omega, (float*)d_out);
}

// Round 19
// 79.169 us; speedup vs baseline: 5.6633x; 1.4068x over previous
//
#include <hip/hip_runtime.h>
#include <hip/hip_bf16.h>

#define B_   256
#define S_   2048
#define DIN  128
#define H_   64
#define SD_  5
#define TOKB 256   // tokens per phaseA block
#define NIT  4     // tiles per wave in phaseA
#define TPB  1024  // phaseB threads per block
#define SEG  2     // tokens per phaseB thread
#define LEV  10    // log2(TPB)

typedef __attribute__((ext_vector_type(8))) short short8_t;   // 8 bf16
typedef __attribute__((ext_vector_type(4))) float float4_t;   // MFMA acc

__device__ __forceinline__ float rcpf_(float x){ return __builtin_amdgcn_rcpf(x); }

// exact-erf GELU: gelu(x)=0.5x(1+erf(x/sqrt2)), A&S 7.1.26
__device__ __forceinline__ float geluf(float v){
  const float kInvSqrt2 = 0.70710678118654752440f;
  float z = v * kInvSqrt2;
  float a = fabsf(z);
  float t = rcpf_(fmaf(0.3275911f, a, 1.0f));
  float p = fmaf(fmaf(fmaf(fmaf(1.061405429f, t, -1.453152027f), t, 1.421413741f),
                      t, -0.284496736f), t, 0.254829592f);
  p *= t;
  float e = 1.0f - p * __expf(-z * z);
  float er = copysignf(e, z);
  return 0.5f * v * (1.0f + er);
}

__device__ __forceinline__ float sigmoidf_(float x){
  return rcpf_(1.0f + __expf(-x));
}

// Pade(3,2) tanh with clamp: |err| <= 0.0065 (attenuated x0.01 by corr_scale)
__device__ __forceinline__ float tanh_pade(float x){
  float xc = fminf(fmaxf(x, -4.0f), 4.0f);
  float t = xc * xc;
  float n = xc * (27.0f + t);
  float d = fmaf(9.0f, t, 27.0f);
  return n * rcpf_(d);
}

__device__ __forceinline__ unsigned short f2bf_hw(float f){
  union { __hip_bfloat16 b; unsigned short u; } cv;
  cv.b = __float2bfloat16(f);
  return cv.u;
}
__device__ __forceinline__ float bf2f(unsigned short h){
  return __uint_as_float(((unsigned int)h) << 16);
}

// ---- contraction window: first relevant (256-aligned) token index ----
// rho = spectral radius bound; tokens before T0 carry weight <= rho^(2W1)
// in s_2047 (truncation error ~1e-10). Deterministic: same fp ops both kernels;
// robust to mismatch (tanh bounds any unwritten-hp correction by ~0.01 with
// weight <= rho^(W-256) ~ 1e-20).
__device__ __forceinline__ int window_T0a(const float* rawL, const float* rawT,
                                          const float* rawG, const float* rawR){
  float aL = sigmoidf_(rawL[0]) * 0.15f + 0.85f;
  float aT = sigmoidf_(rawT[0]) * 0.25f + 0.70f;
  float gg = sigmoidf_(rawG[0]) * 0.20f + 0.80f;
  float aR = sigmoidf_(rawR[0]) * 0.4f;
  float rho = fmaxf(fmaxf(aL, aT), fmaxf(gg, aR));
  if (rho >= 0.9995f) return 0;
  float W1 = ceilf(25.0f / (-logf(rho)));
  int T0 = (int)fmaxf(0.0f, 2048.0f - 2.0f * W1);
  return (T0 >> 8) << 8;
}

// ---- async global->LDS (dest = wave-uniform base + lane*16) ----
__device__ __forceinline__ void gl_lds16(const void* g, void* l){
  __builtin_amdgcn_global_load_lds(
      (const __attribute__((address_space(1))) void*)g,
      (__attribute__((address_space(3))) void*)l, 16, 0, 0);
}

// ---- DPP helpers (phaseA) ----
template<int CTRL>
__device__ __forceinline__ float dpp_radd(float x){
  int sh = __builtin_amdgcn_update_dpp(0, __float_as_int(x), CTRL, 0xf, 0xf, true);
  return x + __int_as_float(sh);
}
__device__ __forceinline__ float red16(float x){
  x = dpp_radd<0xB1>(x);   // quad_perm xor1
  x = dpp_radd<0x4E>(x);   // quad_perm xor2
  x = dpp_radd<0x124>(x);  // row_ror:4
  x = dpp_radd<0x128>(x);  // row_ror:8
  return x;
}

// ---------------------------------------------------------------------------
// wsetup: precompute all weight fragments once (26 KB) into d_ws.
// ---------------------------------------------------------------------------
__global__ __launch_bounds__(64) void wsetup(
    const float* __restrict__ W_in, const float* __restrict__ W_c1,
    const float* __restrict__ W_innov, unsigned short* __restrict__ wf)
{
  const int l = threadIdx.x;
  #pragma unroll
  for (int p = 0; p < 16; ++p){
    int kc = p >> 2, nc = p & 3;
    unsigned short tmp[8];
    #pragma unroll
    for (int m = 0; m < 8; ++m)
      tmp[m] = f2bf_hw(W_in[(32 * kc + 8 * (l >> 4) + m) * 64 + 16 * nc + (l & 15)]);
    *(uint4*)&wf[p * 512 + l * 8] = *(uint4*)tmp;
  }
  #pragma unroll
  for (int p = 0; p < 8; ++p){
    int kc2 = p >> 2, nc = p & 3;
    unsigned short tmp[8];
    #pragma unroll
    for (int m = 0; m < 8; ++m)
      tmp[m] = f2bf_hw(W_c1[(5 + 32 * kc2 + 8 * (l >> 4) + m) * 64 + 16 * nc + (l & 15)]);
    *(uint4*)&wf[8192 + p * 512 + l * 8] = *(uint4*)tmp;
  }
  #pragma unroll
  for (int p = 0; p < 2; ++p){
    unsigned short tmp[8];
    #pragma unroll
    for (int m = 0; m < 8; ++m)
      tmp[m] = ((l & 15) < 5)
             ? f2bf_hw(W_innov[(32 * p + 8 * (l >> 4) + m) * 5 + (l & 15)])
             : (unsigned short)0;
    *(uint4*)&wf[12288 + p * 512 + l * 8] = *(uint4*)tmp;
  }
}

// ---------------------------------------------------------------------------
// Phase A: MFMA + x-prefetch + async weight-frag copy + ch8-major hp layout.
// Blocks entirely before the contraction window exit before touching x.
// ---------------------------------------------------------------------------
__global__ __launch_bounds__(256, 3) void phaseA(
    const float* __restrict__ x, const unsigned short* __restrict__ wf,
    const float* __restrict__ b_in, const float* __restrict__ ln_g,
    const float* __restrict__ ln_b, const float* __restrict__ b_innov,
    const float* __restrict__ b_c1,
    const float* __restrict__ rawL, const float* __restrict__ rawT,
    const float* __restrict__ rawG, const float* __restrict__ rawR,
    unsigned short* __restrict__ hp_out, float* __restrict__ bx_out)
{
  // early-exit: whole block outside the relevant window
  {
    const int rowrel = (blockIdx.x & 7) * TOKB;   // 8 blocks per row
    const int T0a = window_T0a(rawL, rawT, rawG, rawR);
    if (rowrel + TOKB <= T0a) return;
  }

  __shared__ __align__(16) unsigned short Wfs[13312];
  __shared__ __align__(16) unsigned short hbuf[4][16][72];

  unsigned short* WfA = Wfs;
  unsigned short* WfC = Wfs + 8192;
  unsigned short* WfI = Wfs + 12288;

  const int tid  = threadIdx.x;
  const int lane = tid & 63;
  const int w    = tid >> 6;
  const int c16  = lane & 15;
  const int g4   = lane >> 4;
  const long tok0 = (long)blockIdx.x * TOKB;

  for (int i = w; i < 26; i += 4)
    gl_lds16(wf + i * 512 + lane * 8, (char*)Wfs + (size_t)i * 1024);

  float binv[4], lg[4], lb[4], bc1v[4];
  #pragma unroll
  for (int nc = 0; nc < 4; ++nc){
    binv[nc] = b_in[16 * nc + c16];
    lg[nc]   = ln_g[16 * nc + c16];
    lb[nc]   = ln_b[16 * nc + c16];
    bc1v[nc] = b_c1[16 * nc + c16];
  }
  float binn = (c16 < 5) ? b_innov[c16] : 0.0f;

  float4 xf[2][8];
  {
    const float* xr = x + (size_t)(tok0 + w * 16 + c16) * DIN;
    #pragma unroll
    for (int kc = 0; kc < 4; ++kc){
      xf[0][2 * kc]     = *(const float4*)(xr + kc * 32 + g4 * 8);
      xf[0][2 * kc + 1] = *(const float4*)(xr + kc * 32 + g4 * 8 + 4);
    }
  }

  asm volatile("s_waitcnt vmcnt(0)" ::: "memory");
  __builtin_amdgcn_sched_barrier(0);
  __syncthreads();

  #pragma unroll
  for (int it = 0; it < NIT; ++it){
    const int cur = it & 1;
    const int nxt = cur ^ 1;
    const long tbg = tok0 + it * 64 + w * 16;

    if (it + 1 < NIT){
      const float* xr = x + (size_t)(tbg + 64 + c16) * DIN;
      #pragma unroll
      for (int kc = 0; kc < 4; ++kc){
        xf[nxt][2 * kc]     = *(const float4*)(xr + kc * 32 + g4 * 8);
        xf[nxt][2 * kc + 1] = *(const float4*)(xr + kc * 32 + g4 * 8 + 4);
      }
    }

    short8_t a1[4];
    #pragma unroll
    for (int kc = 0; kc < 4; ++kc){
      float4 f0 = xf[cur][2 * kc];
      float4 f1 = xf[cur][2 * kc + 1];
      a1[kc][0] = (short)f2bf_hw(f0.x); a1[kc][1] = (short)f2bf_hw(f0.y);
      a1[kc][2] = (short)f2bf_hw(f0.z); a1[kc][3] = (short)f2bf_hw(f0.w);
      a1[kc][4] = (short)f2bf_hw(f1.x); a1[kc][5] = (short)f2bf_hw(f1.y);
      a1[kc][6] = (short)f2bf_hw(f1.z); a1[kc][7] = (short)f2bf_hw(f1.w);
    }

    float4_t acc1[4] = {{0,0,0,0},{0,0,0,0},{0,0,0,0},{0,0,0,0}};
    #pragma unroll
    for (int kc = 0; kc < 4; ++kc){
      #pragma unroll
      for (int nc = 0; nc < 4; ++nc){
        short8_t bf = *(const short8_t*)&WfA[(kc * 4 + nc) * 512 + lane * 8];
        acc1[nc] = __builtin_amdgcn_mfma_f32_16x16x32_bf16(a1[kc], bf, acc1[nc], 0, 0, 0);
      }
    }

    float v[4][4];
    #pragma unroll
    for (int nc = 0; nc < 4; ++nc)
      #pragma unroll
      for (int r = 0; r < 4; ++r)
        v[nc][r] = acc1[nc][r] + binv[nc];

    float mu[4], rstd[4];
    #pragma unroll
    for (int r = 0; r < 4; ++r){
      float vs = (v[0][r] + v[1][r]) + (v[2][r] + v[3][r]);
      float qs = v[0][r] * v[0][r];
      qs = fmaf(v[1][r], v[1][r], qs);
      qs = fmaf(v[2][r], v[2][r], qs);
      qs = fmaf(v[3][r], v[3][r], qs);
      vs = red16(vs);
      qs = red16(qs);
      float m  = vs * (1.0f / 64.0f);
      float va = fmaxf(qs * (1.0f / 64.0f) - m * m, 0.0f);
      mu[r]   = m;
      rstd[r] = rsqrtf(va + 1e-5f);
    }

    #pragma unroll
    for (int nc = 0; nc < 4; ++nc)
      #pragma unroll
      for (int r = 0; r < 4; ++r){
        float hn = fmaf((v[nc][r] - mu[r]) * rstd[r], lg[nc], lb[nc]);
        hbuf[w][4 * g4 + r][16 * nc + c16] = f2bf_hw(geluf(hn));
      }

    short8_t a2[2];
    a2[0] = *(const short8_t*)&hbuf[w][c16][8 * g4];
    a2[1] = *(const short8_t*)&hbuf[w][c16][32 + 8 * g4];

    float4_t acc2[4] = {{0,0,0,0},{0,0,0,0},{0,0,0,0},{0,0,0,0}};
    #pragma unroll
    for (int kc2 = 0; kc2 < 2; ++kc2){
      #pragma unroll
      for (int nc = 0; nc < 4; ++nc){
        short8_t bf = *(const short8_t*)&WfC[(kc2 * 4 + nc) * 512 + lane * 8];
        acc2[nc] = __builtin_amdgcn_mfma_f32_16x16x32_bf16(a2[kc2], bf, acc2[nc], 0, 0, 0);
      }
    }
    float4_t acc3 = {0, 0, 0, 0};
    {
      short8_t bi0 = *(const short8_t*)&WfI[0 * 512 + lane * 8];
      short8_t bi1 = *(const short8_t*)&WfI[1 * 512 + lane * 8];
      acc3 = __builtin_amdgcn_mfma_f32_16x16x32_bf16(a2[0], bi0, acc3, 0, 0, 0);
      acc3 = __builtin_amdgcn_mfma_f32_16x16x32_bf16(a2[1], bi1, acc3, 0, 0, 0);
    }

    if (c16 < 5){
      #pragma unroll
      for (int r = 0; r < 4; ++r)
        bx_out[(size_t)(tbg + 4 * g4 + r) * 8 + c16] = acc3[r] + binn;
    }

    #pragma unroll
    for (int nc = 0; nc < 4; ++nc)
      #pragma unroll
      for (int r = 0; r < 4; ++r)
        hbuf[w][4 * g4 + r][16 * nc + c16] = f2bf_hw(acc2[nc][r] + bc1v[nc]);

    {
      // hp2[b][ch8][tok][8]: lanes 0..15 = tokens (contiguous 256B segments)
      const int tl = lane & 15, jj = lane >> 4;   // token-in-tile, ch8-pair
      uint4 v0 = *(const uint4*)&hbuf[w][tl][jj * 16];
      uint4 v1 = *(const uint4*)&hbuf[w][tl][jj * 16 + 8];
      const long gt  = tbg + tl;          // global token
      const long bb  = gt >> 11;          // batch row
      const long tlc = gt & (S_ - 1);     // token within row
      unsigned short* hg = hp_out + (((bb * 8 + 2 * jj) * (long)S_ + tlc) * 8);
      *(uint4*)hg            = v0;        // ch8 = 2*jj
      *(uint4*)(hg + S_ * 8) = v1;        // ch8 = 2*jj+1
    }
  }
}

// ---------------------------------------------------------------------------
// Phase B (two-pass parallel scan, 1024 threads / 2 tokens per thread).
// Threads below the contraction window contribute exact zeros: no bx/hp
// loads, no c-eval, no tanh — zeros propagate correctly through the scan.
// ---------------------------------------------------------------------------
__global__ __launch_bounds__(TPB, 1) void phaseB(
    const unsigned short* __restrict__ hp, const float* __restrict__ bx,
    const float* __restrict__ W_c1, const float* __restrict__ W_c2,
    const float* __restrict__ b_c2, const float* __restrict__ corr_scale,
    const float* __restrict__ rawL, const float* __restrict__ rawT,
    const float* __restrict__ rawG, const float* __restrict__ rawR,
    const float* __restrict__ omega, float* __restrict__ out)
{
  __shared__ __align__(16) float scanb[2][TPB][6];   // 48 KB
  __shared__ __align__(16) float Wp[64][12];         // 3 KB

  const int tid = threadIdx.x;
  const int b = blockIdx.x;

  const int T0a = window_T0a(rawL, rawT, rawG, rawR);
  const bool act = (tid * SEG >= T0a);   // both of this thread's tokens in-window

  float aL = sigmoidf_(rawL[0]) * 0.15f + 0.85f;
  float aT = sigmoidf_(rawT[0]) * 0.25f + 0.70f;
  float gg = sigmoidf_(rawG[0]) * 0.20f + 0.80f;
  float om = omega[0];
  float gc = gg * cosf(om), gs = gg * sinf(om);
  float aR = sigmoidf_(rawR[0]) * 0.4f;
  float cs = corr_scale[0];
  float bc0 = b_c2[0], bc1 = b_c2[1], bc2v = b_c2[2], bc3 = b_c2[3], bc4 = b_c2[4];

  if (tid < 64){
    #pragma unroll
    for (int i = 0; i < 5; ++i) Wp[tid][i]     = W_c1[i * 64 + tid];
    #pragma unroll
    for (int i = 0; i < 5; ++i) Wp[tid][5 + i] = W_c2[tid * 5 + i];
  }

  const float* bxr = bx + (size_t)b * S_ * 8 + (size_t)tid * (SEG * 8);
  const unsigned short* hpg = hp + (size_t)b * S_ * H_;   // = b*8*S*8

  // ---- pass 1 local: SEG-step serial prefix (zeros when inactive) ----
  float p[SEG][5];
  {
    float c0 = 0.f, c1 = 0.f, c2 = 0.f, c3 = 0.f, c4 = 0.f;
    if (act){
      #pragma unroll
      for (int j = 0; j < SEG; ++j){
        float4 vb = *(const float4*)&bxr[j * 8];
        float  ve = bxr[j * 8 + 4];
        float n0 = fmaf(c0, aL, vb.x);
        float n1 = fmaf(c1, aT, vb.y);
        float n2 = fmaf(c2, gc, fmaf(c3, gs, vb.z));
        float n3 = fmaf(c2, -gs, fmaf(c3, gc, vb.w));
        float n4 = fmaf(c4, aR, ve);
        c0 = n0; c1 = n1; c2 = n2; c3 = n3; c4 = n4;
        p[j][0] = n0; p[j][1] = n1; p[j][2] = n2; p[j][3] = n3; p[j][4] = n4;
      }
    } else {
      #pragma unroll
      for (int j = 0; j < SEG; ++j){
        p[j][0]=0.f; p[j][1]=0.f; p[j][2]=0.f; p[j][3]=0.f; p[j][4]=0.f;
      }
    }
    scanb[0][tid][0] = c0; scanb[0][tid][1] = c1; scanb[0][tid][2] = c2;
    scanb[0][tid][3] = c3; scanb[0][tid][4] = c4;
  }
  __syncthreads();

  // ---- Kogge-Stone over TPB segment aggregates ----
  int bufc = 0;
  {
    float mL = aL, mT = aT, mc = gc, ms = gs, mR = aR;
    {
      float nc = mc * mc - ms * ms, ns = 2.f * mc * ms;
      mL *= mL; mT *= mT; mR *= mR; mc = nc; ms = ns;
    }
    #pragma unroll
    for (int d = 0; d < LEV; ++d){
      const int off = 1 << d;
      float x0 = scanb[bufc][tid][0], x1 = scanb[bufc][tid][1],
            x2 = scanb[bufc][tid][2], x3 = scanb[bufc][tid][3],
            x4 = scanb[bufc][tid][4];
      if (tid >= off){
        const float* pr = &scanb[bufc][tid - off][0];
        float q0 = pr[0], q1 = pr[1], q2 = pr[2], q3 = pr[3], q4 = pr[4];
        x0 = fmaf(q0, mL, x0);
        x1 = fmaf(q1, mT, x1);
        x2 = fmaf(q2, mc, fmaf(q3, ms, x2));
        x3 = fmaf(q2, -ms, fmaf(q3, mc, x3));
        x4 = fmaf(q4, mR, x4);
      }
      scanb[bufc ^ 1][tid][0] = x0; scanb[bufc ^ 1][tid][1] = x1;
      scanb[bufc ^ 1][tid][2] = x2; scanb[bufc ^ 1][tid][3] = x3;
      scanb[bufc ^ 1][tid][4] = x4;
      __syncthreads();
      bufc ^= 1;
      float nc = mc * mc - ms * ms, ns = 2.f * mc * ms;
      mL *= mL; mT *= mT; mR *= mR; mc = nc; ms = ns;
    }
  }

  // ---- exclusive offset + full states ----
  if (act){
    float o0 = 0.f, o1 = 0.f, o2 = 0.f, o3 = 0.f, o4 = 0.f;
    if (tid > 0){
      const float* pr = &scanb[bufc][tid - 1][0];
      o0 = pr[0]; o1 = pr[1]; o2 = pr[2]; o3 = pr[3]; o4 = pr[4];
    }
    #pragma unroll
    for (int j = 0; j < SEG; ++j){
      float n0 = o0 * aL;
      float n1 = o1 * aT;
      float n2 = fmaf(o2, gc, o3 * gs);
      float n3 = fmaf(o3, gc, -o2 * gs);
      float n4 = o4 * aR;
      o0 = n0; o1 = n1; o2 = n2; o3 = n3; o4 = n4;
      p[j][0] += n0; p[j][1] += n1; p[j][2] += n2; p[j][3] += n3; p[j][4] += n4;
    }
  }

  // ---- c-eval: windowed tokens only (coalesced hp reads) ----
  float acc[SEG][5];
  #pragma unroll
  for (int j = 0; j < SEG; ++j){
    acc[j][0]=0.f; acc[j][1]=0.f; acc[j][2]=0.f; acc[j][3]=0.f; acc[j][4]=0.f;
  }

  if (act){
    #pragma unroll
    for (int ch = 0; ch < 8; ++ch){
      uint4 hpc[SEG];
      #pragma unroll
      for (int tok = 0; tok < SEG; ++tok)
        hpc[tok] = *(const uint4*)&hpg[((size_t)ch * S_ + (tid * SEG + tok)) * 8];
      #pragma unroll
      for (int jj = 0; jj < 8; ++jj){
        const float* wr = &Wp[ch * 8 + jj][0];
        float w0 = wr[0], w1 = wr[1], w2 = wr[2], w3 = wr[3], w4 = wr[4];
        float q0 = wr[5], q1 = wr[6], q2 = wr[7], q3 = wr[8], q4 = wr[9];
        #pragma unroll
        for (int tok = 0; tok < SEG; ++tok){
          unsigned int word = ((const unsigned int*)&hpc[tok])[jj >> 1];
          unsigned short hu = (jj & 1) ? (unsigned short)(word >> 16)
                                       : (unsigned short)(word & 0xffff);
          float hv = bf2f(hu);
          float up = fmaf(p[tok][0], w0, hv);
          up = fmaf(p[tok][1], w1, up);
          up = fmaf(p[tok][2], w2, up);
          up = fmaf(p[tok][3], w3, up);
          up = fmaf(p[tok][4], w4, up);
          float u = up * rcpf_(1.0f + __expf(-1.702f * up));   // sigmoid-GELU
          acc[tok][0] = fmaf(u, q0, acc[tok][0]);
          acc[tok][1] = fmaf(u, q1, acc[tok][1]);
          acc[tok][2] = fmaf(u, q2, acc[tok][2]);
          acc[tok][3] = fmaf(u, q3, acc[tok][3]);
          acc[tok][4] = fmaf(u, q4, acc[tok][4]);
        }
      }
    }
  }

  // ---- pass 2 local aggregate: v' = bx + c (zero when inactive) ----
  float a0 = 0.f, a1 = 0.f, a2 = 0.f, a3 = 0.f, a4 = 0.f;
  if (act){
    #pragma unroll
    for (int j = 0; j < SEG; ++j){
      float4 vb = *(const float4*)&bxr[j * 8];
      float  ve = bxr[j * 8 + 4];
      float c0v = cs * tanh_pade(acc[j][0] + bc0);
      float c1v = cs * tanh_pade(acc[j][1] + bc1);
      float c2v = cs * tanh_pade(acc[j][2] + bc2v);
      float c3v = cs * tanh_pade(acc[j][3] + bc3);
      float c4v = cs * tanh_pade(acc[j][4] + bc4);
      float v0 = vb.x + c0v, v1 = vb.y + c1v, v2 = vb.z + c2v,
            v3 = vb.w + c3v, v4 = ve + c4v;
      float n0 = fmaf(a0, aL, v0);
      float n1 = fmaf(a1, aT, v1);
      float n2 = fmaf(a2, gc, fmaf(a3, gs, v2));
      float n3 = fmaf(a2, -gs, fmaf(a3, gc, v3));
      float n4 = fmaf(a4, aR, v4);
      a0 = n0; a1 = n1; a2 = n2; a3 = n3; a4 = n4;
    }
  }
  __syncthreads();
  scanb[0][tid][0] = a0; scanb[0][tid][1] = a1; scanb[0][tid][2] = a2;
  scanb[0][tid][3] = a3; scanb[0][tid][4] = a4;
  __syncthreads();

  // ---- Kogge-Stone pass 2 (inclusive; thread TPB-1 ends with s_2047) ----
  bufc = 0;
  {
    float mL = aL, mT = aT, mc = gc, ms = gs, mR = aR;
    {
      float nc = mc * mc - ms * ms, ns = 2.f * mc * ms;
      mL *= mL; mT *= mT; mR *= mR; mc = nc; ms = ns;
    }
    float x0 = 0.f, x1 = 0.f, x2 = 0.f, x3 = 0.f, x4 = 0.f;
    #pragma unroll
    for (int d = 0; d < LEV; ++d){
      const int off = 1 << d;
      x0 = scanb[bufc][tid][0]; x1 = scanb[bufc][tid][1];
      x2 = scanb[bufc][tid][2]; x3 = scanb[bufc][tid][3];
      x4 = scanb[bufc][tid][4];
      if (tid >= off){
        const float* pr = &scanb[bufc][tid - off][0];
        float q0 = pr[0], q1 = pr[1], q2 = pr[2], q3 = pr[3], q4 = pr[4];
        x0 = fmaf(q0, mL, x0);
        x1 = fmaf(q1, mT, x1);
        x2 = fmaf(q2, mc, fmaf(q3, ms, x2));
        x3 = fmaf(q2, -ms, fmaf(q3, mc, x3));
        x4 = fmaf(q4, mR, x4);
      }
      scanb[bufc ^ 1][tid][0] = x0; scanb[bufc ^ 1][tid][1] = x1;
      scanb[bufc ^ 1][tid][2] = x2; scanb[bufc ^ 1][tid][3] = x3;
      scanb[bufc ^ 1][tid][4] = x4;
      __syncthreads();
      bufc ^= 1;
      float nc = mc * mc - ms * ms, ns = 2.f * mc * ms;
      mL *= mL; mT *= mT; mR *= mR; mc = nc; ms = ns;
    }
    if (tid == TPB - 1){
      float* o = out + b * SD_;
      o[0] = x0; o[1] = x1; o[2] = x2; o[3] = x3; o[4] = x4;
    }
  }
}

// ---------------------------------------------------------------------------
extern "C" void kernel_launch(void* const* d_in, const int* in_sizes, int n_in,
                              void* d_out, int out_size, void* d_ws, size_t ws_size,
                              hipStream_t stream)
{
  const float* x          = (const float*)d_in[0];
  const float* W_in       = (const float*)d_in[1];
  const float* b_in       = (const float*)d_in[2];
  const float* ln_g       = (const float*)d_in[3];
  const float* ln_b       = (const float*)d_in[4];
  const float* W_innov    = (const float*)d_in[5];
  const float* b_innov    = (const float*)d_in[6];
  const float* W_c1       = (const float*)d_in[7];
  const float* b_c1       = (const float*)d_in[8];
  const float* W_c2       = (const float*)d_in[9];
  const float* b_c2       = (const float*)d_in[10];
  const float* corr_scale = (const float*)d_in[11];
  const float* rawL       = (const float*)d_in[12];
  const float* rawT       = (const float*)d_in[13];
  const float* rawG       = (const float*)d_in[14];
  const float* rawR       = (const float*)d_in[15];
  const float* omega      = (const float*)d_in[16];

  unsigned short* hp = (unsigned short*)d_ws;
  float* bx = (float*)((char*)d_ws + (size_t)B_ * S_ * H_ * 2);
  unsigned short* wf = (unsigned short*)((char*)d_ws
                        + (size_t)B_ * S_ * H_ * 2 + (size_t)B_ * S_ * 8 * 4);

  wsetup<<<1, 64, 0, stream>>>(W_in, W_c1, W_innov, wf);
  int nblocksA = (B_ * S_) / TOKB;   // 2048
  phaseA<<<nblocksA, 256, 0, stream>>>(x, wf, b_in, ln_g, ln_b,
                                       b_innov, b_c1,
                                       rawL, rawT, rawG, rawR, hp, bx);
  phaseB<<<B_, TPB, 0, stream>>>(hp, bx, W_c1, W_c2, b_c2, corr_scale,
                                 rawL, rawT, rawG, rawR, omega, (float*)d_out);
}

// Round 20
// 75.141 us; speedup vs baseline: 5.9669x; 1.0536x over previous
//
#include <hip/hip_runtime.h>
#include <hip/hip_bf16.h>

#define B_   256
#define S_   2048
#define DIN  128
#define H_   64
#define SD_  5
#define TOKB 256   // tokens per phaseA block
#define NIT  4     // tiles per wave in phaseA
#define TPB  1024  // phaseB threads per block
#define SEG  2     // tokens per phaseB thread
#define LEV  10    // log2(TPB)

typedef __attribute__((ext_vector_type(8))) short short8_t;   // 8 bf16
typedef __attribute__((ext_vector_type(4))) float float4_t;   // MFMA acc

__device__ __forceinline__ float rcpf_(float x){ return __builtin_amdgcn_rcpf(x); }

// exact-erf GELU: gelu(x)=0.5x(1+erf(x/sqrt2)), A&S 7.1.26
__device__ __forceinline__ float geluf(float v){
  const float kInvSqrt2 = 0.70710678118654752440f;
  float z = v * kInvSqrt2;
  float a = fabsf(z);
  float t = rcpf_(fmaf(0.3275911f, a, 1.0f));
  float p = fmaf(fmaf(fmaf(fmaf(1.061405429f, t, -1.453152027f), t, 1.421413741f),
                      t, -0.284496736f), t, 0.254829592f);
  p *= t;
  float e = 1.0f - p * __expf(-z * z);
  float er = copysignf(e, z);
  return 0.5f * v * (1.0f + er);
}

__device__ __forceinline__ float sigmoidf_(float x){
  return rcpf_(1.0f + __expf(-x));
}

// Pade(3,2) tanh with clamp: |err| <= 0.0065 (attenuated x0.01 by corr_scale)
__device__ __forceinline__ float tanh_pade(float x){
  float xc = fminf(fmaxf(x, -4.0f), 4.0f);
  float t = xc * xc;
  float n = xc * (27.0f + t);
  float d = fmaf(9.0f, t, 27.0f);
  return n * rcpf_(d);
}

__device__ __forceinline__ unsigned short f2bf_hw(float f){
  union { __hip_bfloat16 b; unsigned short u; } cv;
  cv.b = __float2bfloat16(f);
  return cv.u;
}
__device__ __forceinline__ float bf2f(unsigned short h){
  return __uint_as_float(((unsigned int)h) << 16);
}

// ---- contraction window: first relevant (256-aligned) token index ----
// rho = spectral radius bound. Zero-initializing the scan at T0 injects
// error <= ||s||*rho^(2048-T0) (+ predictor-correction term of the same
// order); with safety 8 and 256-alignment: <= ~40*e^-20 ~ 1e-7, five
// orders below the bf16-hp noise floor. Deterministic across kernels.
__device__ __forceinline__ int window_T0a(const float* rawL, const float* rawT,
                                          const float* rawG, const float* rawR){
  float aL = sigmoidf_(rawL[0]) * 0.15f + 0.85f;
  float aT = sigmoidf_(rawT[0]) * 0.25f + 0.70f;
  float gg = sigmoidf_(rawG[0]) * 0.20f + 0.80f;
  float aR = sigmoidf_(rawR[0]) * 0.4f;
  float rho = fmaxf(fmaxf(aL, aT), fmaxf(gg, aR));
  if (rho >= 0.9995f) return 0;
  float W1 = ceilf(8.0f / (-logf(rho)));
  int T0 = (int)fmaxf(0.0f, 2048.0f - 2.0f * W1);
  return (T0 >> 8) << 8;
}

// ---- async global->LDS (dest = wave-uniform base + lane*16) ----
__device__ __forceinline__ void gl_lds16(const void* g, void* l){
  __builtin_amdgcn_global_load_lds(
      (const __attribute__((address_space(1))) void*)g,
      (__attribute__((address_space(3))) void*)l, 16, 0, 0);
}

// ---- DPP helpers (phaseA) ----
template<int CTRL>
__device__ __forceinline__ float dpp_radd(float x){
  int sh = __builtin_amdgcn_update_dpp(0, __float_as_int(x), CTRL, 0xf, 0xf, true);
  return x + __int_as_float(sh);
}
__device__ __forceinline__ float red16(float x){
  x = dpp_radd<0xB1>(x);   // quad_perm xor1
  x = dpp_radd<0x4E>(x);   // quad_perm xor2
  x = dpp_radd<0x124>(x);  // row_ror:4
  x = dpp_radd<0x128>(x);  // row_ror:8
  return x;
}

// ---------------------------------------------------------------------------
// wsetup: precompute all weight fragments once (26 KB) into d_ws.
// ---------------------------------------------------------------------------
__global__ __launch_bounds__(64) void wsetup(
    const float* __restrict__ W_in, const float* __restrict__ W_c1,
    const float* __restrict__ W_innov, unsigned short* __restrict__ wf)
{
  const int l = threadIdx.x;
  #pragma unroll
  for (int p = 0; p < 16; ++p){
    int kc = p >> 2, nc = p & 3;
    unsigned short tmp[8];
    #pragma unroll
    for (int m = 0; m < 8; ++m)
      tmp[m] = f2bf_hw(W_in[(32 * kc + 8 * (l >> 4) + m) * 64 + 16 * nc + (l & 15)]);
    *(uint4*)&wf[p * 512 + l * 8] = *(uint4*)tmp;
  }
  #pragma unroll
  for (int p = 0; p < 8; ++p){
    int kc2 = p >> 2, nc = p & 3;
    unsigned short tmp[8];
    #pragma unroll
    for (int m = 0; m < 8; ++m)
      tmp[m] = f2bf_hw(W_c1[(5 + 32 * kc2 + 8 * (l >> 4) + m) * 64 + 16 * nc + (l & 15)]);
    *(uint4*)&wf[8192 + p * 512 + l * 8] = *(uint4*)tmp;
  }
  #pragma unroll
  for (int p = 0; p < 2; ++p){
    unsigned short tmp[8];
    #pragma unroll
    for (int m = 0; m < 8; ++m)
      tmp[m] = ((l & 15) < 5)
             ? f2bf_hw(W_innov[(32 * p + 8 * (l >> 4) + m) * 5 + (l & 15)])
             : (unsigned short)0;
    *(uint4*)&wf[12288 + p * 512 + l * 8] = *(uint4*)tmp;
  }
}

// ---------------------------------------------------------------------------
// Phase A: MFMA + x-prefetch + async weight-frag copy + ch8-major hp layout.
// Blocks entirely before the contraction window exit before touching x.
// ---------------------------------------------------------------------------
__global__ __launch_bounds__(256, 3) void phaseA(
    const float* __restrict__ x, const unsigned short* __restrict__ wf,
    const float* __restrict__ b_in, const float* __restrict__ ln_g,
    const float* __restrict__ ln_b, const float* __restrict__ b_innov,
    const float* __restrict__ b_c1,
    const float* __restrict__ rawL, const float* __restrict__ rawT,
    const float* __restrict__ rawG, const float* __restrict__ rawR,
    unsigned short* __restrict__ hp_out, float* __restrict__ bx_out)
{
  // early-exit: whole block outside the relevant window
  {
    const int rowrel = (blockIdx.x & 7) * TOKB;   // 8 blocks per row
    const int T0a = window_T0a(rawL, rawT, rawG, rawR);
    if (rowrel + TOKB <= T0a) return;
  }

  __shared__ __align__(16) unsigned short Wfs[13312];
  __shared__ __align__(16) unsigned short hbuf[4][16][72];

  unsigned short* WfA = Wfs;
  unsigned short* WfC = Wfs + 8192;
  unsigned short* WfI = Wfs + 12288;

  const int tid  = threadIdx.x;
  const int lane = tid & 63;
  const int w    = tid >> 6;
  const int c16  = lane & 15;
  const int g4   = lane >> 4;
  const long tok0 = (long)blockIdx.x * TOKB;

  for (int i = w; i < 26; i += 4)
    gl_lds16(wf + i * 512 + lane * 8, (char*)Wfs + (size_t)i * 1024);

  float binv[4], lg[4], lb[4], bc1v[4];
  #pragma unroll
  for (int nc = 0; nc < 4; ++nc){
    binv[nc] = b_in[16 * nc + c16];
    lg[nc]   = ln_g[16 * nc + c16];
    lb[nc]   = ln_b[16 * nc + c16];
    bc1v[nc] = b_c1[16 * nc + c16];
  }
  float binn = (c16 < 5) ? b_innov[c16] : 0.0f;

  float4 xf[2][8];
  {
    const float* xr = x + (size_t)(tok0 + w * 16 + c16) * DIN;
    #pragma unroll
    for (int kc = 0; kc < 4; ++kc){
      xf[0][2 * kc]     = *(const float4*)(xr + kc * 32 + g4 * 8);
      xf[0][2 * kc + 1] = *(const float4*)(xr + kc * 32 + g4 * 8 + 4);
    }
  }

  asm volatile("s_waitcnt vmcnt(0)" ::: "memory");
  __builtin_amdgcn_sched_barrier(0);
  __syncthreads();

  #pragma unroll
  for (int it = 0; it < NIT; ++it){
    const int cur = it & 1;
    const int nxt = cur ^ 1;
    const long tbg = tok0 + it * 64 + w * 16;

    if (it + 1 < NIT){
      const float* xr = x + (size_t)(tbg + 64 + c16) * DIN;
      #pragma unroll
      for (int kc = 0; kc < 4; ++kc){
        xf[nxt][2 * kc]     = *(const float4*)(xr + kc * 32 + g4 * 8);
        xf[nxt][2 * kc + 1] = *(const float4*)(xr + kc * 32 + g4 * 8 + 4);
      }
    }

    short8_t a1[4];
    #pragma unroll
    for (int kc = 0; kc < 4; ++kc){
      float4 f0 = xf[cur][2 * kc];
      float4 f1 = xf[cur][2 * kc + 1];
      a1[kc][0] = (short)f2bf_hw(f0.x); a1[kc][1] = (short)f2bf_hw(f0.y);
      a1[kc][2] = (short)f2bf_hw(f0.z); a1[kc][3] = (short)f2bf_hw(f0.w);
      a1[kc][4] = (short)f2bf_hw(f1.x); a1[kc][5] = (short)f2bf_hw(f1.y);
      a1[kc][6] = (short)f2bf_hw(f1.z); a1[kc][7] = (short)f2bf_hw(f1.w);
    }

    float4_t acc1[4] = {{0,0,0,0},{0,0,0,0},{0,0,0,0},{0,0,0,0}};
    #pragma unroll
    for (int kc = 0; kc < 4; ++kc){
      #pragma unroll
      for (int nc = 0; nc < 4; ++nc){
        short8_t bf = *(const short8_t*)&WfA[(kc * 4 + nc) * 512 + lane * 8];
        acc1[nc] = __builtin_amdgcn_mfma_f32_16x16x32_bf16(a1[kc], bf, acc1[nc], 0, 0, 0);
      }
    }

    float v[4][4];
    #pragma unroll
    for (int nc = 0; nc < 4; ++nc)
      #pragma unroll
      for (int r = 0; r < 4; ++r)
        v[nc][r] = acc1[nc][r] + binv[nc];

    float mu[4], rstd[4];
    #pragma unroll
    for (int r = 0; r < 4; ++r){
      float vs = (v[0][r] + v[1][r]) + (v[2][r] + v[3][r]);
      float qs = v[0][r] * v[0][r];
      qs = fmaf(v[1][r], v[1][r], qs);
      qs = fmaf(v[2][r], v[2][r], qs);
      qs = fmaf(v[3][r], v[3][r], qs);
      vs = red16(vs);
      qs = red16(qs);
      float m  = vs * (1.0f / 64.0f);
      float va = fmaxf(qs * (1.0f / 64.0f) - m * m, 0.0f);
      mu[r]   = m;
      rstd[r] = rsqrtf(va + 1e-5f);
    }

    #pragma unroll
    for (int nc = 0; nc < 4; ++nc)
      #pragma unroll
      for (int r = 0; r < 4; ++r){
        float hn = fmaf((v[nc][r] - mu[r]) * rstd[r], lg[nc], lb[nc]);
        hbuf[w][4 * g4 + r][16 * nc + c16] = f2bf_hw(geluf(hn));
      }

    short8_t a2[2];
    a2[0] = *(const short8_t*)&hbuf[w][c16][8 * g4];
    a2[1] = *(const short8_t*)&hbuf[w][c16][32 + 8 * g4];

    float4_t acc2[4] = {{0,0,0,0},{0,0,0,0},{0,0,0,0},{0,0,0,0}};
    #pragma unroll
    for (int kc2 = 0; kc2 < 2; ++kc2){
      #pragma unroll
      for (int nc = 0; nc < 4; ++nc){
        short8_t bf = *(const short8_t*)&WfC[(kc2 * 4 + nc) * 512 + lane * 8];
        acc2[nc] = __builtin_amdgcn_mfma_f32_16x16x32_bf16(a2[kc2], bf, acc2[nc], 0, 0, 0);
      }
    }
    float4_t acc3 = {0, 0, 0, 0};
    {
      short8_t bi0 = *(const short8_t*)&WfI[0 * 512 + lane * 8];
      short8_t bi1 = *(const short8_t*)&WfI[1 * 512 + lane * 8];
      acc3 = __builtin_amdgcn_mfma_f32_16x16x32_bf16(a2[0], bi0, acc3, 0, 0, 0);
      acc3 = __builtin_amdgcn_mfma_f32_16x16x32_bf16(a2[1], bi1, acc3, 0, 0, 0);
    }

    if (c16 < 5){
      #pragma unroll
      for (int r = 0; r < 4; ++r)
        bx_out[(size_t)(tbg + 4 * g4 + r) * 8 + c16] = acc3[r] + binn;
    }

    #pragma unroll
    for (int nc = 0; nc < 4; ++nc)
      #pragma unroll
      for (int r = 0; r < 4; ++r)
        hbuf[w][4 * g4 + r][16 * nc + c16] = f2bf_hw(acc2[nc][r] + bc1v[nc]);

    {
      // hp2[b][ch8][tok][8]: lanes 0..15 = tokens (contiguous 256B segments)
      const int tl = lane & 15, jj = lane >> 4;   // token-in-tile, ch8-pair
      uint4 v0 = *(const uint4*)&hbuf[w][tl][jj * 16];
      uint4 v1 = *(const uint4*)&hbuf[w][tl][jj * 16 + 8];
      const long gt  = tbg + tl;          // global token
      const long bb  = gt >> 11;          // batch row
      const long tlc = gt & (S_ - 1);     // token within row
      unsigned short* hg = hp_out + (((bb * 8 + 2 * jj) * (long)S_ + tlc) * 8);
      *(uint4*)hg            = v0;        // ch8 = 2*jj
      *(uint4*)(hg + S_ * 8) = v1;        // ch8 = 2*jj+1
    }
  }
}

// ---------------------------------------------------------------------------
// Phase B (two-pass parallel scan, 1024 threads / 2 tokens per thread).
// Threads below the contraction window contribute exact zeros.
// ---------------------------------------------------------------------------
__global__ __launch_bounds__(TPB, 1) void phaseB(
    const unsigned short* __restrict__ hp, const float* __restrict__ bx,
    const float* __restrict__ W_c1, const float* __restrict__ W_c2,
    const float* __restrict__ b_c2, const float* __restrict__ corr_scale,
    const float* __restrict__ rawL, const float* __restrict__ rawT,
    const float* __restrict__ rawG, const float* __restrict__ rawR,
    const float* __restrict__ omega, float* __restrict__ out)
{
  __shared__ __align__(16) float scanb[2][TPB][6];   // 48 KB
  __shared__ __align__(16) float Wp[64][12];         // 3 KB

  const int tid = threadIdx.x;
  const int b = blockIdx.x;

  const int T0a = window_T0a(rawL, rawT, rawG, rawR);
  const bool act = (tid * SEG >= T0a);   // both of this thread's tokens in-window

  float aL = sigmoidf_(rawL[0]) * 0.15f + 0.85f;
  float aT = sigmoidf_(rawT[0]) * 0.25f + 0.70f;
  float gg = sigmoidf_(rawG[0]) * 0.20f + 0.80f;
  float om = omega[0];
  float gc = gg * cosf(om), gs = gg * sinf(om);
  float aR = sigmoidf_(rawR[0]) * 0.4f;
  float cs = corr_scale[0];
  float bc0 = b_c2[0], bc1 = b_c2[1], bc2v = b_c2[2], bc3 = b_c2[3], bc4 = b_c2[4];

  if (tid < 64){
    #pragma unroll
    for (int i = 0; i < 5; ++i) Wp[tid][i]     = W_c1[i * 64 + tid];
    #pragma unroll
    for (int i = 0; i < 5; ++i) Wp[tid][5 + i] = W_c2[tid * 5 + i];
  }

  const float* bxr = bx + (size_t)b * S_ * 8 + (size_t)tid * (SEG * 8);
  const unsigned short* hpg = hp + (size_t)b * S_ * H_;   // = b*8*S*8

  // ---- pass 1 local: SEG-step serial prefix (zeros when inactive) ----
  float p[SEG][5];
  {
    float c0 = 0.f, c1 = 0.f, c2 = 0.f, c3 = 0.f, c4 = 0.f;
    if (act){
      #pragma unroll
      for (int j = 0; j < SEG; ++j){
        float4 vb = *(const float4*)&bxr[j * 8];
        float  ve = bxr[j * 8 + 4];
        float n0 = fmaf(c0, aL, vb.x);
        float n1 = fmaf(c1, aT, vb.y);
        float n2 = fmaf(c2, gc, fmaf(c3, gs, vb.z));
        float n3 = fmaf(c2, -gs, fmaf(c3, gc, vb.w));
        float n4 = fmaf(c4, aR, ve);
        c0 = n0; c1 = n1; c2 = n2; c3 = n3; c4 = n4;
        p[j][0] = n0; p[j][1] = n1; p[j][2] = n2; p[j][3] = n3; p[j][4] = n4;
      }
    } else {
      #pragma unroll
      for (int j = 0; j < SEG; ++j){
        p[j][0]=0.f; p[j][1]=0.f; p[j][2]=0.f; p[j][3]=0.f; p[j][4]=0.f;
      }
    }
    scanb[0][tid][0] = c0; scanb[0][tid][1] = c1; scanb[0][tid][2] = c2;
    scanb[0][tid][3] = c3; scanb[0][tid][4] = c4;
  }
  __syncthreads();

  // ---- Kogge-Stone over TPB segment aggregates ----
  int bufc = 0;
  {
    float mL = aL, mT = aT, mc = gc, ms = gs, mR = aR;
    {
      float nc = mc * mc - ms * ms, ns = 2.f * mc * ms;
      mL *= mL; mT *= mT; mR *= mR; mc = nc; ms = ns;
    }
    #pragma unroll
    for (int d = 0; d < LEV; ++d){
      const int off = 1 << d;
      float x0 = scanb[bufc][tid][0], x1 = scanb[bufc][tid][1],
            x2 = scanb[bufc][tid][2], x3 = scanb[bufc][tid][3],
            x4 = scanb[bufc][tid][4];
      if (tid >= off){
        const float* pr = &scanb[bufc][tid - off][0];
        float q0 = pr[0], q1 = pr[1], q2 = pr[2], q3 = pr[3], q4 = pr[4];
        x0 = fmaf(q0, mL, x0);
        x1 = fmaf(q1, mT, x1);
        x2 = fmaf(q2, mc, fmaf(q3, ms, x2));
        x3 = fmaf(q2, -ms, fmaf(q3, mc, x3));
        x4 = fmaf(q4, mR, x4);
      }
      scanb[bufc ^ 1][tid][0] = x0; scanb[bufc ^ 1][tid][1] = x1;
      scanb[bufc ^ 1][tid][2] = x2; scanb[bufc ^ 1][tid][3] = x3;
      scanb[bufc ^ 1][tid][4] = x4;
      __syncthreads();
      bufc ^= 1;
      float nc = mc * mc - ms * ms, ns = 2.f * mc * ms;
      mL *= mL; mT *= mT; mR *= mR; mc = nc; ms = ns;
    }
  }

  // ---- exclusive offset + full states ----
  if (act){
    float o0 = 0.f, o1 = 0.f, o2 = 0.f, o3 = 0.f, o4 = 0.f;
    if (tid > 0){
      const float* pr = &scanb[bufc][tid - 1][0];
      o0 = pr[0]; o1 = pr[1]; o2 = pr[2]; o3 = pr[3]; o4 = pr[4];
    }
    #pragma unroll
    for (int j = 0; j < SEG; ++j){
      float n0 = o0 * aL;
      float n1 = o1 * aT;
      float n2 = fmaf(o2, gc, o3 * gs);
      float n3 = fmaf(o3, gc, -o2 * gs);
      float n4 = o4 * aR;
      o0 = n0; o1 = n1; o2 = n2; o3 = n3; o4 = n4;
      p[j][0] += n0; p[j][1] += n1; p[j][2] += n2; p[j][3] += n3; p[j][4] += n4;
    }
  }

  // ---- c-eval: windowed tokens only (coalesced hp reads) ----
  float acc[SEG][5];
  #pragma unroll
  for (int j = 0; j < SEG; ++j){
    acc[j][0]=0.f; acc[j][1]=0.f; acc[j][2]=0.f; acc[j][3]=0.f; acc[j][4]=0.f;
  }

  if (act){
    #pragma unroll
    for (int ch = 0; ch < 8; ++ch){
      uint4 hpc[SEG];
      #pragma unroll
      for (int tok = 0; tok < SEG; ++tok)
        hpc[tok] = *(const uint4*)&hpg[((size_t)ch * S_ + (tid * SEG + tok)) * 8];
      #pragma unroll
      for (int jj = 0; jj < 8; ++jj){
        const float* wr = &Wp[ch * 8 + jj][0];
        float w0 = wr[0], w1 = wr[1], w2 = wr[2], w3 = wr[3], w4 = wr[4];
        float q0 = wr[5], q1 = wr[6], q2 = wr[7], q3 = wr[8], q4 = wr[9];
        #pragma unroll
        for (int tok = 0; tok < SEG; ++tok){
          unsigned int word = ((const unsigned int*)&hpc[tok])[jj >> 1];
          unsigned short hu = (jj & 1) ? (unsigned short)(word >> 16)
                                       : (unsigned short)(word & 0xffff);
          float hv = bf2f(hu);
          float up = fmaf(p[tok][0], w0, hv);
          up = fmaf(p[tok][1], w1, up);
          up = fmaf(p[tok][2], w2, up);
          up = fmaf(p[tok][3], w3, up);
          up = fmaf(p[tok][4], w4, up);
          float u = up * rcpf_(1.0f + __expf(-1.702f * up));   // sigmoid-GELU
          acc[tok][0] = fmaf(u, q0, acc[tok][0]);
          acc[tok][1] = fmaf(u, q1, acc[tok][1]);
          acc[tok][2] = fmaf(u, q2, acc[tok][2]);
          acc[tok][3] = fmaf(u, q3, acc[tok][3]);
          acc[tok][4] = fmaf(u, q4, acc[tok][4]);
        }
      }
    }
  }

  // ---- pass 2 local aggregate: v' = bx + c (zero when inactive) ----
  float a0 = 0.f, a1 = 0.f, a2 = 0.f, a3 = 0.f, a4 = 0.f;
  if (act){
    #pragma unroll
    for (int j = 0; j < SEG; ++j){
      float4 vb = *(const float4*)&bxr[j * 8];
      float  ve = bxr[j * 8 + 4];
      float c0v = cs * tanh_pade(acc[j][0] + bc0);
      float c1v = cs * tanh_pade(acc[j][1] + bc1);
      float c2v = cs * tanh_pade(acc[j][2] + bc2v);
      float c3v = cs * tanh_pade(acc[j][3] + bc3);
      float c4v = cs * tanh_pade(acc[j][4] + bc4);
      float v0 = vb.x + c0v, v1 = vb.y + c1v, v2 = vb.z + c2v,
            v3 = vb.w + c3v, v4 = ve + c4v;
      float n0 = fmaf(a0, aL, v0);
      float n1 = fmaf(a1, aT, v1);
      float n2 = fmaf(a2, gc, fmaf(a3, gs, v2));
      float n3 = fmaf(a2, -gs, fmaf(a3, gc, v3));
      float n4 = fmaf(a4, aR, v4);
      a0 = n0; a1 = n1; a2 = n2; a3 = n3; a4 = n4;
    }
  }
  __syncthreads();
  scanb[0][tid][0] = a0; scanb[0][tid][1] = a1; scanb[0][tid][2] = a2;
  scanb[0][tid][3] = a3; scanb[0][tid][4] = a4;
  __syncthreads();

  // ---- Kogge-Stone pass 2 (inclusive; thread TPB-1 ends with s_2047) ----
  bufc = 0;
  {
    float mL = aL, mT = aT, mc = gc, ms = gs, mR = aR;
    {
      float nc = mc * mc - ms * ms, ns = 2.f * mc * ms;
      mL *= mL; mT *= mT; mR *= mR; mc = nc; ms = ns;
    }
    float x0 = 0.f, x1 = 0.f, x2 = 0.f, x3 = 0.f, x4 = 0.f;
    #pragma unroll
    for (int d = 0; d < LEV; ++d){
      const int off = 1 << d;
      x0 = scanb[bufc][tid][0]; x1 = scanb[bufc][tid][1];
      x2 = scanb[bufc][tid][2]; x3 = scanb[bufc][tid][3];
      x4 = scanb[bufc][tid][4];
      if (tid >= off){
        const float* pr = &scanb[bufc][tid - off][0];
        float q0 = pr[0], q1 = pr[1], q2 = pr[2], q3 = pr[3], q4 = pr[4];
        x0 = fmaf(q0, mL, x0);
        x1 = fmaf(q1, mT, x1);
        x2 = fmaf(q2, mc, fmaf(q3, ms, x2));
        x3 = fmaf(q2, -ms, fmaf(q3, mc, x3));
        x4 = fmaf(q4, mR, x4);
      }
      scanb[bufc ^ 1][tid][0] = x0; scanb[bufc ^ 1][tid][1] = x1;
      scanb[bufc ^ 1][tid][2] = x2; scanb[bufc ^ 1][tid][3] = x3;
      scanb[bufc ^ 1][tid][4] = x4;
      __syncthreads();
      bufc ^= 1;
      float nc = mc * mc - ms * ms, ns = 2.f * mc * ms;
      mL *= mL; mT *= mT; mR *= mR; mc = nc; ms = ns;
    }
    if (tid == TPB - 1){
      float* o = out + b * SD_;
      o[0] = x0; o[1] = x1; o[2] = x2; o[3] = x3; o[4] = x4;
    }
  }
}

// ---------------------------------------------------------------------------
extern "C" void kernel_launch(void* const* d_in, const int* in_sizes, int n_in,
                              void* d_out, int out_size, void* d_ws, size_t ws_size,
                              hipStream_t stream)
{
  const float* x          = (const float*)d_in[0];
  const float* W_in       = (const float*)d_in[1];
  const float* b_in       = (const float*)d_in[2];
  const float* ln_g       = (const float*)d_in[3];
  const float* ln_b       = (const float*)d_in[4];
  const float* W_innov    = (const float*)d_in[5];
  const float* b_innov    = (const float*)d_in[6];
  const float* W_c1       = (const float*)d_in[7];
  const float* b_c1       = (const float*)d_in[8];
  const float* W_c2       = (const float*)d_in[9];
  const float* b_c2       = (const float*)d_in[10];
  const float* corr_scale = (const float*)d_in[11];
  const float* rawL       = (const float*)d_in[12];
  const float* rawT       = (const float*)d_in[13];
  const float* rawG       = (const float*)d_in[14];
  const float* rawR       = (const float*)d_in[15];
  const float* omega      = (const float*)d_in[16];

  unsigned short* hp = (unsigned short*)d_ws;
  float* bx = (float*)((char*)d_ws + (size_t)B_ * S_ * H_ * 2);
  unsigned short* wf = (unsigned short*)((char*)d_ws
                        + (size_t)B_ * S_ * H_ * 2 + (size_t)B_ * S_ * 8 * 4);

  wsetup<<<1, 64, 0, stream>>>(W_in, W_c1, W_innov, wf);
  int nblocksA = (B_ * S_) / TOKB;   // 2048
  phaseA<<<nblocksA, 256, 0, stream>>>(x, wf, b_in, ln_g, ln_b,
                                       b_innov, b_c1,
                                       rawL, rawT, rawG, rawR, hp, bx);
  phaseB<<<B_, TPB, 0, stream>>>(hp, bx, W_c1, W_c2, b_c2, corr_scale,
                                 rawL, rawT, rawG, rawR, omega, (float*)d_out);
}